// Round 2
// baseline (1309.920 us; speedup 1.0000x reference)
//
#include <hip/hip_runtime.h>
#include <hip/hip_bf16.h>
#include <math.h>

#define NNODES 100000
#define NEDGES 1600000

// ---------------- utility ----------------
__global__ void zero_i32(int* p, int n) {
    int i = blockIdx.x * blockDim.x + threadIdx.x;
    if (i < n) p[i] = 0;
}

// count in-degree and sum of edge weights per dst
__global__ void count_k(const int* __restrict__ ei, const float* __restrict__ ew,
                        int* __restrict__ deg, float* __restrict__ sum_ew, int E, int n) {
    int e = blockIdx.x * blockDim.x + threadIdx.x;
    if (e >= E) return;
    unsigned dstv = (unsigned)ei[E + e];
    if (dstv < (unsigned)n) {
        atomicAdd(&deg[dstv], 1);
        atomicAdd(&sum_ew[dstv], ew[e]);
    }
}

// ---------------- scan (counts = deg+1, for self loop) ----------------
// blocks of 1024 elements (256 threads x 4)
__global__ void scanA(const int* __restrict__ deg, int* __restrict__ row_start,
                      int* __restrict__ blkSums, int n) {
    __shared__ int sdata[256];
    int tid = threadIdx.x;
    int base = blockIdx.x * 1024 + tid * 4;
    int v[4];
    int sum = 0;
#pragma unroll
    for (int j = 0; j < 4; j++) {
        int idx = base + j;
        int c = (idx < n) ? (deg[idx] + 1) : 0;
        sum += c;
        v[j] = sum;  // thread-local inclusive
    }
    sdata[tid] = sum;
    __syncthreads();
    for (int off = 1; off < 256; off <<= 1) {
        int t = (tid >= off) ? sdata[tid - off] : 0;
        __syncthreads();
        sdata[tid] += t;
        __syncthreads();
    }
    int excl = sdata[tid] - sum;  // exclusive offset of this thread within block
#pragma unroll
    for (int j = 0; j < 4; j++) {
        int idx = base + j;
        if (idx < n) row_start[idx + 1] = excl + v[j];  // block-local inclusive
    }
    if (tid == 255) blkSums[blockIdx.x] = sdata[255];
}

__global__ void scanB(int* __restrict__ blkSums, int nblk) {
    __shared__ int sdata[128];
    int tid = threadIdx.x;
    int v = (tid < nblk) ? blkSums[tid] : 0;
    sdata[tid] = v;
    __syncthreads();
    for (int off = 1; off < 128; off <<= 1) {
        int t = (tid >= off) ? sdata[tid - off] : 0;
        __syncthreads();
        sdata[tid] += t;
        __syncthreads();
    }
    if (tid < nblk) blkSums[tid] = sdata[tid] - v;  // exclusive
}

__global__ void scanC(int* __restrict__ row_start, const int* __restrict__ blkSums, int n) {
    int idx = blockIdx.x * blockDim.x + threadIdx.x;
    if (idx < n) row_start[idx + 1] += blkSums[idx >> 10];
    if (idx == 0) row_start[0] = 0;
}

// ---------------- scatter edges into CSR (by dst) ----------------
__global__ void scatter_k(const int* __restrict__ ei, const float* __restrict__ ew,
                          const int* __restrict__ row_start, int* __restrict__ fill,
                          const int* __restrict__ deg, const float* __restrict__ sum_ew,
                          int* __restrict__ esrc, float* __restrict__ ewt, int E, int n) {
    int e = blockIdx.x * blockDim.x + threadIdx.x;
    if (e < E) {
        unsigned srcv = (unsigned)ei[e];
        unsigned dstv = (unsigned)ei[E + e];
        if (srcv < (unsigned)n && dstv < (unsigned)n) {
            int pos = row_start[dstv] + atomicAdd(&fill[dstv], 1);
            esrc[pos] = (int)srcv;
            ewt[pos] = ew[e];
        }
    } else if (e < E + n) {
        int i = e - E;
        int dg = deg[i];
        float w = sum_ew[i] / (float)(dg > 1 ? dg : 1);
        int pos = row_start[i] + atomicAdd(&fill[i], 1);
        esrc[pos] = i;
        ewt[pos] = w;
    }
}

// ---------------- ce[l] = dot(We_l, ae_l) ----------------
__global__ void ce_k(const float* We1, const float* ae1,
                     const float* We2, const float* ae2,
                     const float* We3, const float* ae3, float* ce) {
    const float* W;
    const float* a;
    int cout;
    if (blockIdx.x == 0) { W = We1; a = ae1; cout = 128; }
    else if (blockIdx.x == 1) { W = We2; a = ae2; cout = 128; }
    else { W = We3; a = ae3; cout = 64; }
    int lane = threadIdx.x;
    float v = 0.f;
    for (int c = lane; c < cout; c += 64) v += W[c] * a[c];
    for (int o = 32; o; o >>= 1) v += __shfl_xor(v, o);
    if (lane == 0) ce[blockIdx.x] = v;
}

// ---------------- GEMM: H = X @ W  (X [n,cin] row-major, W [cin,cout]) ----------------
// 64x64 tile, 256 threads, 4x4 per thread, K-tile 32
__global__ void gemm_k(const float* __restrict__ X, const float* __restrict__ W,
                       float* __restrict__ H, int nrows, int cin, int cout) {
    __shared__ float xs[64][33];
    __shared__ float ws[32][65];
    int tx = threadIdx.x % 16, ty = threadIdx.x / 16;
    int row0 = blockIdx.x * 64, col0 = blockIdx.y * 64;
    float acc[4][4] = {};
    for (int k0 = 0; k0 < cin; k0 += 32) {
        // X tile: 64 rows x 32 cols = 512 float4
        for (int i = threadIdx.x; i < 512; i += 256) {
            int r = i >> 3;          // /8 float4 per row
            int c = (i & 7) << 2;
            int gr = row0 + r;
            float4 v = make_float4(0.f, 0.f, 0.f, 0.f);
            if (gr < nrows) v = *(const float4*)&X[(size_t)gr * cin + k0 + c];
            xs[r][c] = v.x; xs[r][c + 1] = v.y; xs[r][c + 2] = v.z; xs[r][c + 3] = v.w;
        }
        // W tile: 32 rows x 64 cols = 512 float4
        for (int i = threadIdx.x; i < 512; i += 256) {
            int r = i >> 4;          // /16 float4 per row
            int c = (i & 15) << 2;
            float4 v = *(const float4*)&W[(size_t)(k0 + r) * cout + col0 + c];
            ws[r][c] = v.x; ws[r][c + 1] = v.y; ws[r][c + 2] = v.z; ws[r][c + 3] = v.w;
        }
        __syncthreads();
#pragma unroll
        for (int k = 0; k < 32; k++) {
            float a[4], b[4];
#pragma unroll
            for (int i = 0; i < 4; i++) a[i] = xs[ty * 4 + i][k];
#pragma unroll
            for (int j = 0; j < 4; j++) b[j] = ws[k][tx * 4 + j];
#pragma unroll
            for (int i = 0; i < 4; i++)
#pragma unroll
                for (int j = 0; j < 4; j++) acc[i][j] += a[i] * b[j];
        }
        __syncthreads();
    }
#pragma unroll
    for (int i = 0; i < 4; i++) {
        int r = row0 + ty * 4 + i;
        if (r >= nrows) continue;
#pragma unroll
        for (int j = 0; j < 4; j++) {
            H[(size_t)r * cout + col0 + tx * 4 + j] = acc[i][j];
        }
    }
}

// ---------------- per-node attention scalars: s = h@a_s, d = h@a_d ----------------
__global__ void sd_k(const float* __restrict__ h, const float* __restrict__ as,
                     const float* __restrict__ ad, float* __restrict__ s,
                     float* __restrict__ d, int n, int cout) {
    int wid = (blockIdx.x * blockDim.x + threadIdx.x) >> 6;
    int lane = threadIdx.x & 63;
    if (wid >= n) return;
    const float* hr = &h[(size_t)wid * cout];
    float vs = 0.f, vd = 0.f;
    for (int c = lane; c < cout; c += 64) {
        float hv = hr[c];
        vs += hv * as[c];
        vd += hv * ad[c];
    }
    for (int o = 32; o; o >>= 1) {
        vs += __shfl_xor(vs, o);
        vd += __shfl_xor(vd, o);
    }
    if (lane == 0) { s[wid] = vs; d[wid] = vd; }
}

// ---------------- attention + aggregation: one wave per dst node ----------------
__global__ void agg_k(const int* __restrict__ esrc, const float* __restrict__ ewt,
                      const int* __restrict__ row_start, const float* __restrict__ h,
                      const float* __restrict__ s, const float* __restrict__ d,
                      const float* __restrict__ ce_ptr, const float* __restrict__ bias,
                      float* __restrict__ out, int n, int cout) {
    int wid = (blockIdx.x * blockDim.x + threadIdx.x) >> 6;
    int lane = threadIdx.x & 63;
    if (wid >= n) return;
    int lo = row_start[wid], hi = row_start[wid + 1];
    int ne = hi - lo;
    float ce = *ce_ptr;
    float di = d[wid];
    // pass 1: max logit (lane-parallel over edges)
    float m = -1e30f;
    for (int e = lane; e < ne; e += 64) {
        int src = esrc[lo + e];
        float lg = s[src] + di + ce * ewt[lo + e];
        lg = lg > 0.f ? lg : 0.2f * lg;
        m = fmaxf(m, lg);
    }
    for (int o = 32; o; o >>= 1) m = fmaxf(m, __shfl_xor(m, o));
    // pass 2: serial over edges (uniform), channel-parallel accumulate
    float den = 0.f;
    int c0 = lane, c1 = lane + 64;
    float a0 = 0.f, a1 = 0.f;
    for (int e = 0; e < ne; e++) {
        int src = esrc[lo + e];               // broadcast load
        float lg = s[src] + di + ce * ewt[lo + e];
        lg = lg > 0.f ? lg : 0.2f * lg;
        float ex = expf(lg - m);
        den += ex;
        const float* hr = &h[(size_t)src * cout];
        a0 += ex * hr[c0];
        if (cout > 64) a1 += ex * hr[c1];
    }
    float inv = 1.0f / (den + 1e-16f);
    float o0 = a0 * inv + bias[c0];
    o0 = o0 > 0.f ? o0 : 0.01f * o0;
    out[(size_t)wid * cout + c0] = o0;
    if (cout > 64) {
        float o1 = a1 * inv + bias[c1];
        o1 = o1 > 0.f ? o1 : 0.01f * o1;
        out[(size_t)wid * cout + c1] = o1;
    }
}

extern "C" void kernel_launch(void* const* d_in, const int* in_sizes, int n_in,
                              void* d_out, int out_size, void* d_ws, size_t ws_size,
                              hipStream_t stream) {
    const int N = NNODES, E = NEDGES, EF = NEDGES + NNODES;

    const float* x = (const float*)d_in[0];
    const int* ei = (const int*)d_in[1];   // int32 on device (harness contract)
    const float* ew = (const float*)d_in[2];
    const float* W1 = (const float*)d_in[3];
    const float* as1 = (const float*)d_in[4];
    const float* ad1 = (const float*)d_in[5];
    const float* We1 = (const float*)d_in[6];
    const float* ae1 = (const float*)d_in[7];
    const float* b1 = (const float*)d_in[8];
    const float* W2 = (const float*)d_in[9];
    const float* as2 = (const float*)d_in[10];
    const float* ad2 = (const float*)d_in[11];
    const float* We2 = (const float*)d_in[12];
    const float* ae2 = (const float*)d_in[13];
    const float* b2 = (const float*)d_in[14];
    const float* W3 = (const float*)d_in[15];
    const float* as3 = (const float*)d_in[16];
    const float* ad3 = (const float*)d_in[17];
    const float* We3 = (const float*)d_in[18];
    const float* ae3 = (const float*)d_in[19];
    const float* b3 = (const float*)d_in[20];
    float* out = (float*)d_out;

    // workspace layout
    float* act = (float*)d_ws;                      // N*128
    float* h = act + (size_t)N * 128;               // N*128
    float* s = h + (size_t)N * 128;                 // N
    float* dd = s + N;                              // N
    int* deg = (int*)(dd + N);                      // N   } contiguous for
    float* sum_ew = (float*)(deg + N);              // N   } one zeroing
    int* fill = (int*)(sum_ew + N);                 // N   } launch
    int* row_start = fill + N;                      // N+1
    int* blkSums = row_start + (N + 1);             // 128
    int* esrc = blkSums + 128;                      // EF
    float* ewt = (float*)(esrc + EF);               // EF
    float* ce = ewt + EF;                           // 3

    // ---- build CSR by dst (with self loops, fill_value='mean') ----
    zero_i32<<<(3 * N + 255) / 256, 256, 0, stream>>>(deg, 3 * N);
    count_k<<<(E + 255) / 256, 256, 0, stream>>>(ei, ew, deg, sum_ew, E, N);
    int nblkA = (N + 1023) / 1024;  // 98
    scanA<<<nblkA, 256, 0, stream>>>(deg, row_start, blkSums, N);
    scanB<<<1, 128, 0, stream>>>(blkSums, nblkA);
    scanC<<<(N + 255) / 256, 256, 0, stream>>>(row_start, blkSums, N);
    scatter_k<<<(E + N + 255) / 256, 256, 0, stream>>>(ei, ew, row_start, fill, deg,
                                                       sum_ew, esrc, ewt, E, N);
    ce_k<<<3, 64, 0, stream>>>(We1, ae1, We2, ae2, We3, ae3, ce);

    // ---- layer 1: 256 -> 128 ----
    {
        int cin = 256, cout = 128;
        dim3 grid((N + 63) / 64, cout / 64);
        gemm_k<<<grid, 256, 0, stream>>>(x, W1, h, N, cin, cout);
        sd_k<<<(N + 3) / 4, 256, 0, stream>>>(h, as1, ad1, s, dd, N, cout);
        agg_k<<<(N + 3) / 4, 256, 0, stream>>>(esrc, ewt, row_start, h, s, dd, ce + 0,
                                               b1, act, N, cout);
    }
    // ---- layer 2: 128 -> 128 ----
    {
        int cin = 128, cout = 128;
        dim3 grid((N + 63) / 64, cout / 64);
        gemm_k<<<grid, 256, 0, stream>>>(act, W2, h, N, cin, cout);
        sd_k<<<(N + 3) / 4, 256, 0, stream>>>(h, as2, ad2, s, dd, N, cout);
        agg_k<<<(N + 3) / 4, 256, 0, stream>>>(esrc, ewt, row_start, h, s, dd, ce + 1,
                                               b2, act, N, cout);
    }
    // ---- layer 3: 128 -> 64 ----
    {
        int cin = 128, cout = 64;
        dim3 grid((N + 63) / 64, cout / 64);
        gemm_k<<<grid, 256, 0, stream>>>(act, W3, h, N, cin, cout);
        sd_k<<<(N + 3) / 4, 256, 0, stream>>>(h, as3, ad3, s, dd, N, cout);
        agg_k<<<(N + 3) / 4, 256, 0, stream>>>(esrc, ewt, row_start, h, s, dd, ce + 2,
                                               b3, out, N, cout);
    }
}

// Round 3
// 851.630 us; speedup vs baseline: 1.5381x; 1.5381x over previous
//
#include <hip/hip_runtime.h>
#include <hip/hip_bf16.h>
#include <math.h>

#define NNODES 100000
#define NEDGES 1600000
#define MAXE 128

// ---------------- utility ----------------
__global__ void zero_i32(int* p, int n) {
    int i = blockIdx.x * blockDim.x + threadIdx.x;
    if (i < n) p[i] = 0;
}

// count in-degree and sum of edge weights per dst
__global__ void count_k(const int* __restrict__ ei, const float* __restrict__ ew,
                        int* __restrict__ deg, float* __restrict__ sum_ew, int E, int n) {
    int e = blockIdx.x * blockDim.x + threadIdx.x;
    if (e >= E) return;
    unsigned dstv = (unsigned)ei[E + e];
    if (dstv < (unsigned)n) {
        atomicAdd(&deg[dstv], 1);
        atomicAdd(&sum_ew[dstv], ew[e]);
    }
}

// ---------------- scan (counts = deg+1, for self loop) ----------------
__global__ void scanA(const int* __restrict__ deg, int* __restrict__ row_start,
                      int* __restrict__ blkSums, int n) {
    __shared__ int sdata[256];
    int tid = threadIdx.x;
    int base = blockIdx.x * 1024 + tid * 4;
    int v[4];
    int sum = 0;
#pragma unroll
    for (int j = 0; j < 4; j++) {
        int idx = base + j;
        int c = (idx < n) ? (deg[idx] + 1) : 0;
        sum += c;
        v[j] = sum;
    }
    sdata[tid] = sum;
    __syncthreads();
    for (int off = 1; off < 256; off <<= 1) {
        int t = (tid >= off) ? sdata[tid - off] : 0;
        __syncthreads();
        sdata[tid] += t;
        __syncthreads();
    }
    int excl = sdata[tid] - sum;
#pragma unroll
    for (int j = 0; j < 4; j++) {
        int idx = base + j;
        if (idx < n) row_start[idx + 1] = excl + v[j];
    }
    if (tid == 255) blkSums[blockIdx.x] = sdata[255];
}

__global__ void scanB(int* __restrict__ blkSums, int nblk) {
    __shared__ int sdata[128];
    int tid = threadIdx.x;
    int v = (tid < nblk) ? blkSums[tid] : 0;
    sdata[tid] = v;
    __syncthreads();
    for (int off = 1; off < 128; off <<= 1) {
        int t = (tid >= off) ? sdata[tid - off] : 0;
        __syncthreads();
        sdata[tid] += t;
        __syncthreads();
    }
    if (tid < nblk) blkSums[tid] = sdata[tid] - v;
}

__global__ void scanC(int* __restrict__ row_start, const int* __restrict__ blkSums, int n) {
    int idx = blockIdx.x * blockDim.x + threadIdx.x;
    if (idx < n) row_start[idx + 1] += blkSums[idx >> 10];
    if (idx == 0) row_start[0] = 0;
}

// ---------------- scatter edges into CSR (by dst) ----------------
__global__ void scatter_k(const int* __restrict__ ei, const float* __restrict__ ew,
                          const int* __restrict__ row_start, int* __restrict__ fill,
                          const int* __restrict__ deg, const float* __restrict__ sum_ew,
                          int* __restrict__ esrc, float* __restrict__ ewt, int E, int n) {
    int e = blockIdx.x * blockDim.x + threadIdx.x;
    if (e < E) {
        unsigned srcv = (unsigned)ei[e];
        unsigned dstv = (unsigned)ei[E + e];
        if (srcv < (unsigned)n && dstv < (unsigned)n) {
            int pos = row_start[dstv] + atomicAdd(&fill[dstv], 1);
            esrc[pos] = (int)srcv;
            ewt[pos] = ew[e];
        }
    } else if (e < E + n) {
        int i = e - E;
        int dg = deg[i];
        float w = sum_ew[i] / (float)(dg > 1 ? dg : 1);
        int pos = row_start[i] + atomicAdd(&fill[i], 1);
        esrc[pos] = i;
        ewt[pos] = w;
    }
}

// ---------------- ce[l] = dot(We_l, ae_l) ----------------
__global__ void ce_k(const float* We1, const float* ae1,
                     const float* We2, const float* ae2,
                     const float* We3, const float* ae3, float* ce) {
    const float* W;
    const float* a;
    int cout;
    if (blockIdx.x == 0) { W = We1; a = ae1; cout = 128; }
    else if (blockIdx.x == 1) { W = We2; a = ae2; cout = 128; }
    else { W = We3; a = ae3; cout = 64; }
    int lane = threadIdx.x;
    float v = 0.f;
    for (int c = lane; c < cout; c += 64) v += W[c] * a[c];
    for (int o = 32; o; o >>= 1) v += __shfl_xor(v, o);
    if (lane == 0) ce[blockIdx.x] = v;
}

// ---------------- GEMM: H = X @ W, fused s/d partial dots ----------------
// 64x64 tile, 256 threads, 4x4 per thread, K-tile 32
__global__ void gemm_k(const float* __restrict__ X, const float* __restrict__ W,
                       float* __restrict__ H, const float* __restrict__ as_,
                       const float* __restrict__ ad_, float* __restrict__ s,
                       float* __restrict__ d, int nrows, int cin, int cout) {
    __shared__ float xs[64][33];
    __shared__ float ws[32][65];
    int tx = threadIdx.x % 16, ty = threadIdx.x / 16;
    int row0 = blockIdx.x * 64, col0 = blockIdx.y * 64;
    float acc[4][4] = {};
    for (int k0 = 0; k0 < cin; k0 += 32) {
        for (int i = threadIdx.x; i < 512; i += 256) {
            int r = i >> 3;
            int c = (i & 7) << 2;
            int gr = row0 + r;
            float4 v = make_float4(0.f, 0.f, 0.f, 0.f);
            if (gr < nrows) v = *(const float4*)&X[(size_t)gr * cin + k0 + c];
            xs[r][c] = v.x; xs[r][c + 1] = v.y; xs[r][c + 2] = v.z; xs[r][c + 3] = v.w;
        }
        for (int i = threadIdx.x; i < 512; i += 256) {
            int r = i >> 4;
            int c = (i & 15) << 2;
            float4 v = *(const float4*)&W[(size_t)(k0 + r) * cout + col0 + c];
            ws[r][c] = v.x; ws[r][c + 1] = v.y; ws[r][c + 2] = v.z; ws[r][c + 3] = v.w;
        }
        __syncthreads();
#pragma unroll
        for (int k = 0; k < 32; k++) {
            float a[4], b[4];
#pragma unroll
            for (int i = 0; i < 4; i++) a[i] = xs[ty * 4 + i][k];
#pragma unroll
            for (int j = 0; j < 4; j++) b[j] = ws[k][tx * 4 + j];
#pragma unroll
            for (int i = 0; i < 4; i++)
#pragma unroll
                for (int j = 0; j < 4; j++) acc[i][j] += a[i] * b[j];
        }
        __syncthreads();
    }
#pragma unroll
    for (int i = 0; i < 4; i++) {
        int r = row0 + ty * 4 + i;
        if (r >= nrows) continue;
#pragma unroll
        for (int j = 0; j < 4; j++) {
            H[(size_t)r * cout + col0 + tx * 4 + j] = acc[i][j];
        }
        // fused partial attention dots for this row (16 lanes share row, xor<16 stays in group)
        float ps = 0.f, pd = 0.f;
#pragma unroll
        for (int j = 0; j < 4; j++) {
            int c = col0 + tx * 4 + j;
            ps += acc[i][j] * as_[c];
            pd += acc[i][j] * ad_[c];
        }
        for (int o = 8; o; o >>= 1) {
            ps += __shfl_xor(ps, o);
            pd += __shfl_xor(pd, o);
        }
        if (tx == 0) {
            atomicAdd(&s[r], ps);
            atomicAdd(&d[r], pd);
        }
    }
}

// ---------------- attention + aggregation: one wave per dst node ----------------
__global__ __launch_bounds__(256) void agg_k(
    const int* __restrict__ esrc, const float* __restrict__ ewt,
    const int* __restrict__ row_start, const float* __restrict__ h,
    const float* __restrict__ s, const float* __restrict__ d,
    const float* __restrict__ ce_ptr, const float* __restrict__ bias,
    float* __restrict__ out, int n, int cout) {
    __shared__ float ex_s[4][MAXE];
    __shared__ int src_s[4][MAXE];
    int wslot = threadIdx.x >> 6;
    int wid = (blockIdx.x * blockDim.x + threadIdx.x) >> 6;
    int lane = threadIdx.x & 63;
    if (wid >= n) return;
    int lo = row_start[wid], ne = row_start[wid + 1] - lo;
    float ce = *ce_ptr;
    float di = d[wid];

    if (ne <= MAXE) {
        // pass 1: lane-parallel logits; cache src + logit in LDS
        float m = -1e30f;
        for (int e = lane; e < ne; e += 64) {
            int src = esrc[lo + e];
            float lg = s[src] + di + ce * ewt[lo + e];
            lg = lg > 0.f ? lg : 0.2f * lg;
            src_s[wslot][e] = src;
            ex_s[wslot][e] = lg;
            m = fmaxf(m, lg);
        }
        for (int o = 32; o; o >>= 1) m = fmaxf(m, __shfl_xor(m, o));
        // convert logit -> ex in LDS, reduce denominator
        float den = 0.f;
        for (int e = lane; e < ne; e += 64) {
            float exv = __expf(ex_s[wslot][e] - m);
            ex_s[wslot][e] = exv;
            den += exv;
        }
        for (int o = 32; o; o >>= 1) den += __shfl_xor(den, o);
        float inv = 1.0f / (den + 1e-16f);

        if (cout == 128) {
            // 2 edges/iter x 32 lanes x float4
            int half = lane >> 5, l32 = lane & 31;
            const float4* h4 = (const float4*)h;
            float4 a = make_float4(0.f, 0.f, 0.f, 0.f);
#pragma unroll 4
            for (int e = half; e < ne; e += 2) {
                float exv = ex_s[wslot][e];
                int src = src_s[wslot][e];
                float4 hv = h4[(size_t)src * 32 + l32];
                a.x += exv * hv.x; a.y += exv * hv.y;
                a.z += exv * hv.z; a.w += exv * hv.w;
            }
            a.x += __shfl_xor(a.x, 32); a.y += __shfl_xor(a.y, 32);
            a.z += __shfl_xor(a.z, 32); a.w += __shfl_xor(a.w, 32);
            if (half == 0) {
                float4 bv = ((const float4*)bias)[l32];
                float4 o;
                o.x = a.x * inv + bv.x; o.x = o.x > 0.f ? o.x : 0.01f * o.x;
                o.y = a.y * inv + bv.y; o.y = o.y > 0.f ? o.y : 0.01f * o.y;
                o.z = a.z * inv + bv.z; o.z = o.z > 0.f ? o.z : 0.01f * o.z;
                o.w = a.w * inv + bv.w; o.w = o.w > 0.f ? o.w : 0.01f * o.w;
                ((float4*)out)[(size_t)wid * 32 + l32] = o;
            }
        } else {
            // cout==64: 4 edges/iter x 16 lanes x float4
            int q = lane >> 4, l16 = lane & 15;
            const float4* h4 = (const float4*)h;
            float4 a = make_float4(0.f, 0.f, 0.f, 0.f);
#pragma unroll 4
            for (int e = q; e < ne; e += 4) {
                float exv = ex_s[wslot][e];
                int src = src_s[wslot][e];
                float4 hv = h4[(size_t)src * 16 + l16];
                a.x += exv * hv.x; a.y += exv * hv.y;
                a.z += exv * hv.z; a.w += exv * hv.w;
            }
            a.x += __shfl_xor(a.x, 16); a.y += __shfl_xor(a.y, 16);
            a.z += __shfl_xor(a.z, 16); a.w += __shfl_xor(a.w, 16);
            a.x += __shfl_xor(a.x, 32); a.y += __shfl_xor(a.y, 32);
            a.z += __shfl_xor(a.z, 32); a.w += __shfl_xor(a.w, 32);
            if (q == 0) {
                float4 bv = ((const float4*)bias)[l16];
                float4 o;
                o.x = a.x * inv + bv.x; o.x = o.x > 0.f ? o.x : 0.01f * o.x;
                o.y = a.y * inv + bv.y; o.y = o.y > 0.f ? o.y : 0.01f * o.y;
                o.z = a.z * inv + bv.z; o.z = o.z > 0.f ? o.z : 0.01f * o.z;
                o.w = a.w * inv + bv.w; o.w = o.w > 0.f ? o.w : 0.01f * o.w;
                ((float4*)out)[(size_t)wid * 16 + l16] = o;
            }
        }
        return;
    }

    // ---- fallback (degree > MAXE): original serial path, never hit for this graph ----
    float m = -1e30f;
    for (int e = lane; e < ne; e += 64) {
        int src = esrc[lo + e];
        float lg = s[src] + di + ce * ewt[lo + e];
        lg = lg > 0.f ? lg : 0.2f * lg;
        m = fmaxf(m, lg);
    }
    for (int o = 32; o; o >>= 1) m = fmaxf(m, __shfl_xor(m, o));
    float den = 0.f;
    int c0 = lane, c1 = lane + 64;
    float a0 = 0.f, a1 = 0.f;
    for (int e = 0; e < ne; e++) {
        int src = esrc[lo + e];
        float lg = s[src] + di + ce * ewt[lo + e];
        lg = lg > 0.f ? lg : 0.2f * lg;
        float ex = __expf(lg - m);
        den += ex;
        const float* hr = &h[(size_t)src * cout];
        a0 += ex * hr[c0];
        if (cout > 64) a1 += ex * hr[c1];
    }
    float inv = 1.0f / (den + 1e-16f);
    float o0 = a0 * inv + bias[c0];
    o0 = o0 > 0.f ? o0 : 0.01f * o0;
    out[(size_t)wid * cout + c0] = o0;
    if (cout > 64) {
        float o1 = a1 * inv + bias[c1];
        o1 = o1 > 0.f ? o1 : 0.01f * o1;
        out[(size_t)wid * cout + c1] = o1;
    }
}

extern "C" void kernel_launch(void* const* d_in, const int* in_sizes, int n_in,
                              void* d_out, int out_size, void* d_ws, size_t ws_size,
                              hipStream_t stream) {
    const int N = NNODES, E = NEDGES, EF = NEDGES + NNODES;

    const float* x = (const float*)d_in[0];
    const int* ei = (const int*)d_in[1];   // int32 on device
    const float* ew = (const float*)d_in[2];
    const float* W1 = (const float*)d_in[3];
    const float* as1 = (const float*)d_in[4];
    const float* ad1 = (const float*)d_in[5];
    const float* We1 = (const float*)d_in[6];
    const float* ae1 = (const float*)d_in[7];
    const float* b1 = (const float*)d_in[8];
    const float* W2 = (const float*)d_in[9];
    const float* as2 = (const float*)d_in[10];
    const float* ad2 = (const float*)d_in[11];
    const float* We2 = (const float*)d_in[12];
    const float* ae2 = (const float*)d_in[13];
    const float* b2 = (const float*)d_in[14];
    const float* W3 = (const float*)d_in[15];
    const float* as3 = (const float*)d_in[16];
    const float* ad3 = (const float*)d_in[17];
    const float* We3 = (const float*)d_in[18];
    const float* ae3 = (const float*)d_in[19];
    const float* b3 = (const float*)d_in[20];
    float* out = (float*)d_out;

    // workspace layout
    float* act = (float*)d_ws;                      // N*128
    float* h = act + (size_t)N * 128;               // N*128
    float* sd = h + (size_t)N * 128;                // 6*N (s1,d1,s2,d2,s3,d3)
    int* deg = (int*)(sd + (size_t)6 * N);          // N   }
    float* sum_ew = (float*)(deg + N);              // N   } zeroed together with sd
    int* fill = (int*)(sum_ew + N);                 // N   }
    int* row_start = fill + N;                      // N+1
    int* blkSums = row_start + (N + 1);             // 128
    int* esrc = blkSums + 128;                      // EF
    float* ewt = (float*)(esrc + EF);               // EF
    float* ce = ewt + EF;                           // 3

    // ---- zero sd (6N floats) + deg/sum_ew/fill (3N) in one launch ----
    zero_i32<<<(9 * N + 255) / 256, 256, 0, stream>>>((int*)sd, 9 * N);
    // ---- build CSR by dst (with self loops, fill_value='mean') ----
    count_k<<<(E + 255) / 256, 256, 0, stream>>>(ei, ew, deg, sum_ew, E, N);
    int nblkA = (N + 1023) / 1024;  // 98
    scanA<<<nblkA, 256, 0, stream>>>(deg, row_start, blkSums, N);
    scanB<<<1, 128, 0, stream>>>(blkSums, nblkA);
    scanC<<<(N + 255) / 256, 256, 0, stream>>>(row_start, blkSums, N);
    scatter_k<<<(E + N + 255) / 256, 256, 0, stream>>>(ei, ew, row_start, fill, deg,
                                                       sum_ew, esrc, ewt, E, N);
    ce_k<<<3, 64, 0, stream>>>(We1, ae1, We2, ae2, We3, ae3, ce);

    // ---- layer 1: 256 -> 128 ----
    {
        int cin = 256, cout = 128;
        dim3 grid((N + 63) / 64, cout / 64);
        gemm_k<<<grid, 256, 0, stream>>>(x, W1, h, as1, ad1, sd + 0 * N, sd + 1 * N,
                                         N, cin, cout);
        agg_k<<<(N + 3) / 4, 256, 0, stream>>>(esrc, ewt, row_start, h, sd + 0 * N,
                                               sd + 1 * N, ce + 0, b1, act, N, cout);
    }
    // ---- layer 2: 128 -> 128 ----
    {
        int cin = 128, cout = 128;
        dim3 grid((N + 63) / 64, cout / 64);
        gemm_k<<<grid, 256, 0, stream>>>(act, W2, h, as2, ad2, sd + 2 * N, sd + 3 * N,
                                         N, cin, cout);
        agg_k<<<(N + 3) / 4, 256, 0, stream>>>(esrc, ewt, row_start, h, sd + 2 * N,
                                               sd + 3 * N, ce + 1, b2, act, N, cout);
    }
    // ---- layer 3: 128 -> 64 ----
    {
        int cin = 128, cout = 64;
        dim3 grid((N + 63) / 64, cout / 64);
        gemm_k<<<grid, 256, 0, stream>>>(act, W3, h, as3, ad3, sd + 4 * N, sd + 5 * N,
                                         N, cin, cout);
        agg_k<<<(N + 3) / 4, 256, 0, stream>>>(esrc, ewt, row_start, h, sd + 4 * N,
                                               sd + 5 * N, ce + 2, b3, out, N, cout);
    }
}

// Round 4
// 679.306 us; speedup vs baseline: 1.9283x; 1.2537x over previous
//
#include <hip/hip_runtime.h>
#include <hip/hip_bf16.h>
#include <math.h>

#define NNODES 100000
#define NEDGES 1600000
#define MAXE 128

typedef short bfrag8 __attribute__((ext_vector_type(8)));  // 8 bf16 (4 VGPRs)
typedef float facc4 __attribute__((ext_vector_type(4)));   // 4 fp32 acc

__device__ __forceinline__ unsigned short f2bf(float f) {
    unsigned u = __float_as_uint(f);
    unsigned r = u + 0x7fffu + ((u >> 16) & 1u);  // round-to-nearest-even
    return (unsigned short)(r >> 16);
}

// ---------------- utility ----------------
__global__ void zero_i32(int* p, int n) {
    int i = blockIdx.x * blockDim.x + threadIdx.x;
    if (i < n) p[i] = 0;
}

// count in-degree and sum of edge weights per dst
__global__ void count_k(const int* __restrict__ ei, const float* __restrict__ ew,
                        int* __restrict__ deg, float* __restrict__ sum_ew, int E, int n) {
    int e = blockIdx.x * blockDim.x + threadIdx.x;
    if (e >= E) return;
    unsigned dstv = (unsigned)ei[E + e];
    if (dstv < (unsigned)n) {
        atomicAdd(&deg[dstv], 1);
        atomicAdd(&sum_ew[dstv], ew[e]);
    }
}

// ---------------- scan (counts = deg+1, for self loop) ----------------
__global__ void scanA(const int* __restrict__ deg, int* __restrict__ row_start,
                      int* __restrict__ blkSums, int n) {
    __shared__ int sdata[256];
    int tid = threadIdx.x;
    int base = blockIdx.x * 1024 + tid * 4;
    int v[4];
    int sum = 0;
#pragma unroll
    for (int j = 0; j < 4; j++) {
        int idx = base + j;
        int c = (idx < n) ? (deg[idx] + 1) : 0;
        sum += c;
        v[j] = sum;
    }
    sdata[tid] = sum;
    __syncthreads();
    for (int off = 1; off < 256; off <<= 1) {
        int t = (tid >= off) ? sdata[tid - off] : 0;
        __syncthreads();
        sdata[tid] += t;
        __syncthreads();
    }
    int excl = sdata[tid] - sum;
#pragma unroll
    for (int j = 0; j < 4; j++) {
        int idx = base + j;
        if (idx < n) row_start[idx + 1] = excl + v[j];
    }
    if (tid == 255) blkSums[blockIdx.x] = sdata[255];
}

__global__ void scanB(int* __restrict__ blkSums, int nblk) {
    __shared__ int sdata[128];
    int tid = threadIdx.x;
    int v = (tid < nblk) ? blkSums[tid] : 0;
    sdata[tid] = v;
    __syncthreads();
    for (int off = 1; off < 128; off <<= 1) {
        int t = (tid >= off) ? sdata[tid - off] : 0;
        __syncthreads();
        sdata[tid] += t;
        __syncthreads();
    }
    if (tid < nblk) blkSums[tid] = sdata[tid] - v;
}

__global__ void scanC(int* __restrict__ row_start, const int* __restrict__ blkSums, int n) {
    int idx = blockIdx.x * blockDim.x + threadIdx.x;
    if (idx < n) row_start[idx + 1] += blkSums[idx >> 10];
    if (idx == 0) row_start[0] = 0;
}

// ---------------- scatter edges into CSR (by dst) ----------------
__global__ void scatter_k(const int* __restrict__ ei, const float* __restrict__ ew,
                          const int* __restrict__ row_start, int* __restrict__ fill,
                          const int* __restrict__ deg, const float* __restrict__ sum_ew,
                          int* __restrict__ esrc, float* __restrict__ ewt, int E, int n) {
    int e = blockIdx.x * blockDim.x + threadIdx.x;
    if (e < E) {
        unsigned srcv = (unsigned)ei[e];
        unsigned dstv = (unsigned)ei[E + e];
        if (srcv < (unsigned)n && dstv < (unsigned)n) {
            int pos = row_start[dstv] + atomicAdd(&fill[dstv], 1);
            esrc[pos] = (int)srcv;
            ewt[pos] = ew[e];
        }
    } else if (e < E + n) {
        int i = e - E;
        int dg = deg[i];
        float w = sum_ew[i] / (float)(dg > 1 ? dg : 1);
        int pos = row_start[i] + atomicAdd(&fill[i], 1);
        esrc[pos] = i;
        ewt[pos] = w;
    }
}

// ---------------- ce[l] = dot(We_l, ae_l) ----------------
__global__ void ce_k(const float* We1, const float* ae1,
                     const float* We2, const float* ae2,
                     const float* We3, const float* ae3, float* ce) {
    const float* W;
    const float* a;
    int cout;
    if (blockIdx.x == 0) { W = We1; a = ae1; cout = 128; }
    else if (blockIdx.x == 1) { W = We2; a = ae2; cout = 128; }
    else { W = We3; a = ae3; cout = 64; }
    int lane = threadIdx.x;
    float v = 0.f;
    for (int c = lane; c < cout; c += 64) v += W[c] * a[c];
    for (int o = 32; o; o >>= 1) v += __shfl_xor(v, o);
    if (lane == 0) ce[blockIdx.x] = v;
}

// ---------------- convert W [cin][cout] fp32 -> Wt [cout][cin] bf16 ----------------
__global__ void wt_k(const float* __restrict__ W1, const float* __restrict__ W2,
                     const float* __restrict__ W3, unsigned short* __restrict__ wt1,
                     unsigned short* __restrict__ wt2, unsigned short* __restrict__ wt3) {
    int i = blockIdx.x * 256 + threadIdx.x;
    if (i < 32768) {            // layer1: [256][128] -> [128][256]
        int k = i >> 7, nn = i & 127;
        wt1[nn * 256 + k] = f2bf(W1[i]);
        return;
    }
    i -= 32768;
    if (i < 16384) {            // layer2: [128][128]
        int k = i >> 7, nn = i & 127;
        wt2[nn * 128 + k] = f2bf(W2[i]);
        return;
    }
    i -= 16384;
    if (i < 8192) {             // layer3: [128][64] -> [64][128]
        int k = i >> 6, nn = i & 63;
        wt3[nn * 128 + k] = f2bf(W3[i]);
    }
}

// ---------------- MFMA GEMM: H = X @ W, fused s/d partial dots ----------------
// 64x64 tile, 4 waves; wave wv owns rows [wv*16, wv*16+16) x 64 cols.
// A (X tile) cast fp32->bf16 at staging; B from pre-transposed bf16 Wt[cout][cin].
// LDS rows padded to 40 bf16 (80 B) -> ds_read_b128 spreads over all 8 16B slots.
__global__ __launch_bounds__(256) void gemm_mfma(
    const float* __restrict__ X, const unsigned short* __restrict__ Wt,
    float* __restrict__ H, const float* __restrict__ as_,
    const float* __restrict__ ad_, float* __restrict__ s, float* __restrict__ d,
    int nrows, int cin, int cout) {
    __shared__ __align__(16) unsigned short lA[64 * 40];
    __shared__ __align__(16) unsigned short lB[64 * 40];
    int t = threadIdx.x;
    int wv = t >> 6, lane = t & 63;
    int lr = lane & 15, lg = lane >> 4;      // lr: A-row / B-col / C-col; lg: k-group / C-row-group
    int row0 = blockIdx.x * 64, col0 = blockIdx.y * 64;
    int sr = t >> 2, sc = (t & 3) * 8;       // staging: row 0..63, k-chunk 0/8/16/24

    facc4 acc[4] = {};

    const float* xrow = X + (size_t)(row0 + sr) * cin;
    bool rowok = (row0 + sr) < nrows;
    const unsigned short* wrow = Wt + (size_t)(col0 + sr) * cin;

    for (int k0 = 0; k0 < cin; k0 += 32) {
        union { bfrag8 v; unsigned short u[8]; } pa;
        if (rowok) {
            float4 v0 = *(const float4*)&xrow[k0 + sc];
            float4 v1 = *(const float4*)&xrow[k0 + sc + 4];
            pa.u[0] = f2bf(v0.x); pa.u[1] = f2bf(v0.y);
            pa.u[2] = f2bf(v0.z); pa.u[3] = f2bf(v0.w);
            pa.u[4] = f2bf(v1.x); pa.u[5] = f2bf(v1.y);
            pa.u[6] = f2bf(v1.z); pa.u[7] = f2bf(v1.w);
        } else {
#pragma unroll
            for (int j = 0; j < 8; j++) pa.u[j] = 0;
        }
        *(bfrag8*)&lA[sr * 40 + sc] = pa.v;
        *(bfrag8*)&lB[sr * 40 + sc] = *(const bfrag8*)&wrow[k0 + sc];
        __syncthreads();
        bfrag8 a = *(const bfrag8*)&lA[(wv * 16 + lr) * 40 + lg * 8];
#pragma unroll
        for (int n0 = 0; n0 < 4; n0++) {
            bfrag8 b = *(const bfrag8*)&lB[(n0 * 16 + lr) * 40 + lg * 8];
            acc[n0] = __builtin_amdgcn_mfma_f32_16x16x32_bf16(a, b, acc[n0], 0, 0, 0);
        }
        __syncthreads();
    }
    // epilogue: store H (fp32), fused partial dots vs as_/ad_ on fp32 accumulators
#pragma unroll
    for (int r = 0; r < 4; r++) {
        int row = row0 + wv * 16 + lg * 4 + r;
        if (row >= nrows) continue;
        float ps = 0.f, pd = 0.f;
#pragma unroll
        for (int n0 = 0; n0 < 4; n0++) {
            int col = col0 + n0 * 16 + lr;
            float v = acc[n0][r];
            H[(size_t)row * cout + col] = v;
            ps += v * as_[col];
            pd += v * ad_[col];
        }
        for (int o = 8; o; o >>= 1) {
            ps += __shfl_xor(ps, o);
            pd += __shfl_xor(pd, o);
        }
        if (lr == 0) {
            atomicAdd(&s[row], ps);
            atomicAdd(&d[row], pd);
        }
    }
}

// ---------------- attention + aggregation: one wave per dst node ----------------
__global__ __launch_bounds__(256) void agg_k(
    const int* __restrict__ esrc, const float* __restrict__ ewt,
    const int* __restrict__ row_start, const float* __restrict__ h,
    const float* __restrict__ s, const float* __restrict__ d,
    const float* __restrict__ ce_ptr, const float* __restrict__ bias,
    float* __restrict__ out, int n, int cout) {
    __shared__ float ex_s[4][MAXE];
    __shared__ int src_s[4][MAXE];
    int wslot = threadIdx.x >> 6;
    int wid = (blockIdx.x * blockDim.x + threadIdx.x) >> 6;
    int lane = threadIdx.x & 63;
    if (wid >= n) return;
    int lo = row_start[wid], ne = row_start[wid + 1] - lo;
    float ce = *ce_ptr;
    float di = d[wid];

    if (ne <= MAXE) {
        float m = -1e30f;
        for (int e = lane; e < ne; e += 64) {
            int src = esrc[lo + e];
            float lg = s[src] + di + ce * ewt[lo + e];
            lg = lg > 0.f ? lg : 0.2f * lg;
            src_s[wslot][e] = src;
            ex_s[wslot][e] = lg;
            m = fmaxf(m, lg);
        }
        for (int o = 32; o; o >>= 1) m = fmaxf(m, __shfl_xor(m, o));
        float den = 0.f;
        for (int e = lane; e < ne; e += 64) {
            float exv = __expf(ex_s[wslot][e] - m);
            ex_s[wslot][e] = exv;
            den += exv;
        }
        for (int o = 32; o; o >>= 1) den += __shfl_xor(den, o);
        float inv = 1.0f / (den + 1e-16f);

        if (cout == 128) {
            int half = lane >> 5, l32 = lane & 31;
            const float4* h4 = (const float4*)h;
            float4 a = make_float4(0.f, 0.f, 0.f, 0.f);
#pragma unroll 4
            for (int e = half; e < ne; e += 2) {
                float exv = ex_s[wslot][e];
                int src = src_s[wslot][e];
                float4 hv = h4[(size_t)src * 32 + l32];
                a.x += exv * hv.x; a.y += exv * hv.y;
                a.z += exv * hv.z; a.w += exv * hv.w;
            }
            a.x += __shfl_xor(a.x, 32); a.y += __shfl_xor(a.y, 32);
            a.z += __shfl_xor(a.z, 32); a.w += __shfl_xor(a.w, 32);
            if (half == 0) {
                float4 bv = ((const float4*)bias)[l32];
                float4 o;
                o.x = a.x * inv + bv.x; o.x = o.x > 0.f ? o.x : 0.01f * o.x;
                o.y = a.y * inv + bv.y; o.y = o.y > 0.f ? o.y : 0.01f * o.y;
                o.z = a.z * inv + bv.z; o.z = o.z > 0.f ? o.z : 0.01f * o.z;
                o.w = a.w * inv + bv.w; o.w = o.w > 0.f ? o.w : 0.01f * o.w;
                ((float4*)out)[(size_t)wid * 32 + l32] = o;
            }
        } else {
            int q = lane >> 4, l16 = lane & 15;
            const float4* h4 = (const float4*)h;
            float4 a = make_float4(0.f, 0.f, 0.f, 0.f);
#pragma unroll 4
            for (int e = q; e < ne; e += 4) {
                float exv = ex_s[wslot][e];
                int src = src_s[wslot][e];
                float4 hv = h4[(size_t)src * 16 + l16];
                a.x += exv * hv.x; a.y += exv * hv.y;
                a.z += exv * hv.z; a.w += exv * hv.w;
            }
            a.x += __shfl_xor(a.x, 16); a.y += __shfl_xor(a.y, 16);
            a.z += __shfl_xor(a.z, 16); a.w += __shfl_xor(a.w, 16);
            a.x += __shfl_xor(a.x, 32); a.y += __shfl_xor(a.y, 32);
            a.z += __shfl_xor(a.z, 32); a.w += __shfl_xor(a.w, 32);
            if (q == 0) {
                float4 bv = ((const float4*)bias)[l16];
                float4 o;
                o.x = a.x * inv + bv.x; o.x = o.x > 0.f ? o.x : 0.01f * o.x;
                o.y = a.y * inv + bv.y; o.y = o.y > 0.f ? o.y : 0.01f * o.y;
                o.z = a.z * inv + bv.z; o.z = o.z > 0.f ? o.z : 0.01f * o.z;
                o.w = a.w * inv + bv.w; o.w = o.w > 0.f ? o.w : 0.01f * o.w;
                ((float4*)out)[(size_t)wid * 16 + l16] = o;
            }
        }
        return;
    }

    // ---- fallback (degree > MAXE): serial path, never hit for this graph ----
    float m = -1e30f;
    for (int e = lane; e < ne; e += 64) {
        int src = esrc[lo + e];
        float lg = s[src] + di + ce * ewt[lo + e];
        lg = lg > 0.f ? lg : 0.2f * lg;
        m = fmaxf(m, lg);
    }
    for (int o = 32; o; o >>= 1) m = fmaxf(m, __shfl_xor(m, o));
    float den = 0.f;
    int c0 = lane, c1 = lane + 64;
    float a0 = 0.f, a1 = 0.f;
    for (int e = 0; e < ne; e++) {
        int src = esrc[lo + e];
        float lg = s[src] + di + ce * ewt[lo + e];
        lg = lg > 0.f ? lg : 0.2f * lg;
        float ex = __expf(lg - m);
        den += ex;
        const float* hr = &h[(size_t)src * cout];
        a0 += ex * hr[c0];
        if (cout > 64) a1 += ex * hr[c1];
    }
    float inv = 1.0f / (den + 1e-16f);
    float o0 = a0 * inv + bias[c0];
    o0 = o0 > 0.f ? o0 : 0.01f * o0;
    out[(size_t)wid * cout + c0] = o0;
    if (cout > 64) {
        float o1 = a1 * inv + bias[c1];
        o1 = o1 > 0.f ? o1 : 0.01f * o1;
        out[(size_t)wid * cout + c1] = o1;
    }
}

extern "C" void kernel_launch(void* const* d_in, const int* in_sizes, int n_in,
                              void* d_out, int out_size, void* d_ws, size_t ws_size,
                              hipStream_t stream) {
    const int N = NNODES, E = NEDGES, EF = NEDGES + NNODES;

    const float* x = (const float*)d_in[0];
    const int* ei = (const int*)d_in[1];   // int32 on device
    const float* ew = (const float*)d_in[2];
    const float* W1 = (const float*)d_in[3];
    const float* as1 = (const float*)d_in[4];
    const float* ad1 = (const float*)d_in[5];
    const float* We1 = (const float*)d_in[6];
    const float* ae1 = (const float*)d_in[7];
    const float* b1 = (const float*)d_in[8];
    const float* W2 = (const float*)d_in[9];
    const float* as2 = (const float*)d_in[10];
    const float* ad2 = (const float*)d_in[11];
    const float* We2 = (const float*)d_in[12];
    const float* ae2 = (const float*)d_in[13];
    const float* b2 = (const float*)d_in[14];
    const float* W3 = (const float*)d_in[15];
    const float* as3 = (const float*)d_in[16];
    const float* ad3 = (const float*)d_in[17];
    const float* We3 = (const float*)d_in[18];
    const float* ae3 = (const float*)d_in[19];
    const float* b3 = (const float*)d_in[20];
    float* out = (float*)d_out;

    // workspace layout
    float* act = (float*)d_ws;                      // N*128
    float* h = act + (size_t)N * 128;               // N*128
    float* sd = h + (size_t)N * 128;                // 6*N (s1,d1,s2,d2,s3,d3)
    int* deg = (int*)(sd + (size_t)6 * N);          // N   }
    float* sum_ew = (float*)(deg + N);              // N   } zeroed together with sd
    int* fill = (int*)(sum_ew + N);                 // N   }
    int* row_start = fill + N;                      // N+1
    int* blkSums = row_start + (N + 1);             // 128
    int* esrc = blkSums + 128;                      // EF
    float* ewt = (float*)(esrc + EF);               // EF
    float* ce = ewt + EF;                           // 3
    unsigned short* wt1 = (unsigned short*)(ce + 3);// 32768 bf16
    unsigned short* wt2 = wt1 + 32768;              // 16384 bf16
    unsigned short* wt3 = wt2 + 16384;              // 8192 bf16

    // ---- zero sd (6N) + deg/sum_ew/fill (3N) ----
    zero_i32<<<(9 * N + 255) / 256, 256, 0, stream>>>((int*)sd, 9 * N);
    // ---- build CSR by dst (self loops, fill_value='mean') ----
    count_k<<<(E + 255) / 256, 256, 0, stream>>>(ei, ew, deg, sum_ew, E, N);
    int nblkA = (N + 1023) / 1024;  // 98
    scanA<<<nblkA, 256, 0, stream>>>(deg, row_start, blkSums, N);
    scanB<<<1, 128, 0, stream>>>(blkSums, nblkA);
    scanC<<<(N + 255) / 256, 256, 0, stream>>>(row_start, blkSums, N);
    scatter_k<<<(E + N + 255) / 256, 256, 0, stream>>>(ei, ew, row_start, fill, deg,
                                                       sum_ew, esrc, ewt, E, N);
    ce_k<<<3, 64, 0, stream>>>(We1, ae1, We2, ae2, We3, ae3, ce);
    wt_k<<<(32768 + 16384 + 8192) / 256, 256, 0, stream>>>(W1, W2, W3, wt1, wt2, wt3);

    // ---- layer 1: 256 -> 128 ----
    {
        int cin = 256, cout = 128;
        dim3 grid((N + 63) / 64, cout / 64);
        gemm_mfma<<<grid, 256, 0, stream>>>(x, wt1, h, as1, ad1, sd + 0 * N, sd + 1 * N,
                                            N, cin, cout);
        agg_k<<<(N + 3) / 4, 256, 0, stream>>>(esrc, ewt, row_start, h, sd + 0 * N,
                                               sd + 1 * N, ce + 0, b1, act, N, cout);
    }
    // ---- layer 2: 128 -> 128 ----
    {
        int cin = 128, cout = 128;
        dim3 grid((N + 63) / 64, cout / 64);
        gemm_mfma<<<grid, 256, 0, stream>>>(act, wt2, h, as2, ad2, sd + 2 * N, sd + 3 * N,
                                            N, cin, cout);
        agg_k<<<(N + 3) / 4, 256, 0, stream>>>(esrc, ewt, row_start, h, sd + 2 * N,
                                               sd + 3 * N, ce + 1, b2, act, N, cout);
    }
    // ---- layer 3: 128 -> 64 ----
    {
        int cin = 128, cout = 64;
        dim3 grid((N + 63) / 64, cout / 64);
        gemm_mfma<<<grid, 256, 0, stream>>>(act, wt3, h, as3, ad3, sd + 4 * N, sd + 5 * N,
                                            N, cin, cout);
        agg_k<<<(N + 3) / 4, 256, 0, stream>>>(esrc, ewt, row_start, h, sd + 4 * N,
                                               sd + 5 * N, ce + 2, b3, out, N, cout);
    }
}

// Round 5
// 630.780 us; speedup vs baseline: 2.0767x; 1.0769x over previous
//
#include <hip/hip_runtime.h>
#include <hip/hip_bf16.h>
#include <math.h>

#define NNODES 100000
#define NEDGES 1600000
#define MAXE 128

typedef short bfrag8 __attribute__((ext_vector_type(8)));  // 8 bf16 (4 VGPRs)
typedef float facc4 __attribute__((ext_vector_type(4)));   // 4 fp32 acc
typedef unsigned long long ull;

__device__ __forceinline__ unsigned short f2bf(float f) {
    unsigned u = __float_as_uint(f);
    unsigned r = u + 0x7fffu + ((u >> 16) & 1u);  // round-to-nearest-even
    return (unsigned short)(r >> 16);
}

// ---------------- utility ----------------
__global__ void zero_i32(int* p, int n) {
    int i = blockIdx.x * blockDim.x + threadIdx.x;
    if (i < n) p[i] = 0;
}

// one packed u64 atomic per edge: deg in bits [40,63], fixed-point sum(ew) in [0,40)
__global__ void count_k(const int* __restrict__ ei, const float* __restrict__ ew,
                        ull* __restrict__ packed, int E, int n) {
    int e = blockIdx.x * blockDim.x + threadIdx.x;
    if (e >= E) return;
    unsigned dstv = (unsigned)ei[E + e];
    if (dstv < (unsigned)n) {
        unsigned fx = __float2uint_rn(ew[e] * 16777216.0f);  // w * 2^24
        atomicAdd(&packed[dstv], (1ULL << 40) | (ull)fx);
    }
}

// ---------------- scan (counts = deg+1, for self loop) ----------------
__global__ void scanA(const ull* __restrict__ packed, int* __restrict__ row_start,
                      int* __restrict__ blkSums, int n) {
    __shared__ int sdata[256];
    int tid = threadIdx.x;
    int base = blockIdx.x * 1024 + tid * 4;
    int v[4];
    int sum = 0;
#pragma unroll
    for (int j = 0; j < 4; j++) {
        int idx = base + j;
        int c = (idx < n) ? ((int)(packed[idx] >> 40) + 1) : 0;
        sum += c;
        v[j] = sum;
    }
    sdata[tid] = sum;
    __syncthreads();
    for (int off = 1; off < 256; off <<= 1) {
        int t = (tid >= off) ? sdata[tid - off] : 0;
        __syncthreads();
        sdata[tid] += t;
        __syncthreads();
    }
    int excl = sdata[tid] - sum;
#pragma unroll
    for (int j = 0; j < 4; j++) {
        int idx = base + j;
        if (idx < n) row_start[idx + 1] = excl + v[j];
    }
    if (tid == 255) blkSums[blockIdx.x] = sdata[255];
}

__global__ void scanB(int* __restrict__ blkSums, int nblk) {
    __shared__ int sdata[128];
    int tid = threadIdx.x;
    int v = (tid < nblk) ? blkSums[tid] : 0;
    sdata[tid] = v;
    __syncthreads();
    for (int off = 1; off < 128; off <<= 1) {
        int t = (tid >= off) ? sdata[tid - off] : 0;
        __syncthreads();
        sdata[tid] += t;
        __syncthreads();
    }
    if (tid < nblk) blkSums[tid] = sdata[tid] - v;
}

// finalize row_start; fillpos[i] = row_start[i] + 1 (edge slots start after self-loop slot)
__global__ void scanC(int* __restrict__ row_start, int* __restrict__ fillpos,
                      const int* __restrict__ blkSums, int n) {
    int idx = blockIdx.x * blockDim.x + threadIdx.x;
    if (idx < n) {
        int v = row_start[idx + 1] + blkSums[idx >> 10];
        row_start[idx + 1] = v;
        fillpos[idx + 1] = v + 1;
    }
    if (idx == 0) { row_start[0] = 0; fillpos[0] = 1; }
}

// ---------------- scatter edges into CSR (by dst); packed (src,w) int2 ----------------
__global__ void scatter_k(const int* __restrict__ ei, const float* __restrict__ ew,
                          const int* __restrict__ row_start, int* __restrict__ fillpos,
                          const ull* __restrict__ packed, int2* __restrict__ eswr,
                          int E, int n) {
    int e = blockIdx.x * blockDim.x + threadIdx.x;
    if (e < E) {
        unsigned srcv = (unsigned)ei[e];
        unsigned dstv = (unsigned)ei[E + e];
        if (srcv < (unsigned)n && dstv < (unsigned)n) {
            int pos = atomicAdd(&fillpos[dstv], 1);
            eswr[pos] = make_int2((int)srcv, __float_as_int(ew[e]));
        }
    } else if (e < E + n) {
        int i = e - E;
        ull p = packed[i];
        int dg = (int)(p >> 40);
        float sum = (float)(p & 0xFFFFFFFFFFULL) * (1.0f / 16777216.0f);
        float w = sum / (float)(dg > 1 ? dg : 1);
        eswr[row_start[i]] = make_int2(i, __float_as_int(w));  // self-loop at slot 0
    }
}

// ---------------- ce[l] = dot(We_l, ae_l) ----------------
__global__ void ce_k(const float* We1, const float* ae1,
                     const float* We2, const float* ae2,
                     const float* We3, const float* ae3, float* ce) {
    const float* W;
    const float* a;
    int cout;
    if (blockIdx.x == 0) { W = We1; a = ae1; cout = 128; }
    else if (blockIdx.x == 1) { W = We2; a = ae2; cout = 128; }
    else { W = We3; a = ae3; cout = 64; }
    int lane = threadIdx.x;
    float v = 0.f;
    for (int c = lane; c < cout; c += 64) v += W[c] * a[c];
    for (int o = 32; o; o >>= 1) v += __shfl_xor(v, o);
    if (lane == 0) ce[blockIdx.x] = v;
}

// ---------------- convert W [cin][cout] fp32 -> Wt [cout][cin] bf16 ----------------
__global__ void wt_k(const float* __restrict__ W1, const float* __restrict__ W2,
                     const float* __restrict__ W3, unsigned short* __restrict__ wt1,
                     unsigned short* __restrict__ wt2, unsigned short* __restrict__ wt3) {
    int i = blockIdx.x * 256 + threadIdx.x;
    if (i < 32768) {            // layer1: [256][128] -> [128][256]
        int k = i >> 7, nn = i & 127;
        wt1[nn * 256 + k] = f2bf(W1[i]);
        return;
    }
    i -= 32768;
    if (i < 16384) {            // layer2: [128][128]
        int k = i >> 7, nn = i & 127;
        wt2[nn * 128 + k] = f2bf(W2[i]);
        return;
    }
    i -= 16384;
    if (i < 8192) {             // layer3: [128][64] -> [64][128]
        int k = i >> 6, nn = i & 63;
        wt3[nn * 128 + k] = f2bf(W3[i]);
    }
}

// ---------------- MFMA GEMM: H = X @ W, fused s/d partial dots ----------------
__global__ __launch_bounds__(256) void gemm_mfma(
    const float* __restrict__ X, const unsigned short* __restrict__ Wt,
    float* __restrict__ H, const float* __restrict__ as_,
    const float* __restrict__ ad_, float* __restrict__ s, float* __restrict__ d,
    int nrows, int cin, int cout) {
    __shared__ __align__(16) unsigned short lA[64 * 40];
    __shared__ __align__(16) unsigned short lB[64 * 40];
    int t = threadIdx.x;
    int wv = t >> 6, lane = t & 63;
    int lr = lane & 15, lg = lane >> 4;
    int row0 = blockIdx.x * 64, col0 = blockIdx.y * 64;
    int sr = t >> 2, sc = (t & 3) * 8;

    facc4 acc[4] = {};

    const float* xrow = X + (size_t)(row0 + sr) * cin;
    bool rowok = (row0 + sr) < nrows;
    const unsigned short* wrow = Wt + (size_t)(col0 + sr) * cin;

    for (int k0 = 0; k0 < cin; k0 += 32) {
        union { bfrag8 v; unsigned short u[8]; } pa;
        if (rowok) {
            float4 v0 = *(const float4*)&xrow[k0 + sc];
            float4 v1 = *(const float4*)&xrow[k0 + sc + 4];
            pa.u[0] = f2bf(v0.x); pa.u[1] = f2bf(v0.y);
            pa.u[2] = f2bf(v0.z); pa.u[3] = f2bf(v0.w);
            pa.u[4] = f2bf(v1.x); pa.u[5] = f2bf(v1.y);
            pa.u[6] = f2bf(v1.z); pa.u[7] = f2bf(v1.w);
        } else {
#pragma unroll
            for (int j = 0; j < 8; j++) pa.u[j] = 0;
        }
        *(bfrag8*)&lA[sr * 40 + sc] = pa.v;
        *(bfrag8*)&lB[sr * 40 + sc] = *(const bfrag8*)&wrow[k0 + sc];
        __syncthreads();
        bfrag8 a = *(const bfrag8*)&lA[(wv * 16 + lr) * 40 + lg * 8];
#pragma unroll
        for (int n0 = 0; n0 < 4; n0++) {
            bfrag8 b = *(const bfrag8*)&lB[(n0 * 16 + lr) * 40 + lg * 8];
            acc[n0] = __builtin_amdgcn_mfma_f32_16x16x32_bf16(a, b, acc[n0], 0, 0, 0);
        }
        __syncthreads();
    }
#pragma unroll
    for (int r = 0; r < 4; r++) {
        int row = row0 + wv * 16 + lg * 4 + r;
        if (row >= nrows) continue;
        float ps = 0.f, pd = 0.f;
#pragma unroll
        for (int n0 = 0; n0 < 4; n0++) {
            int col = col0 + n0 * 16 + lr;
            float v = acc[n0][r];
            H[(size_t)row * cout + col] = v;
            ps += v * as_[col];
            pd += v * ad_[col];
        }
        for (int o = 8; o; o >>= 1) {
            ps += __shfl_xor(ps, o);
            pd += __shfl_xor(pd, o);
        }
        if (lr == 0) {
            atomicAdd(&s[row], ps);
            atomicAdd(&d[row], pd);
        }
    }
}

// ---------------- attention + aggregation: one wave per dst node ----------------
__global__ __launch_bounds__(256) void agg_k(
    const int2* __restrict__ eswr, const int* __restrict__ row_start,
    const float* __restrict__ h, const float* __restrict__ s,
    const float* __restrict__ d, const float* __restrict__ ce_ptr,
    const float* __restrict__ bias, float* __restrict__ out, int n, int cout) {
    __shared__ float ex_s[4][MAXE];
    __shared__ int src_s[4][MAXE];
    int wslot = threadIdx.x >> 6;
    int wid = (blockIdx.x * blockDim.x + threadIdx.x) >> 6;
    int lane = threadIdx.x & 63;
    if (wid >= n) return;
    int lo = row_start[wid], ne = row_start[wid + 1] - lo;
    float ce = *ce_ptr;
    float di = d[wid];

    if (ne <= MAXE) {
        float m = -1e30f;
        for (int e = lane; e < ne; e += 64) {
            int2 ev = eswr[lo + e];
            float lg = s[ev.x] + di + ce * __int_as_float(ev.y);
            lg = lg > 0.f ? lg : 0.2f * lg;
            src_s[wslot][e] = ev.x;
            ex_s[wslot][e] = lg;
            m = fmaxf(m, lg);
        }
        for (int o = 32; o; o >>= 1) m = fmaxf(m, __shfl_xor(m, o));
        float den = 0.f;
        for (int e = lane; e < ne; e += 64) {
            float exv = __expf(ex_s[wslot][e] - m);
            ex_s[wslot][e] = exv;
            den += exv;
        }
        for (int o = 32; o; o >>= 1) den += __shfl_xor(den, o);
        float inv = 1.0f / (den + 1e-16f);

        if (cout == 128) {
            int half = lane >> 5, l32 = lane & 31;
            const float4* h4 = (const float4*)h;
            float4 a = make_float4(0.f, 0.f, 0.f, 0.f);
#pragma unroll 4
            for (int e = half; e < ne; e += 2) {
                float exv = ex_s[wslot][e];
                int src = src_s[wslot][e];
                float4 hv = h4[(size_t)src * 32 + l32];
                a.x += exv * hv.x; a.y += exv * hv.y;
                a.z += exv * hv.z; a.w += exv * hv.w;
            }
            a.x += __shfl_xor(a.x, 32); a.y += __shfl_xor(a.y, 32);
            a.z += __shfl_xor(a.z, 32); a.w += __shfl_xor(a.w, 32);
            if (half == 0) {
                float4 bv = ((const float4*)bias)[l32];
                float4 o;
                o.x = a.x * inv + bv.x; o.x = o.x > 0.f ? o.x : 0.01f * o.x;
                o.y = a.y * inv + bv.y; o.y = o.y > 0.f ? o.y : 0.01f * o.y;
                o.z = a.z * inv + bv.z; o.z = o.z > 0.f ? o.z : 0.01f * o.z;
                o.w = a.w * inv + bv.w; o.w = o.w > 0.f ? o.w : 0.01f * o.w;
                ((float4*)out)[(size_t)wid * 32 + l32] = o;
            }
        } else {
            int q = lane >> 4, l16 = lane & 15;
            const float4* h4 = (const float4*)h;
            float4 a = make_float4(0.f, 0.f, 0.f, 0.f);
#pragma unroll 4
            for (int e = q; e < ne; e += 4) {
                float exv = ex_s[wslot][e];
                int src = src_s[wslot][e];
                float4 hv = h4[(size_t)src * 16 + l16];
                a.x += exv * hv.x; a.y += exv * hv.y;
                a.z += exv * hv.z; a.w += exv * hv.w;
            }
            a.x += __shfl_xor(a.x, 16); a.y += __shfl_xor(a.y, 16);
            a.z += __shfl_xor(a.z, 16); a.w += __shfl_xor(a.w, 16);
            a.x += __shfl_xor(a.x, 32); a.y += __shfl_xor(a.y, 32);
            a.z += __shfl_xor(a.z, 32); a.w += __shfl_xor(a.w, 32);
            if (q == 0) {
                float4 bv = ((const float4*)bias)[l16];
                float4 o;
                o.x = a.x * inv + bv.x; o.x = o.x > 0.f ? o.x : 0.01f * o.x;
                o.y = a.y * inv + bv.y; o.y = o.y > 0.f ? o.y : 0.01f * o.y;
                o.z = a.z * inv + bv.z; o.z = o.z > 0.f ? o.z : 0.01f * o.z;
                o.w = a.w * inv + bv.w; o.w = o.w > 0.f ? o.w : 0.01f * o.w;
                ((float4*)out)[(size_t)wid * 16 + l16] = o;
            }
        }
        return;
    }

    // ---- fallback (degree > MAXE): serial path, never hit for this graph ----
    float m = -1e30f;
    for (int e = lane; e < ne; e += 64) {
        int2 ev = eswr[lo + e];
        float lg = s[ev.x] + di + ce * __int_as_float(ev.y);
        lg = lg > 0.f ? lg : 0.2f * lg;
        m = fmaxf(m, lg);
    }
    for (int o = 32; o; o >>= 1) m = fmaxf(m, __shfl_xor(m, o));
    float den = 0.f;
    int c0 = lane, c1 = lane + 64;
    float a0 = 0.f, a1 = 0.f;
    for (int e = 0; e < ne; e++) {
        int2 ev = eswr[lo + e];
        float lg = s[ev.x] + di + ce * __int_as_float(ev.y);
        lg = lg > 0.f ? lg : 0.2f * lg;
        float ex = __expf(lg - m);
        den += ex;
        const float* hr = &h[(size_t)ev.x * cout];
        a0 += ex * hr[c0];
        if (cout > 64) a1 += ex * hr[c1];
    }
    float inv = 1.0f / (den + 1e-16f);
    float o0 = a0 * inv + bias[c0];
    o0 = o0 > 0.f ? o0 : 0.01f * o0;
    out[(size_t)wid * cout + c0] = o0;
    if (cout > 64) {
        float o1 = a1 * inv + bias[c1];
        o1 = o1 > 0.f ? o1 : 0.01f * o1;
        out[(size_t)wid * cout + c1] = o1;
    }
}

extern "C" void kernel_launch(void* const* d_in, const int* in_sizes, int n_in,
                              void* d_out, int out_size, void* d_ws, size_t ws_size,
                              hipStream_t stream) {
    const int N = NNODES, E = NEDGES, EF = NEDGES + NNODES;

    const float* x = (const float*)d_in[0];
    const int* ei = (const int*)d_in[1];   // int32 on device
    const float* ew = (const float*)d_in[2];
    const float* W1 = (const float*)d_in[3];
    const float* as1 = (const float*)d_in[4];
    const float* ad1 = (const float*)d_in[5];
    const float* We1 = (const float*)d_in[6];
    const float* ae1 = (const float*)d_in[7];
    const float* b1 = (const float*)d_in[8];
    const float* W2 = (const float*)d_in[9];
    const float* as2 = (const float*)d_in[10];
    const float* ad2 = (const float*)d_in[11];
    const float* We2 = (const float*)d_in[12];
    const float* ae2 = (const float*)d_in[13];
    const float* b2 = (const float*)d_in[14];
    const float* W3 = (const float*)d_in[15];
    const float* as3 = (const float*)d_in[16];
    const float* ad3 = (const float*)d_in[17];
    const float* We3 = (const float*)d_in[18];
    const float* ae3 = (const float*)d_in[19];
    const float* b3 = (const float*)d_in[20];
    float* out = (float*)d_out;

    // workspace layout
    float* act = (float*)d_ws;                       // N*128 f32
    float* h = act + (size_t)N * 128;                // N*128 f32
    float* sd = h + (size_t)N * 128;                 // 6N f32 (s1,d1,s2,d2,s3,d3)
    ull* packed = (ull*)(sd + (size_t)6 * N);        // N u64 (zeroed with sd)
    int* row_start = (int*)(packed + N);             // N+1
    int* fillpos = row_start + (N + 1);              // N+1
    int* blkSums = fillpos + (N + 1);                // 128 (+2 pad -> keep 8B align after)
    int2* eswr = (int2*)(blkSums + 130);             // EF int2
    float* ce = (float*)(eswr + EF);                 // 4 (padded for 16B align)
    unsigned short* wt1 = (unsigned short*)(ce + 4); // 32768 bf16
    unsigned short* wt2 = wt1 + 32768;               // 16384 bf16
    unsigned short* wt3 = wt2 + 16384;               // 8192 bf16

    // ---- zero sd (6N f32) + packed (N u64 = 2N i32) in one launch ----
    zero_i32<<<(8 * N + 255) / 256, 256, 0, stream>>>((int*)sd, 8 * N);
    // ---- build CSR by dst (self loops, fill_value='mean') ----
    count_k<<<(E + 255) / 256, 256, 0, stream>>>(ei, ew, packed, E, N);
    int nblkA = (N + 1023) / 1024;  // 98
    scanA<<<nblkA, 256, 0, stream>>>(packed, row_start, blkSums, N);
    scanB<<<1, 128, 0, stream>>>(blkSums, nblkA);
    scanC<<<(N + 255) / 256, 256, 0, stream>>>(row_start, fillpos, blkSums, N);
    scatter_k<<<(E + N + 255) / 256, 256, 0, stream>>>(ei, ew, row_start, fillpos,
                                                       packed, eswr, E, N);
    ce_k<<<3, 64, 0, stream>>>(We1, ae1, We2, ae2, We3, ae3, ce);
    wt_k<<<(32768 + 16384 + 8192) / 256, 256, 0, stream>>>(W1, W2, W3, wt1, wt2, wt3);

    // ---- layer 1: 256 -> 128 ----
    {
        int cin = 256, cout = 128;
        dim3 grid((N + 63) / 64, cout / 64);
        gemm_mfma<<<grid, 256, 0, stream>>>(x, wt1, h, as1, ad1, sd + 0 * N, sd + 1 * N,
                                            N, cin, cout);
        agg_k<<<(N + 3) / 4, 256, 0, stream>>>(eswr, row_start, h, sd + 0 * N,
                                               sd + 1 * N, ce + 0, b1, act, N, cout);
    }
    // ---- layer 2: 128 -> 128 ----
    {
        int cin = 128, cout = 128;
        dim3 grid((N + 63) / 64, cout / 64);
        gemm_mfma<<<grid, 256, 0, stream>>>(act, wt2, h, as2, ad2, sd + 2 * N, sd + 3 * N,
                                            N, cin, cout);
        agg_k<<<(N + 3) / 4, 256, 0, stream>>>(eswr, row_start, h, sd + 2 * N,
                                               sd + 3 * N, ce + 1, b2, act, N, cout);
    }
    // ---- layer 3: 128 -> 64 ----
    {
        int cin = 128, cout = 64;
        dim3 grid((N + 63) / 64, cout / 64);
        gemm_mfma<<<grid, 256, 0, stream>>>(act, wt3, h, as3, ad3, sd + 4 * N, sd + 5 * N,
                                            N, cin, cout);
        agg_k<<<(N + 3) / 4, 256, 0, stream>>>(eswr, row_start, h, sd + 4 * N,
                                               sd + 5 * N, ce + 2, b3, out, N, cout);
    }
}

// Round 6
// 450.440 us; speedup vs baseline: 2.9081x; 1.4004x over previous
//
#include <hip/hip_runtime.h>
#include <hip/hip_bf16.h>
#include <math.h>

#define NNODES 100000
#define NEDGES 1600000
#define MAXE 128
#define NSLICE 8
#define SL_SPAN ((NNODES + NSLICE - 1) / NSLICE)

typedef short bfrag8 __attribute__((ext_vector_type(8)));  // 8 bf16 (4 VGPRs)
typedef float facc4 __attribute__((ext_vector_type(4)));   // 4 fp32 acc
typedef unsigned long long ull;

__device__ __forceinline__ unsigned short f2bf(float f) {
    unsigned u = __float_as_uint(f);
    unsigned r = u + 0x7fffu + ((u >> 16) & 1u);  // round-to-nearest-even
    return (unsigned short)(r >> 16);
}
__device__ __forceinline__ float bf2f(unsigned short u) {
    return __uint_as_float((unsigned)u << 16);
}

// ---------------- utility ----------------
__global__ void zero_i32(int* p, int n) {
    int i = blockIdx.x * blockDim.x + threadIdx.x;
    if (i < n) p[i] = 0;
}

// one packed u64 atomic per edge: deg in [40,63], fixed-point sum(ew) in [0,40).
// returns old -> per-edge rank within its dst segment (stored coalesced).
__global__ void count_k(const int* __restrict__ ei, const float* __restrict__ ew,
                        ull* __restrict__ packed, unsigned short* __restrict__ rank16,
                        int E, int n) {
    int e = blockIdx.x * blockDim.x + threadIdx.x;
    if (e >= E) return;
    unsigned dstv = (unsigned)ei[E + e];
    unsigned short rk = 0;
    if (dstv < (unsigned)n) {
        unsigned fx = __float2uint_rn(ew[e] * 16777216.0f);  // w * 2^24
        ull old = atomicAdd(&packed[dstv], (1ULL << 40) | (ull)fx);
        unsigned r = (unsigned)(old >> 40);
        rk = (unsigned short)(r > 65535u ? 65535u : r);
    }
    rank16[e] = rk;
}

// ---------------- scan (counts = deg+1, for self loop) ----------------
__global__ void scanA(const ull* __restrict__ packed, int* __restrict__ row_start,
                      int* __restrict__ blkSums, int n) {
    __shared__ int sdata[256];
    int tid = threadIdx.x;
    int base = blockIdx.x * 1024 + tid * 4;
    int v[4];
    int sum = 0;
#pragma unroll
    for (int j = 0; j < 4; j++) {
        int idx = base + j;
        int c = (idx < n) ? ((int)(packed[idx] >> 40) + 1) : 0;
        sum += c;
        v[j] = sum;
    }
    sdata[tid] = sum;
    __syncthreads();
    for (int off = 1; off < 256; off <<= 1) {
        int t = (tid >= off) ? sdata[tid - off] : 0;
        __syncthreads();
        sdata[tid] += t;
        __syncthreads();
    }
    int excl = sdata[tid] - sum;
#pragma unroll
    for (int j = 0; j < 4; j++) {
        int idx = base + j;
        if (idx < n) row_start[idx + 1] = excl + v[j];
    }
    if (tid == 255) blkSums[blockIdx.x] = sdata[255];
}

__global__ void scanB(int* __restrict__ blkSums, int nblk) {
    __shared__ int sdata[128];
    int tid = threadIdx.x;
    int v = (tid < nblk) ? blkSums[tid] : 0;
    sdata[tid] = v;
    __syncthreads();
    for (int off = 1; off < 128; off <<= 1) {
        int t = (tid >= off) ? sdata[tid - off] : 0;
        __syncthreads();
        sdata[tid] += t;
        __syncthreads();
    }
    if (tid < nblk) blkSums[tid] = sdata[tid] - v;
}

__global__ void scanC(int* __restrict__ row_start, const int* __restrict__ blkSums, int n) {
    int idx = blockIdx.x * blockDim.x + threadIdx.x;
    if (idx < n) row_start[idx + 1] += blkSums[idx >> 10];
    if (idx == 0) row_start[0] = 0;
}

// ---------------- self-loop records: eswr[row_start[i]] = (i, mean_w) ----------------
__global__ void selfloop_k(const ull* __restrict__ packed, const int* __restrict__ row_start,
                           int2* __restrict__ eswr, int n) {
    int i = blockIdx.x * blockDim.x + threadIdx.x;
    if (i >= n) return;
    ull p = packed[i];
    int dg = (int)(p >> 40);
    float sum = (float)(p & 0xFFFFFFFFFFULL) * (1.0f / 16777216.0f);
    float w = sum / (float)(dg > 1 ? dg : 1);
    eswr[row_start[i]] = make_int2(i, __float_as_int(w));
}

// ---------------- dst-sliced scatter: slice s writes only dst in its node range ----
// slice = blockIdx & 7 (XCD-aligned under round-robin dispatch heuristic; correctness
// does not depend on placement). Each eswr line is assembled within one slice.
__global__ __launch_bounds__(256) void scatter_k(
    const int* __restrict__ ei, const float* __restrict__ ew,
    const unsigned short* __restrict__ rank16, const int* __restrict__ row_start,
    int2* __restrict__ eswr, int E, int n) {
    int slice = blockIdx.x & (NSLICE - 1);
    int r = blockIdx.x >> 3;
    int bps = gridDim.x >> 3;
    int lo = slice * SL_SPAN;
    int hi = lo + SL_SPAN;
    for (int base = r * 256; base < E; base += bps * 256) {
        int e = base + threadIdx.x;
        if (e >= E) continue;
        int dst = ei[E + e];
        if (dst >= lo && dst < hi && (unsigned)dst < (unsigned)n) {
            int src = ei[e];
            if ((unsigned)src < (unsigned)n) {
                int pos = row_start[dst] + 1 + (int)rank16[e];
                eswr[pos] = make_int2(src, __float_as_int(ew[e]));
            }
        }
    }
}

// ---------------- ce[l] = dot(We_l, ae_l) ----------------
__global__ void ce_k(const float* We1, const float* ae1,
                     const float* We2, const float* ae2,
                     const float* We3, const float* ae3, float* ce) {
    const float* W;
    const float* a;
    int cout;
    if (blockIdx.x == 0) { W = We1; a = ae1; cout = 128; }
    else if (blockIdx.x == 1) { W = We2; a = ae2; cout = 128; }
    else { W = We3; a = ae3; cout = 64; }
    int lane = threadIdx.x;
    float v = 0.f;
    for (int c = lane; c < cout; c += 64) v += W[c] * a[c];
    for (int o = 32; o; o >>= 1) v += __shfl_xor(v, o);
    if (lane == 0) ce[blockIdx.x] = v;
}

// ---------------- convert W [cin][cout] fp32 -> Wt [cout][cin] bf16 ----------------
__global__ void wt_k(const float* __restrict__ W1, const float* __restrict__ W2,
                     const float* __restrict__ W3, unsigned short* __restrict__ wt1,
                     unsigned short* __restrict__ wt2, unsigned short* __restrict__ wt3) {
    int i = blockIdx.x * 256 + threadIdx.x;
    if (i < 32768) {            // layer1: [256][128] -> [128][256]
        int k = i >> 7, nn = i & 127;
        wt1[nn * 256 + k] = f2bf(W1[i]);
        return;
    }
    i -= 32768;
    if (i < 16384) {            // layer2: [128][128]
        int k = i >> 7, nn = i & 127;
        wt2[nn * 128 + k] = f2bf(W2[i]);
        return;
    }
    i -= 16384;
    if (i < 8192) {             // layer3: [128][64] -> [64][128]
        int k = i >> 6, nn = i & 63;
        wt3[nn * 128 + k] = f2bf(W3[i]);
    }
}

// ---------------- MFMA GEMM: H(bf16) = X @ W, fused s/d partial dots ----------------
__global__ __launch_bounds__(256) void gemm_mfma(
    const float* __restrict__ X, const unsigned short* __restrict__ Wt,
    unsigned short* __restrict__ H, const float* __restrict__ as_,
    const float* __restrict__ ad_, float* __restrict__ s, float* __restrict__ d,
    int nrows, int cin, int cout) {
    __shared__ __align__(16) unsigned short lA[64 * 40];
    __shared__ __align__(16) unsigned short lB[64 * 40];
    int t = threadIdx.x;
    int wv = t >> 6, lane = t & 63;
    int lr = lane & 15, lg = lane >> 4;
    int row0 = blockIdx.x * 64, col0 = blockIdx.y * 64;
    int sr = t >> 2, sc = (t & 3) * 8;

    facc4 acc[4] = {};

    const float* xrow = X + (size_t)(row0 + sr) * cin;
    bool rowok = (row0 + sr) < nrows;
    const unsigned short* wrow = Wt + (size_t)(col0 + sr) * cin;

    for (int k0 = 0; k0 < cin; k0 += 32) {
        union { bfrag8 v; unsigned short u[8]; } pa;
        if (rowok) {
            float4 v0 = *(const float4*)&xrow[k0 + sc];
            float4 v1 = *(const float4*)&xrow[k0 + sc + 4];
            pa.u[0] = f2bf(v0.x); pa.u[1] = f2bf(v0.y);
            pa.u[2] = f2bf(v0.z); pa.u[3] = f2bf(v0.w);
            pa.u[4] = f2bf(v1.x); pa.u[5] = f2bf(v1.y);
            pa.u[6] = f2bf(v1.z); pa.u[7] = f2bf(v1.w);
        } else {
#pragma unroll
            for (int j = 0; j < 8; j++) pa.u[j] = 0;
        }
        *(bfrag8*)&lA[sr * 40 + sc] = pa.v;
        *(bfrag8*)&lB[sr * 40 + sc] = *(const bfrag8*)&wrow[k0 + sc];
        __syncthreads();
        bfrag8 a = *(const bfrag8*)&lA[(wv * 16 + lr) * 40 + lg * 8];
#pragma unroll
        for (int n0 = 0; n0 < 4; n0++) {
            bfrag8 b = *(const bfrag8*)&lB[(n0 * 16 + lr) * 40 + lg * 8];
            acc[n0] = __builtin_amdgcn_mfma_f32_16x16x32_bf16(a, b, acc[n0], 0, 0, 0);
        }
        __syncthreads();
    }
#pragma unroll
    for (int r = 0; r < 4; r++) {
        int row = row0 + wv * 16 + lg * 4 + r;
        if (row >= nrows) continue;
        float ps = 0.f, pd = 0.f;
#pragma unroll
        for (int n0 = 0; n0 < 4; n0++) {
            int col = col0 + n0 * 16 + lr;
            float v = acc[n0][r];
            H[(size_t)row * cout + col] = f2bf(v);
            ps += v * as_[col];
            pd += v * ad_[col];
        }
        for (int o = 8; o; o >>= 1) {
            ps += __shfl_xor(ps, o);
            pd += __shfl_xor(pd, o);
        }
        if (lr == 0) {
            atomicAdd(&s[row], ps);
            atomicAdd(&d[row], pd);
        }
    }
}

// ---------------- attention + aggregation: one wave per dst node (bf16 h) ----------
__global__ __launch_bounds__(256) void agg_k(
    const int2* __restrict__ eswr, const int* __restrict__ row_start,
    const unsigned short* __restrict__ h, const float* __restrict__ s,
    const float* __restrict__ d, const float* __restrict__ ce_ptr,
    const float* __restrict__ bias, float* __restrict__ out, int n, int cout) {
    __shared__ float ex_s[4][MAXE];
    __shared__ int src_s[4][MAXE];
    int wslot = threadIdx.x >> 6;
    int wid = (blockIdx.x * blockDim.x + threadIdx.x) >> 6;
    int lane = threadIdx.x & 63;
    if (wid >= n) return;
    int lo = row_start[wid], ne = row_start[wid + 1] - lo;
    float ce = *ce_ptr;
    float di = d[wid];

    if (ne <= MAXE) {
        float m = -1e30f;
        for (int e = lane; e < ne; e += 64) {
            int2 ev = eswr[lo + e];
            float lg = s[ev.x] + di + ce * __int_as_float(ev.y);
            lg = lg > 0.f ? lg : 0.2f * lg;
            src_s[wslot][e] = ev.x;
            ex_s[wslot][e] = lg;
            m = fmaxf(m, lg);
        }
        for (int o = 32; o; o >>= 1) m = fmaxf(m, __shfl_xor(m, o));
        float den = 0.f;
        for (int e = lane; e < ne; e += 64) {
            float exv = __expf(ex_s[wslot][e] - m);
            ex_s[wslot][e] = exv;
            den += exv;
        }
        for (int o = 32; o; o >>= 1) den += __shfl_xor(den, o);
        float inv = 1.0f / (den + 1e-16f);

        if (cout == 128) {
            // 2 edges/iter x 32 lanes x bf16x4 (8B/lane, full 256B row)
            int half = lane >> 5, l32 = lane & 31;
            const ushort4* h4 = (const ushort4*)h;
            float a0 = 0.f, a1 = 0.f, a2 = 0.f, a3 = 0.f;
#pragma unroll 4
            for (int e = half; e < ne; e += 2) {
                float exv = ex_s[wslot][e];
                int src = src_s[wslot][e];
                ushort4 hv = h4[(size_t)src * 32 + l32];
                a0 += exv * bf2f(hv.x); a1 += exv * bf2f(hv.y);
                a2 += exv * bf2f(hv.z); a3 += exv * bf2f(hv.w);
            }
            a0 += __shfl_xor(a0, 32); a1 += __shfl_xor(a1, 32);
            a2 += __shfl_xor(a2, 32); a3 += __shfl_xor(a3, 32);
            if (half == 0) {
                float4 bv = ((const float4*)bias)[l32];
                float4 o;
                o.x = a0 * inv + bv.x; o.x = o.x > 0.f ? o.x : 0.01f * o.x;
                o.y = a1 * inv + bv.y; o.y = o.y > 0.f ? o.y : 0.01f * o.y;
                o.z = a2 * inv + bv.z; o.z = o.z > 0.f ? o.z : 0.01f * o.z;
                o.w = a3 * inv + bv.w; o.w = o.w > 0.f ? o.w : 0.01f * o.w;
                ((float4*)out)[(size_t)wid * 32 + l32] = o;
            }
        } else {
            // cout==64: 4 edges/iter x 16 lanes x bf16x4
            int q = lane >> 4, l16 = lane & 15;
            const ushort4* h4 = (const ushort4*)h;
            float a0 = 0.f, a1 = 0.f, a2 = 0.f, a3 = 0.f;
#pragma unroll 4
            for (int e = q; e < ne; e += 4) {
                float exv = ex_s[wslot][e];
                int src = src_s[wslot][e];
                ushort4 hv = h4[(size_t)src * 16 + l16];
                a0 += exv * bf2f(hv.x); a1 += exv * bf2f(hv.y);
                a2 += exv * bf2f(hv.z); a3 += exv * bf2f(hv.w);
            }
            a0 += __shfl_xor(a0, 16); a1 += __shfl_xor(a1, 16);
            a2 += __shfl_xor(a2, 16); a3 += __shfl_xor(a3, 16);
            a0 += __shfl_xor(a0, 32); a1 += __shfl_xor(a1, 32);
            a2 += __shfl_xor(a2, 32); a3 += __shfl_xor(a3, 32);
            if (q == 0) {
                float4 bv = ((const float4*)bias)[l16];
                float4 o;
                o.x = a0 * inv + bv.x; o.x = o.x > 0.f ? o.x : 0.01f * o.x;
                o.y = a1 * inv + bv.y; o.y = o.y > 0.f ? o.y : 0.01f * o.y;
                o.z = a2 * inv + bv.z; o.z = o.z > 0.f ? o.z : 0.01f * o.z;
                o.w = a3 * inv + bv.w; o.w = o.w > 0.f ? o.w : 0.01f * o.w;
                ((float4*)out)[(size_t)wid * 16 + l16] = o;
            }
        }
        return;
    }

    // ---- fallback (degree > MAXE): serial path, never hit for this graph ----
    float m = -1e30f;
    for (int e = lane; e < ne; e += 64) {
        int2 ev = eswr[lo + e];
        float lg = s[ev.x] + di + ce * __int_as_float(ev.y);
        lg = lg > 0.f ? lg : 0.2f * lg;
        m = fmaxf(m, lg);
    }
    for (int o = 32; o; o >>= 1) m = fmaxf(m, __shfl_xor(m, o));
    float den = 0.f;
    int c0 = lane, c1 = lane + 64;
    float a0 = 0.f, a1 = 0.f;
    for (int e = 0; e < ne; e++) {
        int2 ev = eswr[lo + e];
        float lg = s[ev.x] + di + ce * __int_as_float(ev.y);
        lg = lg > 0.f ? lg : 0.2f * lg;
        float ex = __expf(lg - m);
        den += ex;
        const unsigned short* hr = &h[(size_t)ev.x * cout];
        a0 += ex * bf2f(hr[c0]);
        if (cout > 64) a1 += ex * bf2f(hr[c1]);
    }
    float inv = 1.0f / (den + 1e-16f);
    float o0 = a0 * inv + bias[c0];
    o0 = o0 > 0.f ? o0 : 0.01f * o0;
    out[(size_t)wid * cout + c0] = o0;
    if (cout > 64) {
        float o1 = a1 * inv + bias[c1];
        o1 = o1 > 0.f ? o1 : 0.01f * o1;
        out[(size_t)wid * cout + c1] = o1;
    }
}

extern "C" void kernel_launch(void* const* d_in, const int* in_sizes, int n_in,
                              void* d_out, int out_size, void* d_ws, size_t ws_size,
                              hipStream_t stream) {
    const int N = NNODES, E = NEDGES, EF = NEDGES + NNODES;

    const float* x = (const float*)d_in[0];
    const int* ei = (const int*)d_in[1];   // int32 on device
    const float* ew = (const float*)d_in[2];
    const float* W1 = (const float*)d_in[3];
    const float* as1 = (const float*)d_in[4];
    const float* ad1 = (const float*)d_in[5];
    const float* We1 = (const float*)d_in[6];
    const float* ae1 = (const float*)d_in[7];
    const float* b1 = (const float*)d_in[8];
    const float* W2 = (const float*)d_in[9];
    const float* as2 = (const float*)d_in[10];
    const float* ad2 = (const float*)d_in[11];
    const float* We2 = (const float*)d_in[12];
    const float* ae2 = (const float*)d_in[13];
    const float* b2 = (const float*)d_in[14];
    const float* W3 = (const float*)d_in[15];
    const float* as3 = (const float*)d_in[16];
    const float* ad3 = (const float*)d_in[17];
    const float* We3 = (const float*)d_in[18];
    const float* ae3 = (const float*)d_in[19];
    const float* b3 = (const float*)d_in[20];
    float* out = (float*)d_out;

    // workspace layout (aligned bump allocator)
    char* wp = (char*)d_ws;
    auto alloc = [&](size_t bytes, size_t align) -> void* {
        size_t a = ((size_t)wp + align - 1) & ~(align - 1);
        wp = (char*)(a + bytes);
        return (void*)a;
    };
    float* act = (float*)alloc((size_t)N * 128 * 4, 16);
    unsigned short* h = (unsigned short*)alloc((size_t)N * 128 * 2, 16);
    float* sd = (float*)alloc((size_t)6 * N * 4, 8);     // s1,d1,s2,d2,s3,d3
    ull* packed = (ull*)alloc((size_t)N * 8, 8);         // contiguous with sd (zeroed together)
    int* row_start = (int*)alloc((size_t)(N + 1) * 4, 4);
    int* blkSums = (int*)alloc(128 * 4, 4);
    int2* eswr = (int2*)alloc((size_t)EF * 8, 8);
    unsigned short* rank16 = (unsigned short*)alloc((size_t)E * 2, 4);
    float* ce = (float*)alloc(4 * 4, 4);
    unsigned short* wt1 = (unsigned short*)alloc(32768 * 2, 16);
    unsigned short* wt2 = (unsigned short*)alloc(16384 * 2, 16);
    unsigned short* wt3 = (unsigned short*)alloc(8192 * 2, 16);

    // ---- zero sd (6N f32) + packed (N u64) in one launch (contiguous) ----
    zero_i32<<<(8 * N + 255) / 256, 256, 0, stream>>>((int*)sd, 8 * N);
    // ---- build CSR by dst (self loops, fill_value='mean') ----
    count_k<<<(E + 255) / 256, 256, 0, stream>>>(ei, ew, packed, rank16, E, N);
    int nblkA = (N + 1023) / 1024;  // 98
    scanA<<<nblkA, 256, 0, stream>>>(packed, row_start, blkSums, N);
    scanB<<<1, 128, 0, stream>>>(blkSums, nblkA);
    scanC<<<(N + 255) / 256, 256, 0, stream>>>(row_start, blkSums, N);
    selfloop_k<<<(N + 255) / 256, 256, 0, stream>>>(packed, row_start, eswr, N);
    scatter_k<<<NSLICE * 128, 256, 0, stream>>>(ei, ew, rank16, row_start, eswr, E, N);
    ce_k<<<3, 64, 0, stream>>>(We1, ae1, We2, ae2, We3, ae3, ce);
    wt_k<<<(32768 + 16384 + 8192) / 256, 256, 0, stream>>>(W1, W2, W3, wt1, wt2, wt3);

    // ---- layer 1: 256 -> 128 ----
    {
        int cin = 256, cout = 128;
        dim3 grid((N + 63) / 64, cout / 64);
        gemm_mfma<<<grid, 256, 0, stream>>>(x, wt1, h, as1, ad1, sd + 0 * N, sd + 1 * N,
                                            N, cin, cout);
        agg_k<<<(N + 3) / 4, 256, 0, stream>>>(eswr, row_start, h, sd + 0 * N,
                                               sd + 1 * N, ce + 0, b1, act, N, cout);
    }
    // ---- layer 2: 128 -> 128 ----
    {
        int cin = 128, cout = 128;
        dim3 grid((N + 63) / 64, cout / 64);
        gemm_mfma<<<grid, 256, 0, stream>>>(act, wt2, h, as2, ad2, sd + 2 * N, sd + 3 * N,
                                            N, cin, cout);
        agg_k<<<(N + 3) / 4, 256, 0, stream>>>(eswr, row_start, h, sd + 2 * N,
                                               sd + 3 * N, ce + 1, b2, act, N, cout);
    }
    // ---- layer 3: 128 -> 64 ----
    {
        int cin = 128, cout = 64;
        dim3 grid((N + 63) / 64, cout / 64);
        gemm_mfma<<<grid, 256, 0, stream>>>(act, wt3, h, as3, ad3, sd + 4 * N, sd + 5 * N,
                                            N, cin, cout);
        agg_k<<<(N + 3) / 4, 256, 0, stream>>>(eswr, row_start, h, sd + 4 * N,
                                               sd + 5 * N, ce + 2, b3, out, N, cout);
    }
}

// Round 7
// 445.546 us; speedup vs baseline: 2.9400x; 1.0110x over previous
//
#include <hip/hip_runtime.h>
#include <hip/hip_bf16.h>
#include <math.h>

#define NNODES 100000
#define NEDGES 1600000
#define MAXE 128
#define NSLICE 8
#define NSUB 2
#define SL_SPAN ((NNODES + NSLICE - 1) / NSLICE)

typedef short bfrag8 __attribute__((ext_vector_type(8)));  // 8 bf16 (4 VGPRs)
typedef float facc4 __attribute__((ext_vector_type(4)));   // 4 fp32 acc
typedef unsigned long long ull;

__device__ __forceinline__ unsigned short f2bf(float f) {
    unsigned u = __float_as_uint(f);
    unsigned r = u + 0x7fffu + ((u >> 16) & 1u);  // round-to-nearest-even
    return (unsigned short)(r >> 16);
}
__device__ __forceinline__ float bf2f(unsigned short u) {
    return __uint_as_float((unsigned)u << 16);
}

// ---------------- utility ----------------
__global__ void zero_i32(int* p, int n) {
    int i = blockIdx.x * blockDim.x + threadIdx.x;
    if (i < n) p[i] = 0;
}

// one packed u64 atomic per edge: deg in [40,63], fixed-point sum(ew) in [0,40).
// returns old -> per-edge rank within its dst segment. Also prepacks erec=(src,w).
__global__ void count_k(const int* __restrict__ ei, const float* __restrict__ ew,
                        ull* __restrict__ packed, unsigned short* __restrict__ rank16,
                        int2* __restrict__ erec, int E, int n) {
    int e = blockIdx.x * blockDim.x + threadIdx.x;
    if (e >= E) return;
    int src = ei[e];
    unsigned dstv = (unsigned)ei[E + e];
    float w = ew[e];
    unsigned short rk = 0;
    if (dstv < (unsigned)n) {
        unsigned fx = __float2uint_rn(w * 16777216.0f);  // w * 2^24
        ull old = atomicAdd(&packed[dstv], (1ULL << 40) | (ull)fx);
        unsigned r = (unsigned)(old >> 40);
        rk = (unsigned short)(r > 65535u ? 65535u : r);
    }
    rank16[e] = rk;
    erec[e] = make_int2(src, __float_as_int(w));
}

// ---------------- scan (counts = deg+1, for self loop) ----------------
__global__ void scanA(const ull* __restrict__ packed, int* __restrict__ row_start,
                      int* __restrict__ blkSums, int n) {
    __shared__ int sdata[256];
    int tid = threadIdx.x;
    int base = blockIdx.x * 1024 + tid * 4;
    int v[4];
    int sum = 0;
#pragma unroll
    for (int j = 0; j < 4; j++) {
        int idx = base + j;
        int c = (idx < n) ? ((int)(packed[idx] >> 40) + 1) : 0;
        sum += c;
        v[j] = sum;
    }
    sdata[tid] = sum;
    __syncthreads();
    for (int off = 1; off < 256; off <<= 1) {
        int t = (tid >= off) ? sdata[tid - off] : 0;
        __syncthreads();
        sdata[tid] += t;
        __syncthreads();
    }
    int excl = sdata[tid] - sum;
#pragma unroll
    for (int j = 0; j < 4; j++) {
        int idx = base + j;
        if (idx < n) row_start[idx + 1] = excl + v[j];
    }
    if (tid == 255) blkSums[blockIdx.x] = sdata[255];
}

__global__ void scanB(int* __restrict__ blkSums, int nblk) {
    __shared__ int sdata[128];
    int tid = threadIdx.x;
    int v = (tid < nblk) ? blkSums[tid] : 0;
    sdata[tid] = v;
    __syncthreads();
    for (int off = 1; off < 128; off <<= 1) {
        int t = (tid >= off) ? sdata[tid - off] : 0;
        __syncthreads();
        sdata[tid] += t;
        __syncthreads();
    }
    if (tid < nblk) blkSums[tid] = sdata[tid] - v;
}

// finalize row_start AND write self-loop record (start of own segment is v - cnt,
// computable locally from packed[idx] -> no dependence on neighbor threads)
__global__ void scanC(int* __restrict__ row_start, const int* __restrict__ blkSums,
                      const ull* __restrict__ packed, int2* __restrict__ eswr, int n) {
    int idx = blockIdx.x * blockDim.x + threadIdx.x;
    if (idx < n) {
        int v = row_start[idx + 1] + blkSums[idx >> 10];
        row_start[idx + 1] = v;
        ull p = packed[idx];
        int cnt = (int)(p >> 40) + 1;
        int dg = cnt - 1;
        float sum = (float)(p & 0xFFFFFFFFFFULL) * (1.0f / 16777216.0f);
        float w = sum / (float)(dg > 1 ? dg : 1);
        eswr[v - cnt] = make_int2(idx, __float_as_int(w));  // self-loop at slot 0
    }
    if (idx == 0) row_start[0] = 0;
}

// ---------------- dst-sliced scatter, sub-windowed ----------------
// slice = blockIdx & 7 (XCD-aligned heuristic; correctness independent of placement).
// NSUB sub-windows shrink the active eswr region to ~850KB so partially-assembled
// lines survive in the XCD L2 and are written back once.
__global__ __launch_bounds__(256) void scatter_k(
    const int* __restrict__ ei_dst, const int2* __restrict__ erec,
    const unsigned short* __restrict__ rank16, const int* __restrict__ row_start,
    int2* __restrict__ eswr, int E, int n) {
    int slice = blockIdx.x & (NSLICE - 1);
    int r = blockIdx.x >> 3;
    int bps = gridDim.x >> 3;
    const int4* d4 = (const int4*)ei_dst;
    int nq = E >> 2;
    int span2 = (SL_SPAN + NSUB - 1) / NSUB;
#pragma unroll
    for (int sub = 0; sub < NSUB; sub++) {
        int lo = slice * SL_SPAN + sub * span2;
        int hi = lo + span2;
        if (hi > n) hi = n;
        for (int q = r * 256 + threadIdx.x; q < nq; q += bps * 256) {
            int4 dv = d4[q];
            int e = q * 4;
            if (dv.x >= lo && dv.x < hi) {
                int pos = row_start[dv.x] + 1 + (int)rank16[e];
                eswr[pos] = erec[e];
            }
            if (dv.y >= lo && dv.y < hi) {
                int pos = row_start[dv.y] + 1 + (int)rank16[e + 1];
                eswr[pos] = erec[e + 1];
            }
            if (dv.z >= lo && dv.z < hi) {
                int pos = row_start[dv.z] + 1 + (int)rank16[e + 2];
                eswr[pos] = erec[e + 2];
            }
            if (dv.w >= lo && dv.w < hi) {
                int pos = row_start[dv.w] + 1 + (int)rank16[e + 3];
                eswr[pos] = erec[e + 3];
            }
        }
    }
}

// ---------------- ce[l] = dot(We_l, ae_l) ----------------
__global__ void ce_k(const float* We1, const float* ae1,
                     const float* We2, const float* ae2,
                     const float* We3, const float* ae3, float* ce) {
    const float* W;
    const float* a;
    int cout;
    if (blockIdx.x == 0) { W = We1; a = ae1; cout = 128; }
    else if (blockIdx.x == 1) { W = We2; a = ae2; cout = 128; }
    else { W = We3; a = ae3; cout = 64; }
    int lane = threadIdx.x;
    float v = 0.f;
    for (int c = lane; c < cout; c += 64) v += W[c] * a[c];
    for (int o = 32; o; o >>= 1) v += __shfl_xor(v, o);
    if (lane == 0) ce[blockIdx.x] = v;
}

// ---------------- convert W [cin][cout] fp32 -> Wt [cout][cin] bf16 ----------------
__global__ void wt_k(const float* __restrict__ W1, const float* __restrict__ W2,
                     const float* __restrict__ W3, unsigned short* __restrict__ wt1,
                     unsigned short* __restrict__ wt2, unsigned short* __restrict__ wt3) {
    int i = blockIdx.x * 256 + threadIdx.x;
    if (i < 32768) {            // layer1: [256][128] -> [128][256]
        int k = i >> 7, nn = i & 127;
        wt1[nn * 256 + k] = f2bf(W1[i]);
        return;
    }
    i -= 32768;
    if (i < 16384) {            // layer2: [128][128]
        int k = i >> 7, nn = i & 127;
        wt2[nn * 128 + k] = f2bf(W2[i]);
        return;
    }
    i -= 16384;
    if (i < 8192) {             // layer3: [128][64] -> [64][128]
        int k = i >> 6, nn = i & 63;
        wt3[nn * 128 + k] = f2bf(W3[i]);
    }
}

// ---------------- MFMA GEMM: H(bf16) = X @ W, fused s/d partial dots ----------------
__global__ __launch_bounds__(256) void gemm_mfma(
    const float* __restrict__ X, const unsigned short* __restrict__ Wt,
    unsigned short* __restrict__ H, const float* __restrict__ as_,
    const float* __restrict__ ad_, float* __restrict__ s, float* __restrict__ d,
    int nrows, int cin, int cout) {
    __shared__ __align__(16) unsigned short lA[64 * 40];
    __shared__ __align__(16) unsigned short lB[64 * 40];
    int t = threadIdx.x;
    int wv = t >> 6, lane = t & 63;
    int lr = lane & 15, lg = lane >> 4;
    int row0 = blockIdx.x * 64, col0 = blockIdx.y * 64;
    int sr = t >> 2, sc = (t & 3) * 8;

    facc4 acc[4] = {};

    const float* xrow = X + (size_t)(row0 + sr) * cin;
    bool rowok = (row0 + sr) < nrows;
    const unsigned short* wrow = Wt + (size_t)(col0 + sr) * cin;

    for (int k0 = 0; k0 < cin; k0 += 32) {
        union { bfrag8 v; unsigned short u[8]; } pa;
        if (rowok) {
            float4 v0 = *(const float4*)&xrow[k0 + sc];
            float4 v1 = *(const float4*)&xrow[k0 + sc + 4];
            pa.u[0] = f2bf(v0.x); pa.u[1] = f2bf(v0.y);
            pa.u[2] = f2bf(v0.z); pa.u[3] = f2bf(v0.w);
            pa.u[4] = f2bf(v1.x); pa.u[5] = f2bf(v1.y);
            pa.u[6] = f2bf(v1.z); pa.u[7] = f2bf(v1.w);
        } else {
#pragma unroll
            for (int j = 0; j < 8; j++) pa.u[j] = 0;
        }
        *(bfrag8*)&lA[sr * 40 + sc] = pa.v;
        *(bfrag8*)&lB[sr * 40 + sc] = *(const bfrag8*)&wrow[k0 + sc];
        __syncthreads();
        bfrag8 a = *(const bfrag8*)&lA[(wv * 16 + lr) * 40 + lg * 8];
#pragma unroll
        for (int n0 = 0; n0 < 4; n0++) {
            bfrag8 b = *(const bfrag8*)&lB[(n0 * 16 + lr) * 40 + lg * 8];
            acc[n0] = __builtin_amdgcn_mfma_f32_16x16x32_bf16(a, b, acc[n0], 0, 0, 0);
        }
        __syncthreads();
    }
#pragma unroll
    for (int r = 0; r < 4; r++) {
        int row = row0 + wv * 16 + lg * 4 + r;
        if (row >= nrows) continue;
        float ps = 0.f, pd = 0.f;
#pragma unroll
        for (int n0 = 0; n0 < 4; n0++) {
            int col = col0 + n0 * 16 + lr;
            float v = acc[n0][r];
            H[(size_t)row * cout + col] = f2bf(v);
            ps += v * as_[col];
            pd += v * ad_[col];
        }
        for (int o = 8; o; o >>= 1) {
            ps += __shfl_xor(ps, o);
            pd += __shfl_xor(pd, o);
        }
        if (lr == 0) {
            atomicAdd(&s[row], ps);
            atomicAdd(&d[row], pd);
        }
    }
}

// ---------------- attention + aggregation: one wave per dst node (bf16 h) ----------
__global__ __launch_bounds__(256) void agg_k(
    const int2* __restrict__ eswr, const int* __restrict__ row_start,
    const unsigned short* __restrict__ h, const float* __restrict__ s,
    const float* __restrict__ d, const float* __restrict__ ce_ptr,
    const float* __restrict__ bias, float* __restrict__ out, int n, int cout) {
    __shared__ float ex_s[4][MAXE];
    __shared__ int src_s[4][MAXE];
    int wslot = threadIdx.x >> 6;
    int wid = (blockIdx.x * blockDim.x + threadIdx.x) >> 6;
    int lane = threadIdx.x & 63;
    if (wid >= n) return;
    int lo = row_start[wid], ne = row_start[wid + 1] - lo;
    float ce = *ce_ptr;
    float di = d[wid];

    if (ne <= MAXE) {
        float m = -1e30f;
        for (int e = lane; e < ne; e += 64) {
            int2 ev = eswr[lo + e];
            float lg = s[ev.x] + di + ce * __int_as_float(ev.y);
            lg = lg > 0.f ? lg : 0.2f * lg;
            src_s[wslot][e] = ev.x;
            ex_s[wslot][e] = lg;
            m = fmaxf(m, lg);
        }
        for (int o = 32; o; o >>= 1) m = fmaxf(m, __shfl_xor(m, o));
        float den = 0.f;
        for (int e = lane; e < ne; e += 64) {
            float exv = __expf(ex_s[wslot][e] - m);
            ex_s[wslot][e] = exv;
            den += exv;
        }
        for (int o = 32; o; o >>= 1) den += __shfl_xor(den, o);
        float inv = 1.0f / (den + 1e-16f);

        if (cout == 128) {
            // 2 edges/iter x 32 lanes x bf16x4 (8B/lane, full 256B row)
            int half = lane >> 5, l32 = lane & 31;
            const ushort4* h4 = (const ushort4*)h;
            float a0 = 0.f, a1 = 0.f, a2 = 0.f, a3 = 0.f;
#pragma unroll 4
            for (int e = half; e < ne; e += 2) {
                float exv = ex_s[wslot][e];
                int src = src_s[wslot][e];
                ushort4 hv = h4[(size_t)src * 32 + l32];
                a0 += exv * bf2f(hv.x); a1 += exv * bf2f(hv.y);
                a2 += exv * bf2f(hv.z); a3 += exv * bf2f(hv.w);
            }
            a0 += __shfl_xor(a0, 32); a1 += __shfl_xor(a1, 32);
            a2 += __shfl_xor(a2, 32); a3 += __shfl_xor(a3, 32);
            if (half == 0) {
                float4 bv = ((const float4*)bias)[l32];
                float4 o;
                o.x = a0 * inv + bv.x; o.x = o.x > 0.f ? o.x : 0.01f * o.x;
                o.y = a1 * inv + bv.y; o.y = o.y > 0.f ? o.y : 0.01f * o.y;
                o.z = a2 * inv + bv.z; o.z = o.z > 0.f ? o.z : 0.01f * o.z;
                o.w = a3 * inv + bv.w; o.w = o.w > 0.f ? o.w : 0.01f * o.w;
                ((float4*)out)[(size_t)wid * 32 + l32] = o;
            }
        } else {
            // cout==64: 4 edges/iter x 16 lanes x bf16x4
            int q = lane >> 4, l16 = lane & 15;
            const ushort4* h4 = (const ushort4*)h;
            float a0 = 0.f, a1 = 0.f, a2 = 0.f, a3 = 0.f;
#pragma unroll 4
            for (int e = q; e < ne; e += 4) {
                float exv = ex_s[wslot][e];
                int src = src_s[wslot][e];
                ushort4 hv = h4[(size_t)src * 16 + l16];
                a0 += exv * bf2f(hv.x); a1 += exv * bf2f(hv.y);
                a2 += exv * bf2f(hv.z); a3 += exv * bf2f(hv.w);
            }
            a0 += __shfl_xor(a0, 16); a1 += __shfl_xor(a1, 16);
            a2 += __shfl_xor(a2, 16); a3 += __shfl_xor(a3, 16);
            a0 += __shfl_xor(a0, 32); a1 += __shfl_xor(a1, 32);
            a2 += __shfl_xor(a2, 32); a3 += __shfl_xor(a3, 32);
            if (q == 0) {
                float4 bv = ((const float4*)bias)[l16];
                float4 o;
                o.x = a0 * inv + bv.x; o.x = o.x > 0.f ? o.x : 0.01f * o.x;
                o.y = a1 * inv + bv.y; o.y = o.y > 0.f ? o.y : 0.01f * o.y;
                o.z = a2 * inv + bv.z; o.z = o.z > 0.f ? o.z : 0.01f * o.z;
                o.w = a3 * inv + bv.w; o.w = o.w > 0.f ? o.w : 0.01f * o.w;
                ((float4*)out)[(size_t)wid * 16 + l16] = o;
            }
        }
        return;
    }

    // ---- fallback (degree > MAXE): serial path, never hit for this graph ----
    float m = -1e30f;
    for (int e = lane; e < ne; e += 64) {
        int2 ev = eswr[lo + e];
        float lg = s[ev.x] + di + ce * __int_as_float(ev.y);
        lg = lg > 0.f ? lg : 0.2f * lg;
        m = fmaxf(m, lg);
    }
    for (int o = 32; o; o >>= 1) m = fmaxf(m, __shfl_xor(m, o));
    float den = 0.f;
    int c0 = lane, c1 = lane + 64;
    float a0 = 0.f, a1 = 0.f;
    for (int e = 0; e < ne; e++) {
        int2 ev = eswr[lo + e];
        float lg = s[ev.x] + di + ce * __int_as_float(ev.y);
        lg = lg > 0.f ? lg : 0.2f * lg;
        float ex = __expf(lg - m);
        den += ex;
        const unsigned short* hr = &h[(size_t)ev.x * cout];
        a0 += ex * bf2f(hr[c0]);
        if (cout > 64) a1 += ex * bf2f(hr[c1]);
    }
    float inv = 1.0f / (den + 1e-16f);
    float o0 = a0 * inv + bias[c0];
    o0 = o0 > 0.f ? o0 : 0.01f * o0;
    out[(size_t)wid * cout + c0] = o0;
    if (cout > 64) {
        float o1 = a1 * inv + bias[c1];
        o1 = o1 > 0.f ? o1 : 0.01f * o1;
        out[(size_t)wid * cout + c1] = o1;
    }
}

extern "C" void kernel_launch(void* const* d_in, const int* in_sizes, int n_in,
                              void* d_out, int out_size, void* d_ws, size_t ws_size,
                              hipStream_t stream) {
    const int N = NNODES, E = NEDGES, EF = NEDGES + NNODES;

    const float* x = (const float*)d_in[0];
    const int* ei = (const int*)d_in[1];   // int32 on device
    const float* ew = (const float*)d_in[2];
    const float* W1 = (const float*)d_in[3];
    const float* as1 = (const float*)d_in[4];
    const float* ad1 = (const float*)d_in[5];
    const float* We1 = (const float*)d_in[6];
    const float* ae1 = (const float*)d_in[7];
    const float* b1 = (const float*)d_in[8];
    const float* W2 = (const float*)d_in[9];
    const float* as2 = (const float*)d_in[10];
    const float* ad2 = (const float*)d_in[11];
    const float* We2 = (const float*)d_in[12];
    const float* ae2 = (const float*)d_in[13];
    const float* b2 = (const float*)d_in[14];
    const float* W3 = (const float*)d_in[15];
    const float* as3 = (const float*)d_in[16];
    const float* ad3 = (const float*)d_in[17];
    const float* We3 = (const float*)d_in[18];
    const float* ae3 = (const float*)d_in[19];
    const float* b3 = (const float*)d_in[20];
    float* out = (float*)d_out;

    // workspace layout (aligned bump allocator)
    char* wp = (char*)d_ws;
    auto alloc = [&](size_t bytes, size_t align) -> void* {
        size_t a = ((size_t)wp + align - 1) & ~(align - 1);
        wp = (char*)(a + bytes);
        return (void*)a;
    };
    float* act = (float*)alloc((size_t)N * 128 * 4, 16);
    unsigned short* h = (unsigned short*)alloc((size_t)N * 128 * 2, 16);
    float* sd = (float*)alloc((size_t)6 * N * 4, 8);     // s1,d1,s2,d2,s3,d3
    ull* packed = (ull*)alloc((size_t)N * 8, 8);         // contiguous with sd (zeroed together)
    int* row_start = (int*)alloc((size_t)(N + 1) * 4, 4);
    int* blkSums = (int*)alloc(128 * 4, 4);
    int2* eswr = (int2*)alloc((size_t)EF * 8, 8);
    int2* erec = (int2*)alloc((size_t)E * 8, 16);
    unsigned short* rank16 = (unsigned short*)alloc((size_t)E * 2, 4);
    float* ce = (float*)alloc(4 * 4, 4);
    unsigned short* wt1 = (unsigned short*)alloc(32768 * 2, 16);
    unsigned short* wt2 = (unsigned short*)alloc(16384 * 2, 16);
    unsigned short* wt3 = (unsigned short*)alloc(8192 * 2, 16);

    // ---- zero sd (6N f32) + packed (N u64) in one launch (contiguous) ----
    zero_i32<<<(8 * N + 255) / 256, 256, 0, stream>>>((int*)sd, 8 * N);
    // ---- build CSR by dst (self loops, fill_value='mean') ----
    count_k<<<(E + 255) / 256, 256, 0, stream>>>(ei, ew, packed, rank16, erec, E, N);
    int nblkA = (N + 1023) / 1024;  // 98
    scanA<<<nblkA, 256, 0, stream>>>(packed, row_start, blkSums, N);
    scanB<<<1, 128, 0, stream>>>(blkSums, nblkA);
    scanC<<<(N + 255) / 256, 256, 0, stream>>>(row_start, blkSums, packed, eswr, N);
    scatter_k<<<NSLICE * 256, 256, 0, stream>>>(ei + E, erec, rank16, row_start, eswr, E, N);
    ce_k<<<3, 64, 0, stream>>>(We1, ae1, We2, ae2, We3, ae3, ce);
    wt_k<<<(32768 + 16384 + 8192) / 256, 256, 0, stream>>>(W1, W2, W3, wt1, wt2, wt3);

    // ---- layer 1: 256 -> 128 ----
    {
        int cin = 256, cout = 128;
        dim3 grid((N + 63) / 64, cout / 64);
        gemm_mfma<<<grid, 256, 0, stream>>>(x, wt1, h, as1, ad1, sd + 0 * N, sd + 1 * N,
                                            N, cin, cout);
        agg_k<<<(N + 3) / 4, 256, 0, stream>>>(eswr, row_start, h, sd + 0 * N,
                                               sd + 1 * N, ce + 0, b1, act, N, cout);
    }
    // ---- layer 2: 128 -> 128 ----
    {
        int cin = 128, cout = 128;
        dim3 grid((N + 63) / 64, cout / 64);
        gemm_mfma<<<grid, 256, 0, stream>>>(act, wt2, h, as2, ad2, sd + 2 * N, sd + 3 * N,
                                            N, cin, cout);
        agg_k<<<(N + 3) / 4, 256, 0, stream>>>(eswr, row_start, h, sd + 2 * N,
                                               sd + 3 * N, ce + 1, b2, act, N, cout);
    }
    // ---- layer 3: 128 -> 64 ----
    {
        int cin = 128, cout = 64;
        dim3 grid((N + 63) / 64, cout / 64);
        gemm_mfma<<<grid, 256, 0, stream>>>(act, wt3, h, as3, ad3, sd + 4 * N, sd + 5 * N,
                                            N, cin, cout);
        agg_k<<<(N + 3) / 4, 256, 0, stream>>>(eswr, row_start, h, sd + 4 * N,
                                               sd + 5 * N, ce + 2, b3, out, N, cout);
    }
}

// Round 8
// 387.036 us; speedup vs baseline: 3.3845x; 1.1512x over previous
//
#include <hip/hip_runtime.h>
#include <hip/hip_bf16.h>
#include <math.h>

#define NNODES 100000
#define NEDGES 1600000
#define MAXE 128
#define NB 391                 // buckets of 256 dsts: ceil(100000/256)
#define CAP 6144               // region capacity per bucket (mean ~4090, 32 sigma headroom)
#define EPT 7
#define BK_EDGES (256 * EPT)   // 1792 edges per block
#define BK_BLOCKS ((NEDGES + BK_EDGES - 1) / BK_EDGES)  // 893

typedef short bfrag8 __attribute__((ext_vector_type(8)));  // 8 bf16 (4 VGPRs)
typedef float facc4 __attribute__((ext_vector_type(4)));   // 4 fp32 acc
typedef unsigned long long ull;

__device__ __forceinline__ unsigned short f2bf(float f) {
    unsigned u = __float_as_uint(f);
    unsigned r = u + 0x7fffu + ((u >> 16) & 1u);  // round-to-nearest-even
    return (unsigned short)(r >> 16);
}
__device__ __forceinline__ float bf2f(unsigned short u) {
    return __uint_as_float((unsigned)u << 16);
}

// ---------------- fused init: zero (sd+fill), Wt transpose, ce dots ----------------
// blocks [0,2369): zero 606256 ints at sd; [2369,2593): wt; [2593,2596): ce
__global__ void init_k(int* zbase,
                       const float* __restrict__ W1, const float* __restrict__ W2,
                       const float* __restrict__ W3, unsigned short* __restrict__ wt1,
                       unsigned short* __restrict__ wt2, unsigned short* __restrict__ wt3,
                       const float* We1, const float* ae1, const float* We2,
                       const float* ae2, const float* We3, const float* ae3, float* ce) {
    int gb = blockIdx.x, t = threadIdx.x;
    if (gb < 2369) {
        int i = gb * 256 + t;
        if (i < 6 * NNODES + NB * 16) zbase[i] = 0;
        return;
    }
    if (gb < 2593) {
        int i = (gb - 2369) * 256 + t;
        if (i < 32768) {            // layer1: [256][128] -> [128][256]
            int k = i >> 7, nn = i & 127;
            wt1[nn * 256 + k] = f2bf(W1[i]);
            return;
        }
        i -= 32768;
        if (i < 16384) {            // layer2: [128][128]
            int k = i >> 7, nn = i & 127;
            wt2[nn * 128 + k] = f2bf(W2[i]);
            return;
        }
        i -= 16384;                 // layer3: [128][64] -> [64][128]
        int k = i >> 6, nn = i & 63;
        wt3[nn * 128 + k] = f2bf(W3[i]);
        return;
    }
    // ce
    if (t >= 64) return;
    int cb = gb - 2593;
    const float* W; const float* a; int cout;
    if (cb == 0) { W = We1; a = ae1; cout = 128; }
    else if (cb == 1) { W = We2; a = ae2; cout = 128; }
    else { W = We3; a = ae3; cout = 64; }
    float v = 0.f;
    for (int c = t; c < cout; c += 64) v += W[c] * a[c];
    for (int o = 32; o; o >>= 1) v += __shfl_xor(v, o);
    if (t == 0) ce[cb] = v;
}

// ---------------- pass 1: bucket edges (LDS histogram + chunk claim + staged write) ----
__global__ __launch_bounds__(256) void bucket_k(
    const int* __restrict__ ei, const float* __restrict__ ew,
    unsigned* __restrict__ fill /* NB*16 padded */, uint2* __restrict__ regions) {
    __shared__ unsigned cnt[NB], lbase[NB], gb_s[NB], cur[NB];
    __shared__ unsigned ssum[256];
    __shared__ uint2 srec[BK_EDGES];
    __shared__ unsigned short sbkt[BK_EDGES];
    int t = threadIdx.x;
    for (int b = t; b < NB; b += 256) cnt[b] = 0;
    __syncthreads();
    int e0 = blockIdx.x * BK_EDGES;
    int dstv[EPT], srcv[EPT];
    unsigned wb[EPT];
#pragma unroll
    for (int j = 0; j < EPT; j++) {
        int e = e0 + j * 256 + t;
        dstv[j] = -1;
        if (e < NEDGES) {
            int dd = ei[NEDGES + e];
            int ss = ei[e];
            if ((unsigned)dd < (unsigned)NNODES && (unsigned)ss < (unsigned)NNODES) {
                dstv[j] = dd; srcv[j] = ss; wb[j] = __float_as_uint(ew[e]);
            }
        }
        if (dstv[j] >= 0) atomicAdd(&cnt[dstv[j] >> 8], 1u);
    }
    __syncthreads();
    // block-local ordering: bucket t at offset before bucket t+256
    unsigned c0 = cnt[t];
    unsigned c1 = (t + 256 < NB) ? cnt[t + 256] : 0u;
    ssum[t] = c0 + c1;
    __syncthreads();
    for (int off = 1; off < 256; off <<= 1) {
        unsigned v = (t >= off) ? ssum[t - off] : 0u;
        __syncthreads();
        ssum[t] += v;
        __syncthreads();
    }
    unsigned excl = ssum[t] - (c0 + c1);
    lbase[t] = excl; cur[t] = excl;
    gb_s[t] = c0 ? atomicAdd(&fill[t * 16], c0) : 0u;
    if (t + 256 < NB) {
        lbase[t + 256] = excl + c0; cur[t + 256] = excl + c0;
        gb_s[t + 256] = c1 ? atomicAdd(&fill[(t + 256) * 16], c1) : 0u;
    }
    __syncthreads();
    // stage records bucket-grouped in LDS
#pragma unroll
    for (int j = 0; j < EPT; j++) {
        if (dstv[j] >= 0) {
            unsigned b = (unsigned)dstv[j] >> 8;
            unsigned p = atomicAdd(&cur[b], 1u);
            srec[p] = make_uint2(((unsigned)(dstv[j] & 255) << 24) | (unsigned)srcv[j], wb[j]);
            sbkt[p] = (unsigned short)b;
        }
    }
    __syncthreads();
    unsigned tot = ssum[255];
    for (unsigned i = t; i < tot; i += 256) {
        unsigned b = sbkt[i];
        unsigned slot = gb_s[b] + (i - lbase[b]);
        if (slot < CAP) regions[(size_t)b * CAP + slot] = srec[i];
    }
}

// ---------------- bucket totals scan -> bucket_base, row_start[N] ----------------
__global__ void bucket_scan_k(const unsigned* __restrict__ fill,
                              unsigned* __restrict__ bucket_base, int* __restrict__ row_start) {
    __shared__ unsigned s[512];
    int t = threadIdx.x;
    unsigned c = 0;
    if (t < NB) {
        unsigned sz = fill[t * 16];
        if (sz > CAP) sz = CAP;
        int nv = NNODES - (t << 8);
        if (nv > 256) nv = 256;
        if (nv < 0) nv = 0;
        c = sz + (unsigned)nv;
    }
    s[t] = c;
    __syncthreads();
    for (int off = 1; off < 512; off <<= 1) {
        unsigned v = (t >= off) ? s[t - off] : 0u;
        __syncthreads();
        s[t] += v;
        __syncthreads();
    }
    if (t < NB) bucket_base[t] = s[t] - c;
    if (t == 511) row_start[NNODES] = (int)s[511];
}

// ---------------- pass 2: per-bucket place (deg/sum count, seg scan, exact CSR) ----
__global__ __launch_bounds__(512) void place_k(
    const uint2* __restrict__ regions, const unsigned* __restrict__ fill,
    const unsigned* __restrict__ bucket_base, int2* __restrict__ eswr,
    int* __restrict__ row_start) {
    __shared__ uint2 rec[CAP];
    __shared__ unsigned deg[256], sumw[256], sc[256], seg[256], cur[256];
    int b = blockIdx.x, t = threadIdx.x;
    unsigned size = fill[b * 16];
    if (size > CAP) size = CAP;
    int dst0 = b << 8;
    int nvalid = NNODES - dst0;
    if (nvalid > 256) nvalid = 256;
    if (nvalid < 0) nvalid = 0;
    if (t < 256) { deg[t] = 0; sumw[t] = 0; }
    __syncthreads();
    for (unsigned i = t; i < size; i += 512) {
        uint2 r = regions[(size_t)b * CAP + i];
        rec[i] = r;
        unsigned dl = r.x >> 24;
        atomicAdd(&deg[dl], 1u);
        atomicAdd(&sumw[dl], __float2uint_rn(__uint_as_float(r.y) * 16777216.0f));
    }
    __syncthreads();
    unsigned cnti = (t < (unsigned)nvalid) ? deg[t] + 1u : 0u;
    if (t < 256) sc[t] = cnti;
    __syncthreads();
    for (int off = 1; off < 256; off <<= 1) {
        unsigned v = (t >= off && t < 256) ? sc[t - off] : 0u;
        __syncthreads();
        if (t < 256) sc[t] += v;
        __syncthreads();
    }
    unsigned bb = bucket_base[b];
    if (t < 256) {
        unsigned excl = sc[t] - cnti;
        seg[t] = excl;
        cur[t] = excl + 1u;
        if (t < (unsigned)nvalid) {
            int dst = dst0 + t;
            row_start[dst] = (int)(bb + excl);
            float sw = (float)sumw[t] * (1.0f / 16777216.0f);
            int dg = (int)deg[t];
            float w = sw / (float)(dg > 1 ? dg : 1);
            eswr[bb + excl] = make_int2(dst, __float_as_int(w));  // self-loop at slot 0
        }
    }
    __syncthreads();
    for (unsigned i = t; i < size; i += 512) {
        uint2 r = rec[i];
        unsigned dl = r.x >> 24;
        unsigned p = atomicAdd(&cur[dl], 1u);
        eswr[bb + p] = make_int2((int)(r.x & 0xFFFFFFu), (int)r.y);
    }
}

// ---------------- MFMA GEMM: H(bf16) = X @ W, fused s/d partial dots ----------------
template <bool ABF16>
__global__ __launch_bounds__(256) void gemm_mfma(
    const void* __restrict__ Xv, const unsigned short* __restrict__ Wt,
    unsigned short* __restrict__ H, const float* __restrict__ as_,
    const float* __restrict__ ad_, float* __restrict__ s, float* __restrict__ d,
    int nrows, int cin, int cout) {
    __shared__ __align__(16) unsigned short lA[64 * 40];
    __shared__ __align__(16) unsigned short lB[64 * 40];
    int t = threadIdx.x;
    int wv = t >> 6, lane = t & 63;
    int lr = lane & 15, lg = lane >> 4;
    int row0 = blockIdx.x * 64, col0 = blockIdx.y * 64;
    int sr = t >> 2, sc = (t & 3) * 8;

    facc4 acc[4] = {};
    bool rowok = (row0 + sr) < nrows;
    const unsigned short* wrow = Wt + (size_t)(col0 + sr) * cin;

    for (int k0 = 0; k0 < cin; k0 += 32) {
        union { bfrag8 v; unsigned short u[8]; } pa;
        if (rowok) {
            if constexpr (ABF16) {
                const unsigned short* xrow = (const unsigned short*)Xv + (size_t)(row0 + sr) * cin;
                pa.v = *(const bfrag8*)&xrow[k0 + sc];
            } else {
                const float* xrow = (const float*)Xv + (size_t)(row0 + sr) * cin;
                float4 v0 = *(const float4*)&xrow[k0 + sc];
                float4 v1 = *(const float4*)&xrow[k0 + sc + 4];
                pa.u[0] = f2bf(v0.x); pa.u[1] = f2bf(v0.y);
                pa.u[2] = f2bf(v0.z); pa.u[3] = f2bf(v0.w);
                pa.u[4] = f2bf(v1.x); pa.u[5] = f2bf(v1.y);
                pa.u[6] = f2bf(v1.z); pa.u[7] = f2bf(v1.w);
            }
        } else {
#pragma unroll
            for (int j = 0; j < 8; j++) pa.u[j] = 0;
        }
        *(bfrag8*)&lA[sr * 40 + sc] = pa.v;
        *(bfrag8*)&lB[sr * 40 + sc] = *(const bfrag8*)&wrow[k0 + sc];
        __syncthreads();
        bfrag8 a = *(const bfrag8*)&lA[(wv * 16 + lr) * 40 + lg * 8];
#pragma unroll
        for (int n0 = 0; n0 < 4; n0++) {
            bfrag8 bfr = *(const bfrag8*)&lB[(n0 * 16 + lr) * 40 + lg * 8];
            acc[n0] = __builtin_amdgcn_mfma_f32_16x16x32_bf16(a, bfr, acc[n0], 0, 0, 0);
        }
        __syncthreads();
    }
#pragma unroll
    for (int r = 0; r < 4; r++) {
        int row = row0 + wv * 16 + lg * 4 + r;
        if (row >= nrows) continue;
        float ps = 0.f, pd = 0.f;
#pragma unroll
        for (int n0 = 0; n0 < 4; n0++) {
            int col = col0 + n0 * 16 + lr;
            float v = acc[n0][r];
            H[(size_t)row * cout + col] = f2bf(v);
            ps += v * as_[col];
            pd += v * ad_[col];
        }
        for (int o = 8; o; o >>= 1) {
            ps += __shfl_xor(ps, o);
            pd += __shfl_xor(pd, o);
        }
        if (lr == 0) {
            atomicAdd(&s[row], ps);
            atomicAdd(&d[row], pd);
        }
    }
}

// ---------------- attention + aggregation: one wave per dst node (bf16 h) ----------
template <bool OBF16>
__global__ __launch_bounds__(256) void agg_k(
    const int2* __restrict__ eswr, const int* __restrict__ row_start,
    const unsigned short* __restrict__ h, const float* __restrict__ s,
    const float* __restrict__ d, const float* __restrict__ ce_ptr,
    const float* __restrict__ bias, void* __restrict__ outv, int n, int cout) {
    __shared__ float ex_s[4][MAXE];
    __shared__ int src_s[4][MAXE];
    int wslot = threadIdx.x >> 6;
    int wid = (blockIdx.x * blockDim.x + threadIdx.x) >> 6;
    int lane = threadIdx.x & 63;
    if (wid >= n) return;
    int lo = row_start[wid], ne = row_start[wid + 1] - lo;
    float ce = *ce_ptr;
    float di = d[wid];

    if (ne <= MAXE) {
        float m = -1e30f;
        for (int e = lane; e < ne; e += 64) {
            int2 ev = eswr[lo + e];
            float lg = s[ev.x] + di + ce * __int_as_float(ev.y);
            lg = lg > 0.f ? lg : 0.2f * lg;
            src_s[wslot][e] = ev.x;
            ex_s[wslot][e] = lg;
            m = fmaxf(m, lg);
        }
        for (int o = 32; o; o >>= 1) m = fmaxf(m, __shfl_xor(m, o));
        float den = 0.f;
        for (int e = lane; e < ne; e += 64) {
            float exv = __expf(ex_s[wslot][e] - m);
            ex_s[wslot][e] = exv;
            den += exv;
        }
        for (int o = 32; o; o >>= 1) den += __shfl_xor(den, o);
        float inv = 1.0f / (den + 1e-16f);

        if (cout == 128) {
            int half = lane >> 5, l32 = lane & 31;
            const ushort4* h4 = (const ushort4*)h;
            float a0 = 0.f, a1 = 0.f, a2 = 0.f, a3 = 0.f;
#pragma unroll 4
            for (int e = half; e < ne; e += 2) {
                float exv = ex_s[wslot][e];
                int src = src_s[wslot][e];
                ushort4 hv = h4[(size_t)src * 32 + l32];
                a0 += exv * bf2f(hv.x); a1 += exv * bf2f(hv.y);
                a2 += exv * bf2f(hv.z); a3 += exv * bf2f(hv.w);
            }
            a0 += __shfl_xor(a0, 32); a1 += __shfl_xor(a1, 32);
            a2 += __shfl_xor(a2, 32); a3 += __shfl_xor(a3, 32);
            if (half == 0) {
                float4 bv = ((const float4*)bias)[l32];
                float4 o;
                o.x = a0 * inv + bv.x; o.x = o.x > 0.f ? o.x : 0.01f * o.x;
                o.y = a1 * inv + bv.y; o.y = o.y > 0.f ? o.y : 0.01f * o.y;
                o.z = a2 * inv + bv.z; o.z = o.z > 0.f ? o.z : 0.01f * o.z;
                o.w = a3 * inv + bv.w; o.w = o.w > 0.f ? o.w : 0.01f * o.w;
                if constexpr (OBF16) {
                    ushort4 ov;
                    ov.x = f2bf(o.x); ov.y = f2bf(o.y); ov.z = f2bf(o.z); ov.w = f2bf(o.w);
                    ((ushort4*)outv)[(size_t)wid * 32 + l32] = ov;
                } else {
                    ((float4*)outv)[(size_t)wid * 32 + l32] = o;
                }
            }
        } else {
            int q = lane >> 4, l16 = lane & 15;
            const ushort4* h4 = (const ushort4*)h;
            float a0 = 0.f, a1 = 0.f, a2 = 0.f, a3 = 0.f;
#pragma unroll 4
            for (int e = q; e < ne; e += 4) {
                float exv = ex_s[wslot][e];
                int src = src_s[wslot][e];
                ushort4 hv = h4[(size_t)src * 16 + l16];
                a0 += exv * bf2f(hv.x); a1 += exv * bf2f(hv.y);
                a2 += exv * bf2f(hv.z); a3 += exv * bf2f(hv.w);
            }
            a0 += __shfl_xor(a0, 16); a1 += __shfl_xor(a1, 16);
            a2 += __shfl_xor(a2, 16); a3 += __shfl_xor(a3, 16);
            a0 += __shfl_xor(a0, 32); a1 += __shfl_xor(a1, 32);
            a2 += __shfl_xor(a2, 32); a3 += __shfl_xor(a3, 32);
            if (q == 0) {
                float4 bv = ((const float4*)bias)[l16];
                float4 o;
                o.x = a0 * inv + bv.x; o.x = o.x > 0.f ? o.x : 0.01f * o.x;
                o.y = a1 * inv + bv.y; o.y = o.y > 0.f ? o.y : 0.01f * o.y;
                o.z = a2 * inv + bv.z; o.z = o.z > 0.f ? o.z : 0.01f * o.z;
                o.w = a3 * inv + bv.w; o.w = o.w > 0.f ? o.w : 0.01f * o.w;
                if constexpr (OBF16) {
                    ushort4 ov;
                    ov.x = f2bf(o.x); ov.y = f2bf(o.y); ov.z = f2bf(o.z); ov.w = f2bf(o.w);
                    ((ushort4*)outv)[(size_t)wid * 16 + l16] = ov;
                } else {
                    ((float4*)outv)[(size_t)wid * 16 + l16] = o;
                }
            }
        }
        return;
    }

    // ---- fallback (degree > MAXE): serial path, never hit for this graph ----
    float m = -1e30f;
    for (int e = lane; e < ne; e += 64) {
        int2 ev = eswr[lo + e];
        float lg = s[ev.x] + di + ce * __int_as_float(ev.y);
        lg = lg > 0.f ? lg : 0.2f * lg;
        m = fmaxf(m, lg);
    }
    for (int o = 32; o; o >>= 1) m = fmaxf(m, __shfl_xor(m, o));
    float den = 0.f;
    int c0 = lane, c1 = lane + 64;
    float a0 = 0.f, a1 = 0.f;
    for (int e = 0; e < ne; e++) {
        int2 ev = eswr[lo + e];
        float lg = s[ev.x] + di + ce * __int_as_float(ev.y);
        lg = lg > 0.f ? lg : 0.2f * lg;
        float ex = __expf(lg - m);
        den += ex;
        const unsigned short* hr = &h[(size_t)ev.x * cout];
        a0 += ex * bf2f(hr[c0]);
        if (cout > 64) a1 += ex * bf2f(hr[c1]);
    }
    float inv = 1.0f / (den + 1e-16f);
    float o0 = a0 * inv + bias[c0];
    o0 = o0 > 0.f ? o0 : 0.01f * o0;
    float o1 = 0.f;
    if (cout > 64) {
        o1 = a1 * inv + bias[c1];
        o1 = o1 > 0.f ? o1 : 0.01f * o1;
    }
    if constexpr (OBF16) {
        unsigned short* out = (unsigned short*)outv;
        out[(size_t)wid * cout + c0] = f2bf(o0);
        if (cout > 64) out[(size_t)wid * cout + c1] = f2bf(o1);
    } else {
        float* out = (float*)outv;
        out[(size_t)wid * cout + c0] = o0;
        if (cout > 64) out[(size_t)wid * cout + c1] = o1;
    }
}

extern "C" void kernel_launch(void* const* d_in, const int* in_sizes, int n_in,
                              void* d_out, int out_size, void* d_ws, size_t ws_size,
                              hipStream_t stream) {
    const int N = NNODES, E = NEDGES, EF = NEDGES + NNODES;

    const float* x = (const float*)d_in[0];
    const int* ei = (const int*)d_in[1];   // int32 on device
    const float* ew = (const float*)d_in[2];
    const float* W1 = (const float*)d_in[3];
    const float* as1 = (const float*)d_in[4];
    const float* ad1 = (const float*)d_in[5];
    const float* We1 = (const float*)d_in[6];
    const float* ae1 = (const float*)d_in[7];
    const float* b1 = (const float*)d_in[8];
    const float* W2 = (const float*)d_in[9];
    const float* as2 = (const float*)d_in[10];
    const float* ad2 = (const float*)d_in[11];
    const float* We2 = (const float*)d_in[12];
    const float* ae2 = (const float*)d_in[13];
    const float* b2 = (const float*)d_in[14];
    const float* W3 = (const float*)d_in[15];
    const float* as3 = (const float*)d_in[16];
    const float* ad3 = (const float*)d_in[17];
    const float* We3 = (const float*)d_in[18];
    const float* ae3 = (const float*)d_in[19];
    const float* b3 = (const float*)d_in[20];
    float* out = (float*)d_out;

    // workspace layout (aligned bump allocator). sd and fill must be adjacent (one zero).
    char* wp = (char*)d_ws;
    auto alloc = [&](size_t bytes, size_t align) -> void* {
        size_t a = ((size_t)wp + align - 1) & ~(align - 1);
        wp = (char*)(a + bytes);
        return (void*)a;
    };
    float* sd = (float*)alloc((size_t)6 * N * 4, 16);            // s1,d1,s2,d2,s3,d3
    unsigned* fill = (unsigned*)alloc((size_t)NB * 16 * 4, 4);   // padded bucket counters
    unsigned short* act = (unsigned short*)alloc((size_t)N * 128 * 2, 16);
    unsigned short* h = (unsigned short*)alloc((size_t)N * 128 * 2, 16);
    int* row_start = (int*)alloc((size_t)(N + 1) * 4, 4);
    unsigned* bucket_base = (unsigned*)alloc((size_t)NB * 4, 4);
    int2* eswr = (int2*)alloc((size_t)EF * 8, 16);
    uint2* regions = (uint2*)alloc((size_t)NB * CAP * 8, 16);
    float* ce = (float*)alloc(4 * 4, 4);
    unsigned short* wt1 = (unsigned short*)alloc(32768 * 2, 16);
    unsigned short* wt2 = (unsigned short*)alloc(16384 * 2, 16);
    unsigned short* wt3 = (unsigned short*)alloc(8192 * 2, 16);

    // ---- init: zero sd+fill, transpose weights, ce dots (one fused launch) ----
    init_k<<<2596, 256, 0, stream>>>((int*)sd, W1, W2, W3, wt1, wt2, wt3,
                                     We1, ae1, We2, ae2, We3, ae3, ce);
    // ---- CSR build via two-level bucket sort ----
    bucket_k<<<BK_BLOCKS, 256, 0, stream>>>(ei, ew, fill, regions);
    bucket_scan_k<<<1, 512, 0, stream>>>(fill, bucket_base, row_start);
    place_k<<<NB, 512, 0, stream>>>(regions, fill, bucket_base, eswr, row_start);

    // ---- layer 1: 256 -> 128 ----
    {
        int cin = 256, cout = 128;
        dim3 grid((N + 63) / 64, cout / 64);
        gemm_mfma<false><<<grid, 256, 0, stream>>>(x, wt1, h, as1, ad1,
                                                   sd + 0 * N, sd + 1 * N, N, cin, cout);
        agg_k<true><<<(N + 3) / 4, 256, 0, stream>>>(eswr, row_start, h, sd + 0 * N,
                                                     sd + 1 * N, ce + 0, b1, act, N, cout);
    }
    // ---- layer 2: 128 -> 128 ----
    {
        int cin = 128, cout = 128;
        dim3 grid((N + 63) / 64, cout / 64);
        gemm_mfma<true><<<grid, 256, 0, stream>>>(act, wt2, h, as2, ad2,
                                                  sd + 2 * N, sd + 3 * N, N, cin, cout);
        agg_k<true><<<(N + 3) / 4, 256, 0, stream>>>(eswr, row_start, h, sd + 2 * N,
                                                     sd + 3 * N, ce + 1, b2, act, N, cout);
    }
    // ---- layer 3: 128 -> 64 ----
    {
        int cin = 128, cout = 64;
        dim3 grid((N + 63) / 64, cout / 64);
        gemm_mfma<true><<<grid, 256, 0, stream>>>(act, wt3, h, as3, ad3,
                                                  sd + 4 * N, sd + 5 * N, N, cin, cout);
        agg_k<false><<<(N + 3) / 4, 256, 0, stream>>>(eswr, row_start, h, sd + 4 * N,
                                                      sd + 5 * N, ce + 2, b3, out, N, cout);
    }
}

// Round 9
// 383.162 us; speedup vs baseline: 3.4187x; 1.0101x over previous
//
#include <hip/hip_runtime.h>
#include <hip/hip_bf16.h>
#include <math.h>

#define NNODES 100000
#define NEDGES 1600000
#define MAXE 128
#define NB 391                 // buckets of 256 dsts: ceil(100000/256)
#define CAP 6144               // region capacity per bucket (mean ~4090, 32 sigma headroom)
#define EPT 7
#define BK_EDGES (256 * EPT)   // 1792 edges per block
#define BK_BLOCKS ((NEDGES + BK_EDGES - 1) / BK_EDGES)  // 893

typedef short bfrag8 __attribute__((ext_vector_type(8)));  // 8 bf16 (4 VGPRs)
typedef float facc4 __attribute__((ext_vector_type(4)));   // 4 fp32 acc
typedef unsigned short ushortv8 __attribute__((ext_vector_type(8)));
typedef unsigned long long ull;

__device__ __forceinline__ unsigned short f2bf(float f) {
    unsigned u = __float_as_uint(f);
    unsigned r = u + 0x7fffu + ((u >> 16) & 1u);  // round-to-nearest-even
    return (unsigned short)(r >> 16);
}
__device__ __forceinline__ float bf2f(unsigned short u) {
    return __uint_as_float((unsigned)u << 16);
}

// ---------------- fused init: zero (sd+fill), Wt transpose, ce dots ----------------
__global__ void init_k(int* zbase,
                       const float* __restrict__ W1, const float* __restrict__ W2,
                       const float* __restrict__ W3, unsigned short* __restrict__ wt1,
                       unsigned short* __restrict__ wt2, unsigned short* __restrict__ wt3,
                       const float* We1, const float* ae1, const float* We2,
                       const float* ae2, const float* We3, const float* ae3, float* ce) {
    int gb = blockIdx.x, t = threadIdx.x;
    if (gb < 2369) {
        int i = gb * 256 + t;
        if (i < 6 * NNODES + NB * 16) zbase[i] = 0;
        return;
    }
    if (gb < 2593) {
        int i = (gb - 2369) * 256 + t;
        if (i < 32768) {            // layer1: [256][128] -> [128][256]
            int k = i >> 7, nn = i & 127;
            wt1[nn * 256 + k] = f2bf(W1[i]);
            return;
        }
        i -= 32768;
        if (i < 16384) {            // layer2: [128][128]
            int k = i >> 7, nn = i & 127;
            wt2[nn * 128 + k] = f2bf(W2[i]);
            return;
        }
        i -= 16384;                 // layer3: [128][64] -> [64][128]
        int k = i >> 6, nn = i & 63;
        wt3[nn * 128 + k] = f2bf(W3[i]);
        return;
    }
    if (t >= 64) return;
    int cb = gb - 2593;
    const float* W; const float* a; int cout;
    if (cb == 0) { W = We1; a = ae1; cout = 128; }
    else if (cb == 1) { W = We2; a = ae2; cout = 128; }
    else { W = We3; a = ae3; cout = 64; }
    float v = 0.f;
    for (int c = t; c < cout; c += 64) v += W[c] * a[c];
    for (int o = 32; o; o >>= 1) v += __shfl_xor(v, o);
    if (t == 0) ce[cb] = v;
}

// ---------------- pass 1: bucket edges (LDS histogram + chunk claim + staged write) ----
__global__ __launch_bounds__(256) void bucket_k(
    const int* __restrict__ ei, const float* __restrict__ ew,
    unsigned* __restrict__ fill /* NB*16 padded */, uint2* __restrict__ regions) {
    __shared__ unsigned cnt[NB], lbase[NB], gb_s[NB], cur[NB];
    __shared__ unsigned ssum[256];
    __shared__ uint2 srec[BK_EDGES];
    __shared__ unsigned short sbkt[BK_EDGES];
    int t = threadIdx.x;
    for (int b = t; b < NB; b += 256) cnt[b] = 0;
    __syncthreads();
    int e0 = blockIdx.x * BK_EDGES;
    int dstv[EPT], srcv[EPT];
    unsigned wb[EPT];
#pragma unroll
    for (int j = 0; j < EPT; j++) {
        int e = e0 + j * 256 + t;
        dstv[j] = -1;
        if (e < NEDGES) {
            int dd = ei[NEDGES + e];
            int ss = ei[e];
            if ((unsigned)dd < (unsigned)NNODES && (unsigned)ss < (unsigned)NNODES) {
                dstv[j] = dd; srcv[j] = ss; wb[j] = __float_as_uint(ew[e]);
            }
        }
        if (dstv[j] >= 0) atomicAdd(&cnt[dstv[j] >> 8], 1u);
    }
    __syncthreads();
    unsigned c0 = cnt[t];
    unsigned c1 = (t + 256 < NB) ? cnt[t + 256] : 0u;
    ssum[t] = c0 + c1;
    __syncthreads();
    for (int off = 1; off < 256; off <<= 1) {
        unsigned v = (t >= off) ? ssum[t - off] : 0u;
        __syncthreads();
        ssum[t] += v;
        __syncthreads();
    }
    unsigned excl = ssum[t] - (c0 + c1);
    lbase[t] = excl; cur[t] = excl;
    gb_s[t] = c0 ? atomicAdd(&fill[t * 16], c0) : 0u;
    if (t + 256 < NB) {
        lbase[t + 256] = excl + c0; cur[t + 256] = excl + c0;
        gb_s[t + 256] = c1 ? atomicAdd(&fill[(t + 256) * 16], c1) : 0u;
    }
    __syncthreads();
#pragma unroll
    for (int j = 0; j < EPT; j++) {
        if (dstv[j] >= 0) {
            unsigned b = (unsigned)dstv[j] >> 8;
            unsigned p = atomicAdd(&cur[b], 1u);
            srec[p] = make_uint2(((unsigned)(dstv[j] & 255) << 24) | (unsigned)srcv[j], wb[j]);
            sbkt[p] = (unsigned short)b;
        }
    }
    __syncthreads();
    unsigned tot = ssum[255];
    for (unsigned i = t; i < tot; i += 256) {
        unsigned b = sbkt[i];
        unsigned slot = gb_s[b] + (i - lbase[b]);
        if (slot < CAP) regions[(size_t)b * CAP + slot] = srec[i];
    }
}

// ---------------- bucket totals scan -> bucket_base, row_start[N] ----------------
__global__ void bucket_scan_k(const unsigned* __restrict__ fill,
                              unsigned* __restrict__ bucket_base, int* __restrict__ row_start) {
    __shared__ unsigned s[512];
    int t = threadIdx.x;
    unsigned c = 0;
    if (t < NB) {
        unsigned sz = fill[t * 16];
        if (sz > CAP) sz = CAP;
        int nv = NNODES - (t << 8);
        if (nv > 256) nv = 256;
        if (nv < 0) nv = 0;
        c = sz + (unsigned)nv;
    }
    s[t] = c;
    __syncthreads();
    for (int off = 1; off < 512; off <<= 1) {
        unsigned v = (t >= off) ? s[t - off] : 0u;
        __syncthreads();
        s[t] += v;
        __syncthreads();
    }
    if (t < NB) bucket_base[t] = s[t] - c;
    if (t == 511) row_start[NNODES] = (int)s[511];
}

// ---------------- pass 2: per-bucket place (deg/sum count, seg scan, exact CSR) ----
__global__ __launch_bounds__(512) void place_k(
    const uint2* __restrict__ regions, const unsigned* __restrict__ fill,
    const unsigned* __restrict__ bucket_base, int2* __restrict__ eswr,
    int* __restrict__ row_start) {
    __shared__ uint2 rec[CAP];
    __shared__ unsigned deg[256], sumw[256], sc[256], seg[256], cur[256];
    int b = blockIdx.x, t = threadIdx.x;
    unsigned size = fill[b * 16];
    if (size > CAP) size = CAP;
    int dst0 = b << 8;
    int nvalid = NNODES - dst0;
    if (nvalid > 256) nvalid = 256;
    if (nvalid < 0) nvalid = 0;
    if (t < 256) { deg[t] = 0; sumw[t] = 0; }
    __syncthreads();
    for (unsigned i = t; i < size; i += 512) {
        uint2 r = regions[(size_t)b * CAP + i];
        rec[i] = r;
        unsigned dl = r.x >> 24;
        atomicAdd(&deg[dl], 1u);
        atomicAdd(&sumw[dl], __float2uint_rn(__uint_as_float(r.y) * 16777216.0f));
    }
    __syncthreads();
    unsigned cnti = (t < (unsigned)nvalid) ? deg[t] + 1u : 0u;
    if (t < 256) sc[t] = cnti;
    __syncthreads();
    for (int off = 1; off < 256; off <<= 1) {
        unsigned v = (t >= off && t < 256) ? sc[t - off] : 0u;
        __syncthreads();
        if (t < 256) sc[t] += v;
        __syncthreads();
    }
    unsigned bb = bucket_base[b];
    if (t < 256) {
        unsigned excl = sc[t] - cnti;
        seg[t] = excl;
        cur[t] = excl + 1u;
        if (t < (unsigned)nvalid) {
            int dst = dst0 + t;
            row_start[dst] = (int)(bb + excl);
            float sw = (float)sumw[t] * (1.0f / 16777216.0f);
            int dg = (int)deg[t];
            float w = sw / (float)(dg > 1 ? dg : 1);
            eswr[bb + excl] = make_int2(dst, __float_as_int(w));  // self-loop at slot 0
        }
    }
    __syncthreads();
    for (unsigned i = t; i < size; i += 512) {
        uint2 r = rec[i];
        unsigned dl = r.x >> 24;
        unsigned p = atomicAdd(&cur[dl], 1u);
        eswr[bb + p] = make_int2((int)(r.x & 0xFFFFFFu), (int)r.y);
    }
}

// ---------------- MFMA GEMM: H(bf16) = X @ W, fused s/d partial dots ----------------
template <bool ABF16>
__global__ __launch_bounds__(256) void gemm_mfma(
    const void* __restrict__ Xv, const unsigned short* __restrict__ Wt,
    unsigned short* __restrict__ H, const float* __restrict__ as_,
    const float* __restrict__ ad_, float* __restrict__ s, float* __restrict__ d,
    int nrows, int cin, int cout) {
    __shared__ __align__(16) unsigned short lA[64 * 40];
    __shared__ __align__(16) unsigned short lB[64 * 40];
    int t = threadIdx.x;
    int wv = t >> 6, lane = t & 63;
    int lr = lane & 15, lg = lane >> 4;
    int row0 = blockIdx.x * 64, col0 = blockIdx.y * 64;
    int sr = t >> 2, sc = (t & 3) * 8;

    facc4 acc[4] = {};
    bool rowok = (row0 + sr) < nrows;
    const unsigned short* wrow = Wt + (size_t)(col0 + sr) * cin;

    for (int k0 = 0; k0 < cin; k0 += 32) {
        union { bfrag8 v; unsigned short u[8]; } pa;
        if (rowok) {
            if constexpr (ABF16) {
                const unsigned short* xrow = (const unsigned short*)Xv + (size_t)(row0 + sr) * cin;
                pa.v = *(const bfrag8*)&xrow[k0 + sc];
            } else {
                const float* xrow = (const float*)Xv + (size_t)(row0 + sr) * cin;
                float4 v0 = *(const float4*)&xrow[k0 + sc];
                float4 v1 = *(const float4*)&xrow[k0 + sc + 4];
                pa.u[0] = f2bf(v0.x); pa.u[1] = f2bf(v0.y);
                pa.u[2] = f2bf(v0.z); pa.u[3] = f2bf(v0.w);
                pa.u[4] = f2bf(v1.x); pa.u[5] = f2bf(v1.y);
                pa.u[6] = f2bf(v1.z); pa.u[7] = f2bf(v1.w);
            }
        } else {
#pragma unroll
            for (int j = 0; j < 8; j++) pa.u[j] = 0;
        }
        *(bfrag8*)&lA[sr * 40 + sc] = pa.v;
        *(bfrag8*)&lB[sr * 40 + sc] = *(const bfrag8*)&wrow[k0 + sc];
        __syncthreads();
        bfrag8 a = *(const bfrag8*)&lA[(wv * 16 + lr) * 40 + lg * 8];
#pragma unroll
        for (int n0 = 0; n0 < 4; n0++) {
            bfrag8 bfr = *(const bfrag8*)&lB[(n0 * 16 + lr) * 40 + lg * 8];
            acc[n0] = __builtin_amdgcn_mfma_f32_16x16x32_bf16(a, bfr, acc[n0], 0, 0, 0);
        }
        __syncthreads();
    }
#pragma unroll
    for (int r = 0; r < 4; r++) {
        int row = row0 + wv * 16 + lg * 4 + r;
        if (row >= nrows) continue;
        float ps = 0.f, pd = 0.f;
#pragma unroll
        for (int n0 = 0; n0 < 4; n0++) {
            int col = col0 + n0 * 16 + lr;
            float v = acc[n0][r];
            H[(size_t)row * cout + col] = f2bf(v);
            ps += v * as_[col];
            pd += v * ad_[col];
        }
        for (int o = 8; o; o >>= 1) {
            ps += __shfl_xor(ps, o);
            pd += __shfl_xor(pd, o);
        }
        if (lr == 0) {
            atomicAdd(&s[row], ps);
            atomicAdd(&d[row], pd);
        }
    }
}

// ---------------- attention + aggregation: one wave per dst node (bf16 h) ----------
// pass 2: 16 lanes x 16B per edge row (cout=128) -> 4 edges/iter, deep unroll for MLP
template <bool OBF16>
__global__ __launch_bounds__(256) void agg_k(
    const int2* __restrict__ eswr, const int* __restrict__ row_start,
    const unsigned short* __restrict__ h, const float* __restrict__ s,
    const float* __restrict__ d, const float* __restrict__ ce_ptr,
    const float* __restrict__ bias, void* __restrict__ outv, int n, int cout) {
    __shared__ int2 es[4][MAXE];   // {src, logit->ex}
    int wslot = threadIdx.x >> 6;
    int wid = (blockIdx.x * blockDim.x + threadIdx.x) >> 6;
    int lane = threadIdx.x & 63;
    if (wid >= n) return;
    int lo = row_start[wid], ne = row_start[wid + 1] - lo;
    float ce = *ce_ptr;
    float di = d[wid];

    if (ne <= MAXE) {
        // pass 1: lane-parallel logits cached in LDS as {src, logit}
        float m = -1e30f;
        for (int e = lane; e < ne; e += 64) {
            int2 ev = eswr[lo + e];
            float lg = s[ev.x] + di + ce * __int_as_float(ev.y);
            lg = lg > 0.f ? lg : 0.2f * lg;
            es[wslot][e] = make_int2(ev.x, __float_as_int(lg));
            m = fmaxf(m, lg);
        }
        for (int o = 32; o; o >>= 1) m = fmaxf(m, __shfl_xor(m, o));
        float den = 0.f;
        for (int e = lane; e < ne; e += 64) {
            float exv = __expf(__int_as_float(es[wslot][e].y) - m);
            es[wslot][e].y = __float_as_int(exv);
            den += exv;
        }
        for (int o = 32; o; o >>= 1) den += __shfl_xor(den, o);
        float inv = 1.0f / (den + 1e-16f);

        float a0 = 0.f, a1 = 0.f, a2 = 0.f, a3 = 0.f;
        float a4 = 0.f, a5 = 0.f, a6 = 0.f, a7 = 0.f;
        if (cout == 128) {
            // 4 edges/iter x 16 lanes x dwordx4: lane = eg*16 + cb
            int eg = lane >> 4, cb = lane & 15;
            const uint4* h16 = (const uint4*)h;   // row = 16 x 16B
#pragma unroll 4
            for (int e = eg; e < ne; e += 4) {
                int2 ev2 = es[wslot][e];
                float exv = __int_as_float(ev2.y);
                uint4 hv = h16[(size_t)ev2.x * 16 + cb];
                a0 += exv * __uint_as_float(hv.x << 16);
                a1 += exv * __uint_as_float(hv.x & 0xffff0000u);
                a2 += exv * __uint_as_float(hv.y << 16);
                a3 += exv * __uint_as_float(hv.y & 0xffff0000u);
                a4 += exv * __uint_as_float(hv.z << 16);
                a5 += exv * __uint_as_float(hv.z & 0xffff0000u);
                a6 += exv * __uint_as_float(hv.w << 16);
                a7 += exv * __uint_as_float(hv.w & 0xffff0000u);
            }
            a0 += __shfl_xor(a0, 16); a1 += __shfl_xor(a1, 16);
            a2 += __shfl_xor(a2, 16); a3 += __shfl_xor(a3, 16);
            a4 += __shfl_xor(a4, 16); a5 += __shfl_xor(a5, 16);
            a6 += __shfl_xor(a6, 16); a7 += __shfl_xor(a7, 16);
            a0 += __shfl_xor(a0, 32); a1 += __shfl_xor(a1, 32);
            a2 += __shfl_xor(a2, 32); a3 += __shfl_xor(a3, 32);
            a4 += __shfl_xor(a4, 32); a5 += __shfl_xor(a5, 32);
            a6 += __shfl_xor(a6, 32); a7 += __shfl_xor(a7, 32);
            if (eg == 0) {
                float4 b0 = ((const float4*)bias)[cb * 2];
                float4 b1 = ((const float4*)bias)[cb * 2 + 1];
                float o0 = a0 * inv + b0.x; o0 = o0 > 0.f ? o0 : 0.01f * o0;
                float o1 = a1 * inv + b0.y; o1 = o1 > 0.f ? o1 : 0.01f * o1;
                float o2 = a2 * inv + b0.z; o2 = o2 > 0.f ? o2 : 0.01f * o2;
                float o3 = a3 * inv + b0.w; o3 = o3 > 0.f ? o3 : 0.01f * o3;
                float o4 = a4 * inv + b1.x; o4 = o4 > 0.f ? o4 : 0.01f * o4;
                float o5 = a5 * inv + b1.y; o5 = o5 > 0.f ? o5 : 0.01f * o5;
                float o6 = a6 * inv + b1.z; o6 = o6 > 0.f ? o6 : 0.01f * o6;
                float o7 = a7 * inv + b1.w; o7 = o7 > 0.f ? o7 : 0.01f * o7;
                if constexpr (OBF16) {
                    ushortv8 ov;
                    ov[0] = f2bf(o0); ov[1] = f2bf(o1); ov[2] = f2bf(o2); ov[3] = f2bf(o3);
                    ov[4] = f2bf(o4); ov[5] = f2bf(o5); ov[6] = f2bf(o6); ov[7] = f2bf(o7);
                    ((ushortv8*)outv)[(size_t)wid * 16 + cb] = ov;
                } else {
                    float* op = (float*)outv + (size_t)wid * 128 + cb * 8;
                    *(float4*)op = make_float4(o0, o1, o2, o3);
                    *(float4*)(op + 4) = make_float4(o4, o5, o6, o7);
                }
            }
        } else {
            // cout==64: 8 edges/iter x 8 lanes x dwordx4
            int eg = lane >> 3, cb = lane & 7;
            const uint4* h16 = (const uint4*)h;   // row = 8 x 16B
#pragma unroll 2
            for (int e = eg; e < ne; e += 8) {
                int2 ev2 = es[wslot][e];
                float exv = __int_as_float(ev2.y);
                uint4 hv = h16[(size_t)ev2.x * 8 + cb];
                a0 += exv * __uint_as_float(hv.x << 16);
                a1 += exv * __uint_as_float(hv.x & 0xffff0000u);
                a2 += exv * __uint_as_float(hv.y << 16);
                a3 += exv * __uint_as_float(hv.y & 0xffff0000u);
                a4 += exv * __uint_as_float(hv.z << 16);
                a5 += exv * __uint_as_float(hv.z & 0xffff0000u);
                a6 += exv * __uint_as_float(hv.w << 16);
                a7 += exv * __uint_as_float(hv.w & 0xffff0000u);
            }
            a0 += __shfl_xor(a0, 8); a1 += __shfl_xor(a1, 8);
            a2 += __shfl_xor(a2, 8); a3 += __shfl_xor(a3, 8);
            a4 += __shfl_xor(a4, 8); a5 += __shfl_xor(a5, 8);
            a6 += __shfl_xor(a6, 8); a7 += __shfl_xor(a7, 8);
            a0 += __shfl_xor(a0, 16); a1 += __shfl_xor(a1, 16);
            a2 += __shfl_xor(a2, 16); a3 += __shfl_xor(a3, 16);
            a4 += __shfl_xor(a4, 16); a5 += __shfl_xor(a5, 16);
            a6 += __shfl_xor(a6, 16); a7 += __shfl_xor(a7, 16);
            a0 += __shfl_xor(a0, 32); a1 += __shfl_xor(a1, 32);
            a2 += __shfl_xor(a2, 32); a3 += __shfl_xor(a3, 32);
            a4 += __shfl_xor(a4, 32); a5 += __shfl_xor(a5, 32);
            a6 += __shfl_xor(a6, 32); a7 += __shfl_xor(a7, 32);
            if (eg == 0) {
                float4 b0 = ((const float4*)bias)[cb * 2];
                float4 b1 = ((const float4*)bias)[cb * 2 + 1];
                float o0 = a0 * inv + b0.x; o0 = o0 > 0.f ? o0 : 0.01f * o0;
                float o1 = a1 * inv + b0.y; o1 = o1 > 0.f ? o1 : 0.01f * o1;
                float o2 = a2 * inv + b0.z; o2 = o2 > 0.f ? o2 : 0.01f * o2;
                float o3 = a3 * inv + b0.w; o3 = o3 > 0.f ? o3 : 0.01f * o3;
                float o4 = a4 * inv + b1.x; o4 = o4 > 0.f ? o4 : 0.01f * o4;
                float o5 = a5 * inv + b1.y; o5 = o5 > 0.f ? o5 : 0.01f * o5;
                float o6 = a6 * inv + b1.z; o6 = o6 > 0.f ? o6 : 0.01f * o6;
                float o7 = a7 * inv + b1.w; o7 = o7 > 0.f ? o7 : 0.01f * o7;
                if constexpr (OBF16) {
                    ushortv8 ov;
                    ov[0] = f2bf(o0); ov[1] = f2bf(o1); ov[2] = f2bf(o2); ov[3] = f2bf(o3);
                    ov[4] = f2bf(o4); ov[5] = f2bf(o5); ov[6] = f2bf(o6); ov[7] = f2bf(o7);
                    ((ushortv8*)outv)[(size_t)wid * 8 + cb] = ov;
                } else {
                    float* op = (float*)outv + (size_t)wid * 64 + cb * 8;
                    *(float4*)op = make_float4(o0, o1, o2, o3);
                    *(float4*)(op + 4) = make_float4(o4, o5, o6, o7);
                }
            }
        }
        return;
    }

    // ---- fallback (degree > MAXE): serial path, never hit for this graph ----
    float m = -1e30f;
    for (int e = lane; e < ne; e += 64) {
        int2 ev = eswr[lo + e];
        float lg = s[ev.x] + di + ce * __int_as_float(ev.y);
        lg = lg > 0.f ? lg : 0.2f * lg;
        m = fmaxf(m, lg);
    }
    for (int o = 32; o; o >>= 1) m = fmaxf(m, __shfl_xor(m, o));
    float den = 0.f;
    int c0 = lane, c1 = lane + 64;
    float a0 = 0.f, a1 = 0.f;
    for (int e = 0; e < ne; e++) {
        int2 ev = eswr[lo + e];
        float lg = s[ev.x] + di + ce * __int_as_float(ev.y);
        lg = lg > 0.f ? lg : 0.2f * lg;
        float ex = __expf(lg - m);
        den += ex;
        const unsigned short* hr = &h[(size_t)ev.x * cout];
        a0 += ex * bf2f(hr[c0]);
        if (cout > 64) a1 += ex * bf2f(hr[c1]);
    }
    float inv = 1.0f / (den + 1e-16f);
    float o0 = a0 * inv + bias[c0];
    o0 = o0 > 0.f ? o0 : 0.01f * o0;
    float o1 = 0.f;
    if (cout > 64) {
        o1 = a1 * inv + bias[c1];
        o1 = o1 > 0.f ? o1 : 0.01f * o1;
    }
    if constexpr (OBF16) {
        unsigned short* out = (unsigned short*)outv;
        out[(size_t)wid * cout + c0] = f2bf(o0);
        if (cout > 64) out[(size_t)wid * cout + c1] = f2bf(o1);
    } else {
        float* out = (float*)outv;
        out[(size_t)wid * cout + c0] = o0;
        if (cout > 64) out[(size_t)wid * cout + c1] = o1;
    }
}

extern "C" void kernel_launch(void* const* d_in, const int* in_sizes, int n_in,
                              void* d_out, int out_size, void* d_ws, size_t ws_size,
                              hipStream_t stream) {
    const int N = NNODES, E = NEDGES, EF = NEDGES + NNODES;

    const float* x = (const float*)d_in[0];
    const int* ei = (const int*)d_in[1];   // int32 on device
    const float* ew = (const float*)d_in[2];
    const float* W1 = (const float*)d_in[3];
    const float* as1 = (const float*)d_in[4];
    const float* ad1 = (const float*)d_in[5];
    const float* We1 = (const float*)d_in[6];
    const float* ae1 = (const float*)d_in[7];
    const float* b1 = (const float*)d_in[8];
    const float* W2 = (const float*)d_in[9];
    const float* as2 = (const float*)d_in[10];
    const float* ad2 = (const float*)d_in[11];
    const float* We2 = (const float*)d_in[12];
    const float* ae2 = (const float*)d_in[13];
    const float* b2 = (const float*)d_in[14];
    const float* W3 = (const float*)d_in[15];
    const float* as3 = (const float*)d_in[16];
    const float* ad3 = (const float*)d_in[17];
    const float* We3 = (const float*)d_in[18];
    const float* ae3 = (const float*)d_in[19];
    const float* b3 = (const float*)d_in[20];
    float* out = (float*)d_out;

    // workspace layout (aligned bump allocator). sd and fill must be adjacent (one zero).
    char* wp = (char*)d_ws;
    auto alloc = [&](size_t bytes, size_t align) -> void* {
        size_t a = ((size_t)wp + align - 1) & ~(align - 1);
        wp = (char*)(a + bytes);
        return (void*)a;
    };
    float* sd = (float*)alloc((size_t)6 * N * 4, 16);            // s1,d1,s2,d2,s3,d3
    unsigned* fill = (unsigned*)alloc((size_t)NB * 16 * 4, 4);   // padded bucket counters
    unsigned short* act = (unsigned short*)alloc((size_t)N * 128 * 2, 16);
    unsigned short* h = (unsigned short*)alloc((size_t)N * 128 * 2, 16);
    int* row_start = (int*)alloc((size_t)(N + 1) * 4, 4);
    unsigned* bucket_base = (unsigned*)alloc((size_t)NB * 4, 4);
    int2* eswr = (int2*)alloc((size_t)EF * 8, 16);
    uint2* regions = (uint2*)alloc((size_t)NB * CAP * 8, 16);
    float* ce = (float*)alloc(4 * 4, 4);
    unsigned short* wt1 = (unsigned short*)alloc(32768 * 2, 16);
    unsigned short* wt2 = (unsigned short*)alloc(16384 * 2, 16);
    unsigned short* wt3 = (unsigned short*)alloc(8192 * 2, 16);

    // ---- init: zero sd+fill, transpose weights, ce dots (one fused launch) ----
    init_k<<<2596, 256, 0, stream>>>((int*)sd, W1, W2, W3, wt1, wt2, wt3,
                                     We1, ae1, We2, ae2, We3, ae3, ce);
    // ---- CSR build via two-level bucket sort ----
    bucket_k<<<BK_BLOCKS, 256, 0, stream>>>(ei, ew, fill, regions);
    bucket_scan_k<<<1, 512, 0, stream>>>(fill, bucket_base, row_start);
    place_k<<<NB, 512, 0, stream>>>(regions, fill, bucket_base, eswr, row_start);

    // ---- layer 1: 256 -> 128 ----
    {
        int cin = 256, cout = 128;
        dim3 grid((N + 63) / 64, cout / 64);
        gemm_mfma<false><<<grid, 256, 0, stream>>>(x, wt1, h, as1, ad1,
                                                   sd + 0 * N, sd + 1 * N, N, cin, cout);
        agg_k<true><<<(N + 3) / 4, 256, 0, stream>>>(eswr, row_start, h, sd + 0 * N,
                                                     sd + 1 * N, ce + 0, b1, act, N, cout);
    }
    // ---- layer 2: 128 -> 128 ----
    {
        int cin = 128, cout = 128;
        dim3 grid((N + 63) / 64, cout / 64);
        gemm_mfma<true><<<grid, 256, 0, stream>>>(act, wt2, h, as2, ad2,
                                                  sd + 2 * N, sd + 3 * N, N, cin, cout);
        agg_k<true><<<(N + 3) / 4, 256, 0, stream>>>(eswr, row_start, h, sd + 2 * N,
                                                     sd + 3 * N, ce + 1, b2, act, N, cout);
    }
    // ---- layer 3: 128 -> 64 ----
    {
        int cin = 128, cout = 64;
        dim3 grid((N + 63) / 64, cout / 64);
        gemm_mfma<true><<<grid, 256, 0, stream>>>(act, wt3, h, as3, ad3,
                                                  sd + 4 * N, sd + 5 * N, N, cin, cout);
        agg_k<false><<<(N + 3) / 4, 256, 0, stream>>>(eswr, row_start, h, sd + 4 * N,
                                                      sd + 5 * N, ce + 2, b3, out, N, cout);
    }
}

// Round 10
// 374.883 us; speedup vs baseline: 3.4942x; 1.0221x over previous
//
#include <hip/hip_runtime.h>
#include <hip/hip_bf16.h>
#include <math.h>

#define NNODES 100000
#define NEDGES 1600000
#define MAXE 128
#define NB 391                 // buckets of 256 dsts: ceil(100000/256)
#define CAP 6144               // region capacity per bucket (mean ~4090, 32 sigma headroom)
#define EPT 7
#define BK_EDGES (256 * EPT)   // 1792 edges per block
#define BK_BLOCKS ((NEDGES + BK_EDGES - 1) / BK_EDGES)  // 893

typedef short bfrag8 __attribute__((ext_vector_type(8)));  // 8 bf16 (4 VGPRs)
typedef float facc4 __attribute__((ext_vector_type(4)));   // 4 fp32 acc
typedef unsigned short ushortv8 __attribute__((ext_vector_type(8)));
typedef unsigned long long ull;

__device__ __forceinline__ unsigned short f2bf(float f) {
    unsigned u = __float_as_uint(f);
    unsigned r = u + 0x7fffu + ((u >> 16) & 1u);  // round-to-nearest-even
    return (unsigned short)(r >> 16);
}
__device__ __forceinline__ float bf2f(unsigned short u) {
    return __uint_as_float((unsigned)u << 16);
}

// ---------------- fused init: zero (sd+fill), Wt transpose, ce dots ----------------
__global__ void init_k(int* zbase,
                       const float* __restrict__ W1, const float* __restrict__ W2,
                       const float* __restrict__ W3, unsigned short* __restrict__ wt1,
                       unsigned short* __restrict__ wt2, unsigned short* __restrict__ wt3,
                       const float* We1, const float* ae1, const float* We2,
                       const float* ae2, const float* We3, const float* ae3, float* ce) {
    int gb = blockIdx.x, t = threadIdx.x;
    if (gb < 2369) {
        int i = gb * 256 + t;
        if (i < 6 * NNODES + NB * 16) zbase[i] = 0;
        return;
    }
    if (gb < 2593) {
        int i = (gb - 2369) * 256 + t;
        if (i < 32768) {            // layer1: [256][128] -> [128][256]
            int k = i >> 7, nn = i & 127;
            wt1[nn * 256 + k] = f2bf(W1[i]);
            return;
        }
        i -= 32768;
        if (i < 16384) {            // layer2: [128][128]
            int k = i >> 7, nn = i & 127;
            wt2[nn * 128 + k] = f2bf(W2[i]);
            return;
        }
        i -= 16384;                 // layer3: [128][64] -> [64][128]
        int k = i >> 6, nn = i & 63;
        wt3[nn * 128 + k] = f2bf(W3[i]);
        return;
    }
    if (t >= 64) return;
    int cb = gb - 2593;
    const float* W; const float* a; int cout;
    if (cb == 0) { W = We1; a = ae1; cout = 128; }
    else if (cb == 1) { W = We2; a = ae2; cout = 128; }
    else { W = We3; a = ae3; cout = 64; }
    float v = 0.f;
    for (int c = t; c < cout; c += 64) v += W[c] * a[c];
    for (int o = 32; o; o >>= 1) v += __shfl_xor(v, o);
    if (t == 0) ce[cb] = v;
}

// ---------------- pass 1: bucket edges (LDS histogram + chunk claim + staged write) ----
__global__ __launch_bounds__(256) void bucket_k(
    const int* __restrict__ ei, const float* __restrict__ ew,
    unsigned* __restrict__ fill /* NB*16 padded */, uint2* __restrict__ regions) {
    __shared__ unsigned cnt[NB], lbase[NB], gb_s[NB], cur[NB];
    __shared__ unsigned ssum[256];
    __shared__ uint2 srec[BK_EDGES];
    __shared__ unsigned short sbkt[BK_EDGES];
    int t = threadIdx.x;
    for (int b = t; b < NB; b += 256) cnt[b] = 0;
    __syncthreads();
    int e0 = blockIdx.x * BK_EDGES;
    int dstv[EPT], srcv[EPT];
    unsigned wb[EPT];
#pragma unroll
    for (int j = 0; j < EPT; j++) {
        int e = e0 + j * 256 + t;
        dstv[j] = -1;
        if (e < NEDGES) {
            int dd = ei[NEDGES + e];
            int ss = ei[e];
            if ((unsigned)dd < (unsigned)NNODES && (unsigned)ss < (unsigned)NNODES) {
                dstv[j] = dd; srcv[j] = ss; wb[j] = __float_as_uint(ew[e]);
            }
        }
        if (dstv[j] >= 0) atomicAdd(&cnt[dstv[j] >> 8], 1u);
    }
    __syncthreads();
    unsigned c0 = cnt[t];
    unsigned c1 = (t + 256 < NB) ? cnt[t + 256] : 0u;
    ssum[t] = c0 + c1;
    __syncthreads();
    for (int off = 1; off < 256; off <<= 1) {
        unsigned v = (t >= off) ? ssum[t - off] : 0u;
        __syncthreads();
        ssum[t] += v;
        __syncthreads();
    }
    unsigned excl = ssum[t] - (c0 + c1);
    lbase[t] = excl; cur[t] = excl;
    gb_s[t] = c0 ? atomicAdd(&fill[t * 16], c0) : 0u;
    if (t + 256 < NB) {
        lbase[t + 256] = excl + c0; cur[t + 256] = excl + c0;
        gb_s[t + 256] = c1 ? atomicAdd(&fill[(t + 256) * 16], c1) : 0u;
    }
    __syncthreads();
#pragma unroll
    for (int j = 0; j < EPT; j++) {
        if (dstv[j] >= 0) {
            unsigned b = (unsigned)dstv[j] >> 8;
            unsigned p = atomicAdd(&cur[b], 1u);
            srec[p] = make_uint2(((unsigned)(dstv[j] & 255) << 24) | (unsigned)srcv[j], wb[j]);
            sbkt[p] = (unsigned short)b;
        }
    }
    __syncthreads();
    unsigned tot = ssum[255];
    for (unsigned i = t; i < tot; i += 256) {
        unsigned b = sbkt[i];
        unsigned slot = gb_s[b] + (i - lbase[b]);
        if (slot < CAP) regions[(size_t)b * CAP + slot] = srec[i];
    }
}

// ---------------- bucket totals scan -> bucket_base, row_start[N] ----------------
__global__ void bucket_scan_k(const unsigned* __restrict__ fill,
                              unsigned* __restrict__ bucket_base, int* __restrict__ row_start) {
    __shared__ unsigned s[512];
    int t = threadIdx.x;
    unsigned c = 0;
    if (t < NB) {
        unsigned sz = fill[t * 16];
        if (sz > CAP) sz = CAP;
        int nv = NNODES - (t << 8);
        if (nv > 256) nv = 256;
        if (nv < 0) nv = 0;
        c = sz + (unsigned)nv;
    }
    s[t] = c;
    __syncthreads();
    for (int off = 1; off < 512; off <<= 1) {
        unsigned v = (t >= off) ? s[t - off] : 0u;
        __syncthreads();
        s[t] += v;
        __syncthreads();
    }
    if (t < NB) bucket_base[t] = s[t] - c;
    if (t == 511) row_start[NNODES] = (int)s[511];
}

// ---------------- pass 2: per-bucket place (deg/sum count, seg scan, exact CSR) ----
__global__ __launch_bounds__(512) void place_k(
    const uint2* __restrict__ regions, const unsigned* __restrict__ fill,
    const unsigned* __restrict__ bucket_base, int2* __restrict__ eswr,
    int* __restrict__ row_start) {
    __shared__ uint2 rec[CAP];
    __shared__ unsigned deg[256], sumw[256], sc[256], seg[256], cur[256];
    int b = blockIdx.x, t = threadIdx.x;
    unsigned size = fill[b * 16];
    if (size > CAP) size = CAP;
    int dst0 = b << 8;
    int nvalid = NNODES - dst0;
    if (nvalid > 256) nvalid = 256;
    if (nvalid < 0) nvalid = 0;
    if (t < 256) { deg[t] = 0; sumw[t] = 0; }
    __syncthreads();
    for (unsigned i = t; i < size; i += 512) {
        uint2 r = regions[(size_t)b * CAP + i];
        rec[i] = r;
        unsigned dl = r.x >> 24;
        atomicAdd(&deg[dl], 1u);
        atomicAdd(&sumw[dl], __float2uint_rn(__uint_as_float(r.y) * 16777216.0f));
    }
    __syncthreads();
    unsigned cnti = (t < (unsigned)nvalid) ? deg[t] + 1u : 0u;
    if (t < 256) sc[t] = cnti;
    __syncthreads();
    for (int off = 1; off < 256; off <<= 1) {
        unsigned v = (t >= off && t < 256) ? sc[t - off] : 0u;
        __syncthreads();
        if (t < 256) sc[t] += v;
        __syncthreads();
    }
    unsigned bb = bucket_base[b];
    if (t < 256) {
        unsigned excl = sc[t] - cnti;
        seg[t] = excl;
        cur[t] = excl + 1u;
        if (t < (unsigned)nvalid) {
            int dst = dst0 + t;
            row_start[dst] = (int)(bb + excl);
            float sw = (float)sumw[t] * (1.0f / 16777216.0f);
            int dg = (int)deg[t];
            float w = sw / (float)(dg > 1 ? dg : 1);
            eswr[bb + excl] = make_int2(dst, __float_as_int(w));  // self-loop at slot 0
        }
    }
    __syncthreads();
    for (unsigned i = t; i < size; i += 512) {
        uint2 r = rec[i];
        unsigned dl = r.x >> 24;
        unsigned p = atomicAdd(&cur[dl], 1u);
        eswr[bb + p] = make_int2((int)(r.x & 0xFFFFFFu), (int)r.y);
    }
}

// ---------------- MFMA GEMM: H(bf16) = X @ W, fused s/d partial dots ----------------
// NC col-blocks of 64 computed per block from ONE staged A tile (A read once from HBM).
template <bool ABF16, int NC>
__global__ __launch_bounds__(256) void gemm_mfma(
    const void* __restrict__ Xv, const unsigned short* __restrict__ Wt,
    unsigned short* __restrict__ H, const float* __restrict__ as_,
    const float* __restrict__ ad_, float* __restrict__ s, float* __restrict__ d,
    int nrows, int cin, int cout) {
    __shared__ __align__(16) unsigned short lA[64 * 40];
    __shared__ __align__(16) unsigned short lB[NC * 64 * 40];
    int t = threadIdx.x;
    int wv = t >> 6, lane = t & 63;
    int lr = lane & 15, lg = lane >> 4;
    int row0 = blockIdx.x * 64;
    int sr = t >> 2, sc = (t & 3) * 8;

    facc4 acc[NC][4] = {};
    bool rowok = (row0 + sr) < nrows;

    for (int k0 = 0; k0 < cin; k0 += 32) {
        union { bfrag8 v; unsigned short u[8]; } pa;
        if (rowok) {
            if constexpr (ABF16) {
                const unsigned short* xrow = (const unsigned short*)Xv + (size_t)(row0 + sr) * cin;
                pa.v = *(const bfrag8*)&xrow[k0 + sc];
            } else {
                const float* xrow = (const float*)Xv + (size_t)(row0 + sr) * cin;
                float4 v0 = *(const float4*)&xrow[k0 + sc];
                float4 v1 = *(const float4*)&xrow[k0 + sc + 4];
                pa.u[0] = f2bf(v0.x); pa.u[1] = f2bf(v0.y);
                pa.u[2] = f2bf(v0.z); pa.u[3] = f2bf(v0.w);
                pa.u[4] = f2bf(v1.x); pa.u[5] = f2bf(v1.y);
                pa.u[6] = f2bf(v1.z); pa.u[7] = f2bf(v1.w);
            }
        } else {
#pragma unroll
            for (int j = 0; j < 8; j++) pa.u[j] = 0;
        }
        *(bfrag8*)&lA[sr * 40 + sc] = pa.v;
#pragma unroll
        for (int cb = 0; cb < NC; cb++) {
            *(bfrag8*)&lB[(cb * 64 + sr) * 40 + sc] =
                *(const bfrag8*)&Wt[(size_t)(cb * 64 + sr) * cin + k0 + sc];
        }
        __syncthreads();
        bfrag8 a = *(const bfrag8*)&lA[(wv * 16 + lr) * 40 + lg * 8];
#pragma unroll
        for (int cb = 0; cb < NC; cb++) {
#pragma unroll
            for (int n0 = 0; n0 < 4; n0++) {
                bfrag8 bfr = *(const bfrag8*)&lB[(cb * 64 + n0 * 16 + lr) * 40 + lg * 8];
                acc[cb][n0] = __builtin_amdgcn_mfma_f32_16x16x32_bf16(a, bfr, acc[cb][n0], 0, 0, 0);
            }
        }
        __syncthreads();
    }
#pragma unroll
    for (int r = 0; r < 4; r++) {
        int row = row0 + wv * 16 + lg * 4 + r;
        if (row >= nrows) continue;
        float ps = 0.f, pd = 0.f;
#pragma unroll
        for (int cb = 0; cb < NC; cb++) {
#pragma unroll
            for (int n0 = 0; n0 < 4; n0++) {
                int col = cb * 64 + n0 * 16 + lr;
                float v = acc[cb][n0][r];
                H[(size_t)row * cout + col] = f2bf(v);
                ps += v * as_[col];
                pd += v * ad_[col];
            }
        }
        for (int o = 8; o; o >>= 1) {
            ps += __shfl_xor(ps, o);
            pd += __shfl_xor(pd, o);
        }
        if (lr == 0) {
            atomicAdd(&s[row], ps);
            atomicAdd(&d[row], pd);
        }
    }
}

// ---------------- attention + aggregation: one wave per dst node (bf16 h) ----------
template <bool OBF16>
__global__ __launch_bounds__(256) void agg_k(
    const int2* __restrict__ eswr, const int* __restrict__ row_start,
    const unsigned short* __restrict__ h, const float* __restrict__ s,
    const float* __restrict__ d, const float* __restrict__ ce_ptr,
    const float* __restrict__ bias, void* __restrict__ outv, int n, int cout) {
    __shared__ int2 es[4][MAXE];   // {src, logit->ex}
    int wslot = threadIdx.x >> 6;
    int wid = (blockIdx.x * blockDim.x + threadIdx.x) >> 6;
    int lane = threadIdx.x & 63;
    if (wid >= n) return;
    int lo = row_start[wid], ne = row_start[wid + 1] - lo;
    float ce = *ce_ptr;
    float di = d[wid];

    if (ne <= MAXE) {
        float m = -1e30f;
        for (int e = lane; e < ne; e += 64) {
            int2 ev = eswr[lo + e];
            float lg = s[ev.x] + di + ce * __int_as_float(ev.y);
            lg = lg > 0.f ? lg : 0.2f * lg;
            es[wslot][e] = make_int2(ev.x, __float_as_int(lg));
            m = fmaxf(m, lg);
        }
        for (int o = 32; o; o >>= 1) m = fmaxf(m, __shfl_xor(m, o));
        float den = 0.f;
        for (int e = lane; e < ne; e += 64) {
            float exv = __expf(__int_as_float(es[wslot][e].y) - m);
            es[wslot][e].y = __float_as_int(exv);
            den += exv;
        }
        for (int o = 32; o; o >>= 1) den += __shfl_xor(den, o);
        float inv = 1.0f / (den + 1e-16f);

        float a0 = 0.f, a1 = 0.f, a2 = 0.f, a3 = 0.f;
        float a4 = 0.f, a5 = 0.f, a6 = 0.f, a7 = 0.f;
        if (cout == 128) {
            int eg = lane >> 4, cb = lane & 15;
            const uint4* h16 = (const uint4*)h;
#pragma unroll 4
            for (int e = eg; e < ne; e += 4) {
                int2 ev2 = es[wslot][e];
                float exv = __int_as_float(ev2.y);
                uint4 hv = h16[(size_t)ev2.x * 16 + cb];
                a0 += exv * __uint_as_float(hv.x << 16);
                a1 += exv * __uint_as_float(hv.x & 0xffff0000u);
                a2 += exv * __uint_as_float(hv.y << 16);
                a3 += exv * __uint_as_float(hv.y & 0xffff0000u);
                a4 += exv * __uint_as_float(hv.z << 16);
                a5 += exv * __uint_as_float(hv.z & 0xffff0000u);
                a6 += exv * __uint_as_float(hv.w << 16);
                a7 += exv * __uint_as_float(hv.w & 0xffff0000u);
            }
            a0 += __shfl_xor(a0, 16); a1 += __shfl_xor(a1, 16);
            a2 += __shfl_xor(a2, 16); a3 += __shfl_xor(a3, 16);
            a4 += __shfl_xor(a4, 16); a5 += __shfl_xor(a5, 16);
            a6 += __shfl_xor(a6, 16); a7 += __shfl_xor(a7, 16);
            a0 += __shfl_xor(a0, 32); a1 += __shfl_xor(a1, 32);
            a2 += __shfl_xor(a2, 32); a3 += __shfl_xor(a3, 32);
            a4 += __shfl_xor(a4, 32); a5 += __shfl_xor(a5, 32);
            a6 += __shfl_xor(a6, 32); a7 += __shfl_xor(a7, 32);
            if (eg == 0) {
                float4 b0 = ((const float4*)bias)[cb * 2];
                float4 b1 = ((const float4*)bias)[cb * 2 + 1];
                float o0 = a0 * inv + b0.x; o0 = o0 > 0.f ? o0 : 0.01f * o0;
                float o1 = a1 * inv + b0.y; o1 = o1 > 0.f ? o1 : 0.01f * o1;
                float o2 = a2 * inv + b0.z; o2 = o2 > 0.f ? o2 : 0.01f * o2;
                float o3 = a3 * inv + b0.w; o3 = o3 > 0.f ? o3 : 0.01f * o3;
                float o4 = a4 * inv + b1.x; o4 = o4 > 0.f ? o4 : 0.01f * o4;
                float o5 = a5 * inv + b1.y; o5 = o5 > 0.f ? o5 : 0.01f * o5;
                float o6 = a6 * inv + b1.z; o6 = o6 > 0.f ? o6 : 0.01f * o6;
                float o7 = a7 * inv + b1.w; o7 = o7 > 0.f ? o7 : 0.01f * o7;
                if constexpr (OBF16) {
                    ushortv8 ov;
                    ov[0] = f2bf(o0); ov[1] = f2bf(o1); ov[2] = f2bf(o2); ov[3] = f2bf(o3);
                    ov[4] = f2bf(o4); ov[5] = f2bf(o5); ov[6] = f2bf(o6); ov[7] = f2bf(o7);
                    ((ushortv8*)outv)[(size_t)wid * 16 + cb] = ov;
                } else {
                    float* op = (float*)outv + (size_t)wid * 128 + cb * 8;
                    *(float4*)op = make_float4(o0, o1, o2, o3);
                    *(float4*)(op + 4) = make_float4(o4, o5, o6, o7);
                }
            }
        } else {
            int eg = lane >> 3, cb = lane & 7;
            const uint4* h16 = (const uint4*)h;
#pragma unroll 2
            for (int e = eg; e < ne; e += 8) {
                int2 ev2 = es[wslot][e];
                float exv = __int_as_float(ev2.y);
                uint4 hv = h16[(size_t)ev2.x * 8 + cb];
                a0 += exv * __uint_as_float(hv.x << 16);
                a1 += exv * __uint_as_float(hv.x & 0xffff0000u);
                a2 += exv * __uint_as_float(hv.y << 16);
                a3 += exv * __uint_as_float(hv.y & 0xffff0000u);
                a4 += exv * __uint_as_float(hv.z << 16);
                a5 += exv * __uint_as_float(hv.z & 0xffff0000u);
                a6 += exv * __uint_as_float(hv.w << 16);
                a7 += exv * __uint_as_float(hv.w & 0xffff0000u);
            }
            a0 += __shfl_xor(a0, 8); a1 += __shfl_xor(a1, 8);
            a2 += __shfl_xor(a2, 8); a3 += __shfl_xor(a3, 8);
            a4 += __shfl_xor(a4, 8); a5 += __shfl_xor(a5, 8);
            a6 += __shfl_xor(a6, 8); a7 += __shfl_xor(a7, 8);
            a0 += __shfl_xor(a0, 16); a1 += __shfl_xor(a1, 16);
            a2 += __shfl_xor(a2, 16); a3 += __shfl_xor(a3, 16);
            a4 += __shfl_xor(a4, 16); a5 += __shfl_xor(a5, 16);
            a6 += __shfl_xor(a6, 16); a7 += __shfl_xor(a7, 16);
            a0 += __shfl_xor(a0, 32); a1 += __shfl_xor(a1, 32);
            a2 += __shfl_xor(a2, 32); a3 += __shfl_xor(a3, 32);
            a4 += __shfl_xor(a4, 32); a5 += __shfl_xor(a5, 32);
            a6 += __shfl_xor(a6, 32); a7 += __shfl_xor(a7, 32);
            if (eg == 0) {
                float4 b0 = ((const float4*)bias)[cb * 2];
                float4 b1 = ((const float4*)bias)[cb * 2 + 1];
                float o0 = a0 * inv + b0.x; o0 = o0 > 0.f ? o0 : 0.01f * o0;
                float o1 = a1 * inv + b0.y; o1 = o1 > 0.f ? o1 : 0.01f * o1;
                float o2 = a2 * inv + b0.z; o2 = o2 > 0.f ? o2 : 0.01f * o2;
                float o3 = a3 * inv + b0.w; o3 = o3 > 0.f ? o3 : 0.01f * o3;
                float o4 = a4 * inv + b1.x; o4 = o4 > 0.f ? o4 : 0.01f * o4;
                float o5 = a5 * inv + b1.y; o5 = o5 > 0.f ? o5 : 0.01f * o5;
                float o6 = a6 * inv + b1.z; o6 = o6 > 0.f ? o6 : 0.01f * o6;
                float o7 = a7 * inv + b1.w; o7 = o7 > 0.f ? o7 : 0.01f * o7;
                if constexpr (OBF16) {
                    ushortv8 ov;
                    ov[0] = f2bf(o0); ov[1] = f2bf(o1); ov[2] = f2bf(o2); ov[3] = f2bf(o3);
                    ov[4] = f2bf(o4); ov[5] = f2bf(o5); ov[6] = f2bf(o6); ov[7] = f2bf(o7);
                    ((ushortv8*)outv)[(size_t)wid * 8 + cb] = ov;
                } else {
                    float* op = (float*)outv + (size_t)wid * 64 + cb * 8;
                    *(float4*)op = make_float4(o0, o1, o2, o3);
                    *(float4*)(op + 4) = make_float4(o4, o5, o6, o7);
                }
            }
        }
        return;
    }

    // ---- fallback (degree > MAXE): serial path, never hit for this graph ----
    float m = -1e30f;
    for (int e = lane; e < ne; e += 64) {
        int2 ev = eswr[lo + e];
        float lg = s[ev.x] + di + ce * __int_as_float(ev.y);
        lg = lg > 0.f ? lg : 0.2f * lg;
        m = fmaxf(m, lg);
    }
    for (int o = 32; o; o >>= 1) m = fmaxf(m, __shfl_xor(m, o));
    float den = 0.f;
    int c0 = lane, c1 = lane + 64;
    float a0 = 0.f, a1 = 0.f;
    for (int e = 0; e < ne; e++) {
        int2 ev = eswr[lo + e];
        float lg = s[ev.x] + di + ce * __int_as_float(ev.y);
        lg = lg > 0.f ? lg : 0.2f * lg;
        float ex = __expf(lg - m);
        den += ex;
        const unsigned short* hr = &h[(size_t)ev.x * cout];
        a0 += ex * bf2f(hr[c0]);
        if (cout > 64) a1 += ex * bf2f(hr[c1]);
    }
    float inv = 1.0f / (den + 1e-16f);
    float o0 = a0 * inv + bias[c0];
    o0 = o0 > 0.f ? o0 : 0.01f * o0;
    float o1 = 0.f;
    if (cout > 64) {
        o1 = a1 * inv + bias[c1];
        o1 = o1 > 0.f ? o1 : 0.01f * o1;
    }
    if constexpr (OBF16) {
        unsigned short* out = (unsigned short*)outv;
        out[(size_t)wid * cout + c0] = f2bf(o0);
        if (cout > 64) out[(size_t)wid * cout + c1] = f2bf(o1);
    } else {
        float* out = (float*)outv;
        out[(size_t)wid * cout + c0] = o0;
        if (cout > 64) out[(size_t)wid * cout + c1] = o1;
    }
}

extern "C" void kernel_launch(void* const* d_in, const int* in_sizes, int n_in,
                              void* d_out, int out_size, void* d_ws, size_t ws_size,
                              hipStream_t stream) {
    const int N = NNODES, E = NEDGES, EF = NEDGES + NNODES;

    const float* x = (const float*)d_in[0];
    const int* ei = (const int*)d_in[1];   // int32 on device
    const float* ew = (const float*)d_in[2];
    const float* W1 = (const float*)d_in[3];
    const float* as1 = (const float*)d_in[4];
    const float* ad1 = (const float*)d_in[5];
    const float* We1 = (const float*)d_in[6];
    const float* ae1 = (const float*)d_in[7];
    const float* b1 = (const float*)d_in[8];
    const float* W2 = (const float*)d_in[9];
    const float* as2 = (const float*)d_in[10];
    const float* ad2 = (const float*)d_in[11];
    const float* We2 = (const float*)d_in[12];
    const float* ae2 = (const float*)d_in[13];
    const float* b2 = (const float*)d_in[14];
    const float* W3 = (const float*)d_in[15];
    const float* as3 = (const float*)d_in[16];
    const float* ad3 = (const float*)d_in[17];
    const float* We3 = (const float*)d_in[18];
    const float* ae3 = (const float*)d_in[19];
    const float* b3 = (const float*)d_in[20];
    float* out = (float*)d_out;

    // workspace layout (aligned bump allocator). sd and fill must be adjacent (one zero).
    char* wp = (char*)d_ws;
    auto alloc = [&](size_t bytes, size_t align) -> void* {
        size_t a = ((size_t)wp + align - 1) & ~(align - 1);
        wp = (char*)(a + bytes);
        return (void*)a;
    };
    float* sd = (float*)alloc((size_t)6 * N * 4, 16);            // s1,d1,s2,d2,s3,d3
    unsigned* fill = (unsigned*)alloc((size_t)NB * 16 * 4, 4);   // padded bucket counters
    unsigned short* act = (unsigned short*)alloc((size_t)N * 128 * 2, 16);
    unsigned short* h = (unsigned short*)alloc((size_t)N * 128 * 2, 16);
    int* row_start = (int*)alloc((size_t)(N + 1) * 4, 4);
    unsigned* bucket_base = (unsigned*)alloc((size_t)NB * 4, 4);
    int2* eswr = (int2*)alloc((size_t)EF * 8, 16);
    uint2* regions = (uint2*)alloc((size_t)NB * CAP * 8, 16);
    float* ce = (float*)alloc(4 * 4, 4);
    unsigned short* wt1 = (unsigned short*)alloc(32768 * 2, 16);
    unsigned short* wt2 = (unsigned short*)alloc(16384 * 2, 16);
    unsigned short* wt3 = (unsigned short*)alloc(8192 * 2, 16);

    // ---- init: zero sd+fill, transpose weights, ce dots (one fused launch) ----
    init_k<<<2596, 256, 0, stream>>>((int*)sd, W1, W2, W3, wt1, wt2, wt3,
                                     We1, ae1, We2, ae2, We3, ae3, ce);
    // ---- CSR build via two-level bucket sort ----
    bucket_k<<<BK_BLOCKS, 256, 0, stream>>>(ei, ew, fill, regions);
    bucket_scan_k<<<1, 512, 0, stream>>>(fill, bucket_base, row_start);
    place_k<<<NB, 512, 0, stream>>>(regions, fill, bucket_base, eswr, row_start);

    // ---- layer 1: 256 -> 128 ----
    {
        int cin = 256, cout = 128;
        gemm_mfma<false, 2><<<(N + 63) / 64, 256, 0, stream>>>(
            x, wt1, h, as1, ad1, sd + 0 * N, sd + 1 * N, N, cin, cout);
        agg_k<true><<<(N + 3) / 4, 256, 0, stream>>>(eswr, row_start, h, sd + 0 * N,
                                                     sd + 1 * N, ce + 0, b1, act, N, cout);
    }
    // ---- layer 2: 128 -> 128 ----
    {
        int cin = 128, cout = 128;
        gemm_mfma<true, 2><<<(N + 63) / 64, 256, 0, stream>>>(
            act, wt2, h, as2, ad2, sd + 2 * N, sd + 3 * N, N, cin, cout);
        agg_k<true><<<(N + 3) / 4, 256, 0, stream>>>(eswr, row_start, h, sd + 2 * N,
                                                     sd + 3 * N, ce + 1, b2, act, N, cout);
    }
    // ---- layer 3: 128 -> 64 ----
    {
        int cin = 128, cout = 64;
        gemm_mfma<true, 1><<<(N + 63) / 64, 256, 0, stream>>>(
            act, wt3, h, as3, ad3, sd + 4 * N, sd + 5 * N, N, cin, cout);
        agg_k<false><<<(N + 3) / 4, 256, 0, stream>>>(eswr, row_start, h, sd + 4 * N,
                                                      sd + 5 * N, ce + 2, b3, out, N, cout);
    }
}

// Round 11
// 372.690 us; speedup vs baseline: 3.5148x; 1.0059x over previous
//
#include <hip/hip_runtime.h>
#include <hip/hip_bf16.h>
#include <math.h>

#define NNODES 100000
#define NEDGES 1600000
#define MAXE 128
#define NB 391                 // buckets of 256 dsts: ceil(100000/256)
#define CAP 6144               // region capacity per bucket (mean ~4090, 32 sigma headroom)
#define EPT 7
#define BK_EDGES (256 * EPT)   // 1792 edges per block
#define BK_BLOCKS ((NEDGES + BK_EDGES - 1) / BK_EDGES)  // 893

typedef short bfrag8 __attribute__((ext_vector_type(8)));  // 8 bf16 (4 VGPRs)
typedef float facc4 __attribute__((ext_vector_type(4)));   // 4 fp32 acc
typedef unsigned short ushortv8 __attribute__((ext_vector_type(8)));
typedef unsigned long long ull;

__device__ __forceinline__ unsigned short f2bf(float f) {
    unsigned u = __float_as_uint(f);
    unsigned r = u + 0x7fffu + ((u >> 16) & 1u);  // round-to-nearest-even
    return (unsigned short)(r >> 16);
}
__device__ __forceinline__ float bf2f(unsigned short u) {
    return __uint_as_float((unsigned)u << 16);
}

// ---------------- fused init: zero (sd+fill), Wt transpose, ce dots ----------------
__global__ void init_k(int* zbase,
                       const float* __restrict__ W1, const float* __restrict__ W2,
                       const float* __restrict__ W3, unsigned short* __restrict__ wt1,
                       unsigned short* __restrict__ wt2, unsigned short* __restrict__ wt3,
                       const float* We1, const float* ae1, const float* We2,
                       const float* ae2, const float* We3, const float* ae3, float* ce) {
    int gb = blockIdx.x, t = threadIdx.x;
    if (gb < 2369) {
        int i = gb * 256 + t;
        if (i < 6 * NNODES + NB * 16) zbase[i] = 0;
        return;
    }
    if (gb < 2593) {
        int i = (gb - 2369) * 256 + t;
        if (i < 32768) {            // layer1: [256][128] -> [128][256]
            int k = i >> 7, nn = i & 127;
            wt1[nn * 256 + k] = f2bf(W1[i]);
            return;
        }
        i -= 32768;
        if (i < 16384) {            // layer2: [128][128]
            int k = i >> 7, nn = i & 127;
            wt2[nn * 128 + k] = f2bf(W2[i]);
            return;
        }
        i -= 16384;                 // layer3: [128][64] -> [64][128]
        int k = i >> 6, nn = i & 63;
        wt3[nn * 128 + k] = f2bf(W3[i]);
        return;
    }
    if (t >= 64) return;
    int cb = gb - 2593;
    const float* W; const float* a; int cout;
    if (cb == 0) { W = We1; a = ae1; cout = 128; }
    else if (cb == 1) { W = We2; a = ae2; cout = 128; }
    else { W = We3; a = ae3; cout = 64; }
    float v = 0.f;
    for (int c = t; c < cout; c += 64) v += W[c] * a[c];
    for (int o = 32; o; o >>= 1) v += __shfl_xor(v, o);
    if (t == 0) ce[cb] = v;
}

// ---------------- pass 1: bucket edges (LDS histogram + chunk claim + staged write) ----
__global__ __launch_bounds__(256) void bucket_k(
    const int* __restrict__ ei, const float* __restrict__ ew,
    unsigned* __restrict__ fill /* NB*16 padded */, uint2* __restrict__ regions) {
    __shared__ unsigned cnt[NB], lbase[NB], gb_s[NB], cur[NB];
    __shared__ unsigned ssum[256];
    __shared__ uint2 srec[BK_EDGES];
    __shared__ unsigned short sbkt[BK_EDGES];
    int t = threadIdx.x;
    for (int b = t; b < NB; b += 256) cnt[b] = 0;
    __syncthreads();
    int e0 = blockIdx.x * BK_EDGES;
    int dstv[EPT], srcv[EPT];
    unsigned wb[EPT];
#pragma unroll
    for (int j = 0; j < EPT; j++) {
        int e = e0 + j * 256 + t;
        dstv[j] = -1;
        if (e < NEDGES) {
            int dd = ei[NEDGES + e];
            int ss = ei[e];
            if ((unsigned)dd < (unsigned)NNODES && (unsigned)ss < (unsigned)NNODES) {
                dstv[j] = dd; srcv[j] = ss; wb[j] = __float_as_uint(ew[e]);
            }
        }
        if (dstv[j] >= 0) atomicAdd(&cnt[dstv[j] >> 8], 1u);
    }
    __syncthreads();
    unsigned c0 = cnt[t];
    unsigned c1 = (t + 256 < NB) ? cnt[t + 256] : 0u;
    ssum[t] = c0 + c1;
    __syncthreads();
    for (int off = 1; off < 256; off <<= 1) {
        unsigned v = (t >= off) ? ssum[t - off] : 0u;
        __syncthreads();
        ssum[t] += v;
        __syncthreads();
    }
    unsigned excl = ssum[t] - (c0 + c1);
    lbase[t] = excl; cur[t] = excl;
    gb_s[t] = c0 ? atomicAdd(&fill[t * 16], c0) : 0u;
    if (t + 256 < NB) {
        lbase[t + 256] = excl + c0; cur[t + 256] = excl + c0;
        gb_s[t + 256] = c1 ? atomicAdd(&fill[(t + 256) * 16], c1) : 0u;
    }
    __syncthreads();
#pragma unroll
    for (int j = 0; j < EPT; j++) {
        if (dstv[j] >= 0) {
            unsigned b = (unsigned)dstv[j] >> 8;
            unsigned p = atomicAdd(&cur[b], 1u);
            srec[p] = make_uint2(((unsigned)(dstv[j] & 255) << 24) | (unsigned)srcv[j], wb[j]);
            sbkt[p] = (unsigned short)b;
        }
    }
    __syncthreads();
    unsigned tot = ssum[255];
    for (unsigned i = t; i < tot; i += 256) {
        unsigned b = sbkt[i];
        unsigned slot = gb_s[b] + (i - lbase[b]);
        if (slot < CAP) regions[(size_t)b * CAP + slot] = srec[i];
    }
}

// ---------------- pass 2: per-bucket place (internal prefix, deg/sum, seg scan, CSR) ----
__global__ __launch_bounds__(1024) void place_k(
    const uint2* __restrict__ regions, const unsigned* __restrict__ fill,
    int2* __restrict__ eswr, int* __restrict__ row_start) {
    __shared__ uint2 rec[CAP];
    __shared__ unsigned deg[256], sumw[256], sc[256], cur[256];
    __shared__ unsigned red[1024];
    int b = blockIdx.x, t = threadIdx.x;
    unsigned size = fill[b * 16];
    if (size > CAP) size = CAP;
    int dst0 = b << 8;
    int nvalid = NNODES - dst0;
    if (nvalid > 256) nvalid = 256;
    if (nvalid < 0) nvalid = 0;
    // internal bucket_base prefix: sum over j<b of (min(fill[j],CAP) + nvalid(j));
    // b < NB <= 1024 so each thread owns at most one j.
    unsigned part = 0;
    if (t < b) {
        unsigned c = fill[t * 16];
        if (c > CAP) c = CAP;
        int nv = NNODES - (t << 8);
        if (nv > 256) nv = 256;
        part = c + (unsigned)nv;
    }
    red[t] = part;
    if (t < 256) { deg[t] = 0; sumw[t] = 0; }
    __syncthreads();
    for (int off = 512; off; off >>= 1) {
        if (t < off) red[t] += red[t + off];
        __syncthreads();
    }
    unsigned bb = red[0];
    // load region + per-dst histogram
    for (unsigned i = t; i < size; i += 1024) {
        uint2 r = regions[(size_t)b * CAP + i];
        rec[i] = r;
        unsigned dl = r.x >> 24;
        atomicAdd(&deg[dl], 1u);
        atomicAdd(&sumw[dl], __float2uint_rn(__uint_as_float(r.y) * 16777216.0f));
    }
    __syncthreads();
    // scan 256 per-dst counts (deg+1 for self loop)
    unsigned cnti = (t < (unsigned)nvalid) ? deg[t] + 1u : 0u;
    if (t < 256) sc[t] = cnti;
    __syncthreads();
    for (int off = 1; off < 256; off <<= 1) {
        unsigned v = (t >= off && t < 256) ? sc[t - off] : 0u;
        __syncthreads();
        if (t < 256) sc[t] += v;
        __syncthreads();
    }
    if (t < 256) {
        unsigned excl = sc[t] - cnti;
        cur[t] = excl + 1u;
        if (t < (unsigned)nvalid) {
            int dst = dst0 + t;
            row_start[dst] = (int)(bb + excl);
            float sw = (float)sumw[t] * (1.0f / 16777216.0f);
            int dg = (int)deg[t];
            float w = sw / (float)(dg > 1 ? dg : 1);
            eswr[bb + excl] = make_int2(dst, __float_as_int(w));  // self-loop at slot 0
        }
    }
    if (b == NB - 1 && t == 0) row_start[NNODES] = (int)(bb + sc[255]);
    __syncthreads();
    for (unsigned i = t; i < size; i += 1024) {
        uint2 r = rec[i];
        unsigned dl = r.x >> 24;
        unsigned p = atomicAdd(&cur[dl], 1u);
        eswr[bb + p] = make_int2((int)(r.x & 0xFFFFFFu), (int)r.y);
    }
}

// ---------------- MFMA GEMM: H(bf16) = X @ W, fused s/d partial dots ----------------
// NC col-blocks of 64 computed per block from ONE staged A tile (A read once from HBM).
template <bool ABF16, int NC>
__global__ __launch_bounds__(256) void gemm_mfma(
    const void* __restrict__ Xv, const unsigned short* __restrict__ Wt,
    unsigned short* __restrict__ H, const float* __restrict__ as_,
    const float* __restrict__ ad_, float* __restrict__ s, float* __restrict__ d,
    int nrows, int cin, int cout) {
    __shared__ __align__(16) unsigned short lA[64 * 40];
    __shared__ __align__(16) unsigned short lB[NC * 64 * 40];
    int t = threadIdx.x;
    int wv = t >> 6, lane = t & 63;
    int lr = lane & 15, lg = lane >> 4;
    int row0 = blockIdx.x * 64;
    int sr = t >> 2, sc = (t & 3) * 8;

    facc4 acc[NC][4] = {};
    bool rowok = (row0 + sr) < nrows;

    for (int k0 = 0; k0 < cin; k0 += 32) {
        union { bfrag8 v; unsigned short u[8]; } pa;
        if (rowok) {
            if constexpr (ABF16) {
                const unsigned short* xrow = (const unsigned short*)Xv + (size_t)(row0 + sr) * cin;
                pa.v = *(const bfrag8*)&xrow[k0 + sc];
            } else {
                const float* xrow = (const float*)Xv + (size_t)(row0 + sr) * cin;
                float4 v0 = *(const float4*)&xrow[k0 + sc];
                float4 v1 = *(const float4*)&xrow[k0 + sc + 4];
                pa.u[0] = f2bf(v0.x); pa.u[1] = f2bf(v0.y);
                pa.u[2] = f2bf(v0.z); pa.u[3] = f2bf(v0.w);
                pa.u[4] = f2bf(v1.x); pa.u[5] = f2bf(v1.y);
                pa.u[6] = f2bf(v1.z); pa.u[7] = f2bf(v1.w);
            }
        } else {
#pragma unroll
            for (int j = 0; j < 8; j++) pa.u[j] = 0;
        }
        *(bfrag8*)&lA[sr * 40 + sc] = pa.v;
#pragma unroll
        for (int cb = 0; cb < NC; cb++) {
            *(bfrag8*)&lB[(cb * 64 + sr) * 40 + sc] =
                *(const bfrag8*)&Wt[(size_t)(cb * 64 + sr) * cin + k0 + sc];
        }
        __syncthreads();
        bfrag8 a = *(const bfrag8*)&lA[(wv * 16 + lr) * 40 + lg * 8];
#pragma unroll
        for (int cb = 0; cb < NC; cb++) {
#pragma unroll
            for (int n0 = 0; n0 < 4; n0++) {
                bfrag8 bfr = *(const bfrag8*)&lB[(cb * 64 + n0 * 16 + lr) * 40 + lg * 8];
                acc[cb][n0] = __builtin_amdgcn_mfma_f32_16x16x32_bf16(a, bfr, acc[cb][n0], 0, 0, 0);
            }
        }
        __syncthreads();
    }
#pragma unroll
    for (int r = 0; r < 4; r++) {
        int row = row0 + wv * 16 + lg * 4 + r;
        if (row >= nrows) continue;
        float ps = 0.f, pd = 0.f;
#pragma unroll
        for (int cb = 0; cb < NC; cb++) {
#pragma unroll
            for (int n0 = 0; n0 < 4; n0++) {
                int col = cb * 64 + n0 * 16 + lr;
                float v = acc[cb][n0][r];
                H[(size_t)row * cout + col] = f2bf(v);
                ps += v * as_[col];
                pd += v * ad_[col];
            }
        }
        for (int o = 8; o; o >>= 1) {
            ps += __shfl_xor(ps, o);
            pd += __shfl_xor(pd, o);
        }
        if (lr == 0) {
            atomicAdd(&s[row], ps);
            atomicAdd(&d[row], pd);
        }
    }
}

// ---------------- attention + aggregation: one wave per dst node (bf16 h) ----------
template <bool OBF16>
__global__ __launch_bounds__(256) void agg_k(
    const int2* __restrict__ eswr, const int* __restrict__ row_start,
    const unsigned short* __restrict__ h, const float* __restrict__ s,
    const float* __restrict__ d, const float* __restrict__ ce_ptr,
    const float* __restrict__ bias, void* __restrict__ outv, int n, int cout) {
    __shared__ int2 es[4][MAXE];   // {src, logit->ex}
    int wslot = threadIdx.x >> 6;
    int wid = (blockIdx.x * blockDim.x + threadIdx.x) >> 6;
    int lane = threadIdx.x & 63;
    if (wid >= n) return;
    int lo = row_start[wid], ne = row_start[wid + 1] - lo;
    float ce = *ce_ptr;
    float di = d[wid];

    if (ne <= MAXE) {
        float m = -1e30f;
        for (int e = lane; e < ne; e += 64) {
            int2 ev = eswr[lo + e];
            float lg = s[ev.x] + di + ce * __int_as_float(ev.y);
            lg = lg > 0.f ? lg : 0.2f * lg;
            es[wslot][e] = make_int2(ev.x, __float_as_int(lg));
            m = fmaxf(m, lg);
        }
        for (int o = 32; o; o >>= 1) m = fmaxf(m, __shfl_xor(m, o));
        float den = 0.f;
        for (int e = lane; e < ne; e += 64) {
            float exv = __expf(__int_as_float(es[wslot][e].y) - m);
            es[wslot][e].y = __float_as_int(exv);
            den += exv;
        }
        for (int o = 32; o; o >>= 1) den += __shfl_xor(den, o);
        float inv = 1.0f / (den + 1e-16f);

        float a0 = 0.f, a1 = 0.f, a2 = 0.f, a3 = 0.f;
        float a4 = 0.f, a5 = 0.f, a6 = 0.f, a7 = 0.f;
        if (cout == 128) {
            int eg = lane >> 4, cb = lane & 15;
            const uint4* h16 = (const uint4*)h;
#pragma unroll 4
            for (int e = eg; e < ne; e += 4) {
                int2 ev2 = es[wslot][e];
                float exv = __int_as_float(ev2.y);
                uint4 hv = h16[(size_t)ev2.x * 16 + cb];
                a0 += exv * __uint_as_float(hv.x << 16);
                a1 += exv * __uint_as_float(hv.x & 0xffff0000u);
                a2 += exv * __uint_as_float(hv.y << 16);
                a3 += exv * __uint_as_float(hv.y & 0xffff0000u);
                a4 += exv * __uint_as_float(hv.z << 16);
                a5 += exv * __uint_as_float(hv.z & 0xffff0000u);
                a6 += exv * __uint_as_float(hv.w << 16);
                a7 += exv * __uint_as_float(hv.w & 0xffff0000u);
            }
            a0 += __shfl_xor(a0, 16); a1 += __shfl_xor(a1, 16);
            a2 += __shfl_xor(a2, 16); a3 += __shfl_xor(a3, 16);
            a4 += __shfl_xor(a4, 16); a5 += __shfl_xor(a5, 16);
            a6 += __shfl_xor(a6, 16); a7 += __shfl_xor(a7, 16);
            a0 += __shfl_xor(a0, 32); a1 += __shfl_xor(a1, 32);
            a2 += __shfl_xor(a2, 32); a3 += __shfl_xor(a3, 32);
            a4 += __shfl_xor(a4, 32); a5 += __shfl_xor(a5, 32);
            a6 += __shfl_xor(a6, 32); a7 += __shfl_xor(a7, 32);
            if (eg == 0) {
                float4 b0 = ((const float4*)bias)[cb * 2];
                float4 b1 = ((const float4*)bias)[cb * 2 + 1];
                float o0 = a0 * inv + b0.x; o0 = o0 > 0.f ? o0 : 0.01f * o0;
                float o1 = a1 * inv + b0.y; o1 = o1 > 0.f ? o1 : 0.01f * o1;
                float o2 = a2 * inv + b0.z; o2 = o2 > 0.f ? o2 : 0.01f * o2;
                float o3 = a3 * inv + b0.w; o3 = o3 > 0.f ? o3 : 0.01f * o3;
                float o4 = a4 * inv + b1.x; o4 = o4 > 0.f ? o4 : 0.01f * o4;
                float o5 = a5 * inv + b1.y; o5 = o5 > 0.f ? o5 : 0.01f * o5;
                float o6 = a6 * inv + b1.z; o6 = o6 > 0.f ? o6 : 0.01f * o6;
                float o7 = a7 * inv + b1.w; o7 = o7 > 0.f ? o7 : 0.01f * o7;
                if constexpr (OBF16) {
                    ushortv8 ov;
                    ov[0] = f2bf(o0); ov[1] = f2bf(o1); ov[2] = f2bf(o2); ov[3] = f2bf(o3);
                    ov[4] = f2bf(o4); ov[5] = f2bf(o5); ov[6] = f2bf(o6); ov[7] = f2bf(o7);
                    ((ushortv8*)outv)[(size_t)wid * 16 + cb] = ov;
                } else {
                    float* op = (float*)outv + (size_t)wid * 128 + cb * 8;
                    *(float4*)op = make_float4(o0, o1, o2, o3);
                    *(float4*)(op + 4) = make_float4(o4, o5, o6, o7);
                }
            }
        } else {
            int eg = lane >> 3, cb = lane & 7;
            const uint4* h16 = (const uint4*)h;
#pragma unroll 2
            for (int e = eg; e < ne; e += 8) {
                int2 ev2 = es[wslot][e];
                float exv = __int_as_float(ev2.y);
                uint4 hv = h16[(size_t)ev2.x * 8 + cb];
                a0 += exv * __uint_as_float(hv.x << 16);
                a1 += exv * __uint_as_float(hv.x & 0xffff0000u);
                a2 += exv * __uint_as_float(hv.y << 16);
                a3 += exv * __uint_as_float(hv.y & 0xffff0000u);
                a4 += exv * __uint_as_float(hv.z << 16);
                a5 += exv * __uint_as_float(hv.z & 0xffff0000u);
                a6 += exv * __uint_as_float(hv.w << 16);
                a7 += exv * __uint_as_float(hv.w & 0xffff0000u);
            }
            a0 += __shfl_xor(a0, 8); a1 += __shfl_xor(a1, 8);
            a2 += __shfl_xor(a2, 8); a3 += __shfl_xor(a3, 8);
            a4 += __shfl_xor(a4, 8); a5 += __shfl_xor(a5, 8);
            a6 += __shfl_xor(a6, 8); a7 += __shfl_xor(a7, 8);
            a0 += __shfl_xor(a0, 16); a1 += __shfl_xor(a1, 16);
            a2 += __shfl_xor(a2, 16); a3 += __shfl_xor(a3, 16);
            a4 += __shfl_xor(a4, 16); a5 += __shfl_xor(a5, 16);
            a6 += __shfl_xor(a6, 16); a7 += __shfl_xor(a7, 16);
            a0 += __shfl_xor(a0, 32); a1 += __shfl_xor(a1, 32);
            a2 += __shfl_xor(a2, 32); a3 += __shfl_xor(a3, 32);
            a4 += __shfl_xor(a4, 32); a5 += __shfl_xor(a5, 32);
            a6 += __shfl_xor(a6, 32); a7 += __shfl_xor(a7, 32);
            if (eg == 0) {
                float4 b0 = ((const float4*)bias)[cb * 2];
                float4 b1 = ((const float4*)bias)[cb * 2 + 1];
                float o0 = a0 * inv + b0.x; o0 = o0 > 0.f ? o0 : 0.01f * o0;
                float o1 = a1 * inv + b0.y; o1 = o1 > 0.f ? o1 : 0.01f * o1;
                float o2 = a2 * inv + b0.z; o2 = o2 > 0.f ? o2 : 0.01f * o2;
                float o3 = a3 * inv + b0.w; o3 = o3 > 0.f ? o3 : 0.01f * o3;
                float o4 = a4 * inv + b1.x; o4 = o4 > 0.f ? o4 : 0.01f * o4;
                float o5 = a5 * inv + b1.y; o5 = o5 > 0.f ? o5 : 0.01f * o5;
                float o6 = a6 * inv + b1.z; o6 = o6 > 0.f ? o6 : 0.01f * o6;
                float o7 = a7 * inv + b1.w; o7 = o7 > 0.f ? o7 : 0.01f * o7;
                if constexpr (OBF16) {
                    ushortv8 ov;
                    ov[0] = f2bf(o0); ov[1] = f2bf(o1); ov[2] = f2bf(o2); ov[3] = f2bf(o3);
                    ov[4] = f2bf(o4); ov[5] = f2bf(o5); ov[6] = f2bf(o6); ov[7] = f2bf(o7);
                    ((ushortv8*)outv)[(size_t)wid * 8 + cb] = ov;
                } else {
                    float* op = (float*)outv + (size_t)wid * 64 + cb * 8;
                    *(float4*)op = make_float4(o0, o1, o2, o3);
                    *(float4*)(op + 4) = make_float4(o4, o5, o6, o7);
                }
            }
        }
        return;
    }

    // ---- fallback (degree > MAXE): serial path, never hit for this graph ----
    float m = -1e30f;
    for (int e = lane; e < ne; e += 64) {
        int2 ev = eswr[lo + e];
        float lg = s[ev.x] + di + ce * __int_as_float(ev.y);
        lg = lg > 0.f ? lg : 0.2f * lg;
        m = fmaxf(m, lg);
    }
    for (int o = 32; o; o >>= 1) m = fmaxf(m, __shfl_xor(m, o));
    float den = 0.f;
    int c0 = lane, c1 = lane + 64;
    float a0 = 0.f, a1 = 0.f;
    for (int e = 0; e < ne; e++) {
        int2 ev = eswr[lo + e];
        float lg = s[ev.x] + di + ce * __int_as_float(ev.y);
        lg = lg > 0.f ? lg : 0.2f * lg;
        float ex = __expf(lg - m);
        den += ex;
        const unsigned short* hr = &h[(size_t)ev.x * cout];
        a0 += ex * bf2f(hr[c0]);
        if (cout > 64) a1 += ex * bf2f(hr[c1]);
    }
    float inv = 1.0f / (den + 1e-16f);
    float o0 = a0 * inv + bias[c0];
    o0 = o0 > 0.f ? o0 : 0.01f * o0;
    float o1 = 0.f;
    if (cout > 64) {
        o1 = a1 * inv + bias[c1];
        o1 = o1 > 0.f ? o1 : 0.01f * o1;
    }
    if constexpr (OBF16) {
        unsigned short* out = (unsigned short*)outv;
        out[(size_t)wid * cout + c0] = f2bf(o0);
        if (cout > 64) out[(size_t)wid * cout + c1] = f2bf(o1);
    } else {
        float* out = (float*)outv;
        out[(size_t)wid * cout + c0] = o0;
        if (cout > 64) out[(size_t)wid * cout + c1] = o1;
    }
}

extern "C" void kernel_launch(void* const* d_in, const int* in_sizes, int n_in,
                              void* d_out, int out_size, void* d_ws, size_t ws_size,
                              hipStream_t stream) {
    const int N = NNODES, E = NEDGES, EF = NEDGES + NNODES;

    const float* x = (const float*)d_in[0];
    const int* ei = (const int*)d_in[1];   // int32 on device
    const float* ew = (const float*)d_in[2];
    const float* W1 = (const float*)d_in[3];
    const float* as1 = (const float*)d_in[4];
    const float* ad1 = (const float*)d_in[5];
    const float* We1 = (const float*)d_in[6];
    const float* ae1 = (const float*)d_in[7];
    const float* b1 = (const float*)d_in[8];
    const float* W2 = (const float*)d_in[9];
    const float* as2 = (const float*)d_in[10];
    const float* ad2 = (const float*)d_in[11];
    const float* We2 = (const float*)d_in[12];
    const float* ae2 = (const float*)d_in[13];
    const float* b2 = (const float*)d_in[14];
    const float* W3 = (const float*)d_in[15];
    const float* as3 = (const float*)d_in[16];
    const float* ad3 = (const float*)d_in[17];
    const float* We3 = (const float*)d_in[18];
    const float* ae3 = (const float*)d_in[19];
    const float* b3 = (const float*)d_in[20];
    float* out = (float*)d_out;

    // workspace layout (aligned bump allocator). sd and fill must be adjacent (one zero).
    char* wp = (char*)d_ws;
    auto alloc = [&](size_t bytes, size_t align) -> void* {
        size_t a = ((size_t)wp + align - 1) & ~(align - 1);
        wp = (char*)(a + bytes);
        return (void*)a;
    };
    float* sd = (float*)alloc((size_t)6 * N * 4, 16);            // s1,d1,s2,d2,s3,d3
    unsigned* fill = (unsigned*)alloc((size_t)NB * 16 * 4, 4);   // padded bucket counters
    unsigned short* act = (unsigned short*)alloc((size_t)N * 128 * 2, 16);
    unsigned short* h = (unsigned short*)alloc((size_t)N * 128 * 2, 16);
    int* row_start = (int*)alloc((size_t)(N + 1) * 4, 4);
    int2* eswr = (int2*)alloc((size_t)EF * 8, 16);
    uint2* regions = (uint2*)alloc((size_t)NB * CAP * 8, 16);
    float* ce = (float*)alloc(4 * 4, 4);
    unsigned short* wt1 = (unsigned short*)alloc(32768 * 2, 16);
    unsigned short* wt2 = (unsigned short*)alloc(16384 * 2, 16);
    unsigned short* wt3 = (unsigned short*)alloc(8192 * 2, 16);

    // ---- init: zero sd+fill, transpose weights, ce dots (one fused launch) ----
    init_k<<<2596, 256, 0, stream>>>((int*)sd, W1, W2, W3, wt1, wt2, wt3,
                                     We1, ae1, We2, ae2, We3, ae3, ce);
    // ---- CSR build via two-level bucket sort (scan folded into place_k) ----
    bucket_k<<<BK_BLOCKS, 256, 0, stream>>>(ei, ew, fill, regions);
    place_k<<<NB, 1024, 0, stream>>>(regions, fill, eswr, row_start);

    // ---- layer 1: 256 -> 128 ----
    {
        int cin = 256, cout = 128;
        gemm_mfma<false, 2><<<(N + 63) / 64, 256, 0, stream>>>(
            x, wt1, h, as1, ad1, sd + 0 * N, sd + 1 * N, N, cin, cout);
        agg_k<true><<<(N + 3) / 4, 256, 0, stream>>>(eswr, row_start, h, sd + 0 * N,
                                                     sd + 1 * N, ce + 0, b1, act, N, cout);
    }
    // ---- layer 2: 128 -> 128 ----
    {
        int cin = 128, cout = 128;
        gemm_mfma<true, 2><<<(N + 63) / 64, 256, 0, stream>>>(
            act, wt2, h, as2, ad2, sd + 2 * N, sd + 3 * N, N, cin, cout);
        agg_k<true><<<(N + 3) / 4, 256, 0, stream>>>(eswr, row_start, h, sd + 2 * N,
                                                     sd + 3 * N, ce + 1, b2, act, N, cout);
    }
    // ---- layer 3: 128 -> 64 ----
    {
        int cin = 128, cout = 64;
        gemm_mfma<true, 1><<<(N + 63) / 64, 256, 0, stream>>>(
            act, wt3, h, as3, ad3, sd + 4 * N, sd + 5 * N, N, cin, cout);
        agg_k<false><<<(N + 3) / 4, 256, 0, stream>>>(eswr, row_start, h, sd + 4 * N,
                                                      sd + 5 * N, ce + 2, b3, out, N, cout);
    }
}